// Round 1
// baseline (1822.289 us; speedup 1.0000x reference)
//
#include <hip/hip_runtime.h>
#include <math.h>

#define EPS 1e-5f

constexpr int Bv   = 16384;   // batch
constexpr int Dv   = 1024;    // hidden
constexpr int Lv   = 3;       // blocks
constexpr int NKVv = 128;
constexpr int Vv   = 256;
constexpr int OUTv = 256;
constexpr int ZLD  = Lv * Dv; // 3072 concat width

// ---------------------------------------------------------------------------
// prep: vmean_i[v] = mean_n values[i][n][v];  c_i[d] = sum_k tile(vmean)[k] * Wout[i][d][k]
// (softmax row-sums are exactly 1, so the whole attention == add constant c_i)
// ---------------------------------------------------------------------------
__global__ void prep_kernel(const float* __restrict__ values,
                            const float* __restrict__ Wout,
                            float* __restrict__ cvec) {
    const int i = blockIdx.x;   // layer
    const int t = threadIdx.x;  // 0..255
    __shared__ float sv[1024];  // tiled vmean (H=4 repeats of 256)
    const float* vals = values + (size_t)i * NKVv * Vv;
    float s = 0.f;
    for (int n = 0; n < NKVv; ++n) s += vals[n * Vv + t];
    s *= (1.0f / NKVv);
    sv[t] = s; sv[t + 256] = s; sv[t + 512] = s; sv[t + 768] = s;
    __syncthreads();
    const float* Wo = Wout + (size_t)i * Dv * 1024;
    for (int d = t; d < Dv; d += 256) {
        const float* row = Wo + (size_t)d * 1024;
        float acc = 0.f;
        for (int k = 0; k < 1024; ++k) acc = fmaf(sv[k], row[k], acc);
        cvec[i * Dv + d] = acc;
    }
}

// ---------------------------------------------------------------------------
// Tiled f32 NT GEMM: C[m][n] = sum_k A[m][k] * Bm[n][k]   (+ epilogue)
// BM=BN=128, BK=16, 256 threads, 8x8 acc/thread.
// RELU_C: v = relu(acc + bias[n]) + cvec[n];  else: v = acc + bias[n]
// ---------------------------------------------------------------------------
template<bool RELU_C>
__global__ __launch_bounds__(256, 2)
void gemm_nt(const float* __restrict__ A, int lda,
             const float* __restrict__ Bm,      // (N,K) row-major
             const float* __restrict__ bias,    // (N)
             const float* __restrict__ cvec,    // (N) or null
             float* __restrict__ C, int ldc,
             int K) {
    constexpr int BM = 128, BN = 128, BK = 16;
    __shared__ float As[BK][BM];
    __shared__ float Bs[BK][BN];
    const int tid = threadIdx.x;
    const int lr = tid >> 2;          // 0..63
    const int lc = (tid & 3) << 2;    // 0,4,8,12
    const int tx = tid & 15, ty = tid >> 4;
    const float* Ab = A  + (size_t)blockIdx.y * BM * lda;
    const float* Bb = Bm + (size_t)blockIdx.x * BN * K;
    float acc[8][8] = {};

    for (int k0 = 0; k0 < K; k0 += BK) {
        float4 a0 = *(const float4*)&Ab[(size_t)lr        * lda + k0 + lc];
        float4 a1 = *(const float4*)&Ab[(size_t)(lr + 64) * lda + k0 + lc];
        float4 b0 = *(const float4*)&Bb[(size_t)lr        * K   + k0 + lc];
        float4 b1 = *(const float4*)&Bb[(size_t)(lr + 64) * K   + k0 + lc];
        __syncthreads();   // previous iteration's LDS reads complete
        As[lc + 0][lr] = a0.x; As[lc + 1][lr] = a0.y; As[lc + 2][lr] = a0.z; As[lc + 3][lr] = a0.w;
        As[lc + 0][lr + 64] = a1.x; As[lc + 1][lr + 64] = a1.y; As[lc + 2][lr + 64] = a1.z; As[lc + 3][lr + 64] = a1.w;
        Bs[lc + 0][lr] = b0.x; Bs[lc + 1][lr] = b0.y; Bs[lc + 2][lr] = b0.z; Bs[lc + 3][lr] = b0.w;
        Bs[lc + 0][lr + 64] = b1.x; Bs[lc + 1][lr + 64] = b1.y; Bs[lc + 2][lr + 64] = b1.z; Bs[lc + 3][lr + 64] = b1.w;
        __syncthreads();
#pragma unroll
        for (int kk = 0; kk < BK; ++kk) {
            float4 av0 = *(const float4*)&As[kk][ty * 8];
            float4 av1 = *(const float4*)&As[kk][ty * 8 + 4];
            float4 bv0 = *(const float4*)&Bs[kk][tx * 8];
            float4 bv1 = *(const float4*)&Bs[kk][tx * 8 + 4];
            float ar[8] = {av0.x, av0.y, av0.z, av0.w, av1.x, av1.y, av1.z, av1.w};
            float br[8] = {bv0.x, bv0.y, bv0.z, bv0.w, bv1.x, bv1.y, bv1.z, bv1.w};
#pragma unroll
            for (int i = 0; i < 8; ++i)
#pragma unroll
                for (int j = 0; j < 8; ++j)
                    acc[i][j] = fmaf(ar[i], br[j], acc[i][j]);
        }
    }

    const int m0 = blockIdx.y * BM + ty * 8;
    const int n0 = blockIdx.x * BN + tx * 8;
    float bs[8], cs[8];
#pragma unroll
    for (int j = 0; j < 8; ++j) {
        bs[j] = bias[n0 + j];
        cs[j] = RELU_C ? cvec[n0 + j] : 0.f;
    }
#pragma unroll
    for (int i = 0; i < 8; ++i) {
        float o[8];
#pragma unroll
        for (int j = 0; j < 8; ++j) {
            float v = acc[i][j] + bs[j];
            if (RELU_C) v = fmaxf(v, 0.f) + cs[j];
            o[j] = v;
        }
        float* cp = &C[(size_t)(m0 + i) * ldc + n0];
        *(float4*)cp       = make_float4(o[0], o[1], o[2], o[3]);
        *(float4*)(cp + 4) = make_float4(o[4], o[5], o[6], o[7]);
    }
}

// ---------------------------------------------------------------------------
// In-place LayerNorm over width 1024, row stride ZLD. 256 threads = 1 row.
// Two-pass (mean, then centered var) to match the reference numerics.
// ---------------------------------------------------------------------------
__global__ void ln_stage(float* __restrict__ z,
                         const float* __restrict__ g,
                         const float* __restrict__ bb) {
    __shared__ float sm[4];
    const int t = threadIdx.x;
    float* p = z + (size_t)blockIdx.x * ZLD;
    float4 v = *(const float4*)&p[t * 4];
    float s = v.x + v.y + v.z + v.w;
#pragma unroll
    for (int o = 1; o < 64; o <<= 1) s += __shfl_xor(s, o, 64);
    const int lane = t & 63, w = t >> 6;
    if (lane == 0) sm[w] = s;
    __syncthreads();
    const float mean = (sm[0] + sm[1] + sm[2] + sm[3]) * (1.f / Dv);
    const float d0 = v.x - mean, d1 = v.y - mean, d2 = v.z - mean, d3 = v.w - mean;
    float q = d0 * d0 + d1 * d1 + d2 * d2 + d3 * d3;
#pragma unroll
    for (int o = 1; o < 64; o <<= 1) q += __shfl_xor(q, o, 64);
    __syncthreads();
    if (lane == 0) sm[w] = q;
    __syncthreads();
    const float var = (sm[0] + sm[1] + sm[2] + sm[3]) * (1.f / Dv);
    const float r = rsqrtf(var + EPS);
    const float4 gg = *(const float4*)&g[t * 4];
    const float4 bv = *(const float4*)&bb[t * 4];
    float4 o;
    o.x = d0 * r * gg.x + bv.x;
    o.y = d1 * r * gg.y + bv.y;
    o.z = d2 * r * gg.z + bv.z;
    o.w = d3 * r * gg.w + bv.w;
    *(float4*)&p[t * 4] = o;
}

// ---------------------------------------------------------------------------
// In-place LayerNorm (width 256) + sigmoid on d_out. 1 wave per row, 4 rows/block.
// ---------------------------------------------------------------------------
__global__ void ln_sig(float* __restrict__ y,
                       const float* __restrict__ g,
                       const float* __restrict__ bb) {
    const int lane = threadIdx.x & 63;
    const int row = blockIdx.x * 4 + (threadIdx.x >> 6);
    float* p = y + (size_t)row * OUTv;
    float4 v = *(const float4*)&p[lane * 4];
    float s = v.x + v.y + v.z + v.w;
#pragma unroll
    for (int o = 1; o < 64; o <<= 1) s += __shfl_xor(s, o, 64);
    const float mean = s * (1.f / OUTv);
    const float d0 = v.x - mean, d1 = v.y - mean, d2 = v.z - mean, d3 = v.w - mean;
    float q = d0 * d0 + d1 * d1 + d2 * d2 + d3 * d3;
#pragma unroll
    for (int o = 1; o < 64; o <<= 1) q += __shfl_xor(q, o, 64);
    const float r = rsqrtf(q * (1.f / OUTv) + EPS);
    const float4 gg = *(const float4*)&g[lane * 4];
    const float4 bv = *(const float4*)&bb[lane * 4];
    float4 o;
    float t0 = d0 * r * gg.x + bv.x;
    float t1 = d1 * r * gg.y + bv.y;
    float t2 = d2 * r * gg.z + bv.z;
    float t3 = d3 * r * gg.w + bv.w;
    o.x = 1.f / (1.f + expf(-t0));
    o.y = 1.f / (1.f + expf(-t1));
    o.z = 1.f / (1.f + expf(-t2));
    o.w = 1.f / (1.f + expf(-t3));
    *(float4*)&p[lane * 4] = o;
}

// ---------------------------------------------------------------------------
extern "C" void kernel_launch(void* const* d_in, const int* in_sizes, int n_in,
                              void* d_out, int out_size, void* d_ws, size_t ws_size,
                              hipStream_t stream) {
    const float* x      = (const float*)d_in[0];
    const float* W      = (const float*)d_in[1];
    const float* b      = (const float*)d_in[2];
    // d_in[3] = Wq, d_in[4] = keys : dead code (softmax row-sums are 1)
    const float* values = (const float*)d_in[5];
    const float* Wout   = (const float*)d_in[6];
    const float* ln_g   = (const float*)d_in[7];
    const float* ln_b   = (const float*)d_in[8];
    const float* Wf     = (const float*)d_in[9];
    const float* bf     = (const float*)d_in[10];
    const float* lnf_g  = (const float*)d_in[11];
    const float* lnf_b  = (const float*)d_in[12];
    float* out = (float*)d_out;

    float* zbuf = (float*)d_ws;                      // (B, 3072) concat buffer
    float* cvec = zbuf + (size_t)Bv * ZLD;           // (L, 1024) constant mem vectors

    prep_kernel<<<Lv, 256, 0, stream>>>(values, Wout, cvec);

    for (int i = 0; i < Lv; ++i) {
        const float* Ain = (i == 0) ? x : (zbuf + (size_t)(i - 1) * Dv);
        const int lda = (i == 0) ? Dv : ZLD;
        dim3 grid(Dv / 128, Bv / 128);
        gemm_nt<true><<<grid, 256, 0, stream>>>(
            Ain, lda, W + (size_t)i * Dv * Dv, b + (size_t)i * Dv,
            cvec + (size_t)i * Dv, zbuf + (size_t)i * Dv, ZLD, Dv);
        ln_stage<<<Bv, 256, 0, stream>>>(zbuf + (size_t)i * Dv,
                                         ln_g + (size_t)i * Dv, ln_b + (size_t)i * Dv);
    }

    dim3 gridf(OUTv / 128, Bv / 128);
    gemm_nt<false><<<gridf, 256, 0, stream>>>(zbuf, ZLD, Wf, bf, nullptr, out, OUTv, ZLD);
    ln_sig<<<Bv / 4, 256, 0, stream>>>(out, lnf_g, lnf_b);
}

// Round 2
// 418.202 us; speedup vs baseline: 4.3574x; 4.3574x over previous
//
#include <hip/hip_runtime.h>
#include <math.h>

#define EPS 1e-5f

constexpr int Bv   = 16384;   // batch
constexpr int Dv   = 1024;    // hidden
constexpr int Lv   = 3;       // blocks
constexpr int NKVv = 128;
constexpr int Vv   = 256;
constexpr int OUTv = 256;
constexpr int ZLD  = Lv * Dv; // 3072 concat width (bf16 buffer row stride)

typedef short bf16x8 __attribute__((ext_vector_type(8)));
typedef float f32x4  __attribute__((ext_vector_type(4)));

using gas_t = __attribute__((address_space(1))) const void;
using las_t = __attribute__((address_space(3))) void;
#define GLD_LDS16(gp, lp) \
    __builtin_amdgcn_global_load_lds((gas_t*)(gp), (las_t*)(lp), 16, 0, 0)

// round-to-nearest-even f32 -> bf16 bits
static __device__ __forceinline__ ushort f2bf(float f) {
    unsigned u = __float_as_uint(f);
    u = (u + 0x7fffu + ((u >> 16) & 1u)) >> 16;
    return (ushort)u;
}

// ---------------------------------------------------------------------------
// cvec_i[d] = sum_k tile(values[i].mean(0))[k] * Wout[i][d][k]
// (softmax rows sum to exactly 1 -> attention == add constant vector)
// grid (4, L), 256 threads; thread owns one d.
// ---------------------------------------------------------------------------
__global__ void prep_kernel(const float* __restrict__ values,
                            const float* __restrict__ Wout,
                            float* __restrict__ cvec) {
    const int i = blockIdx.y;
    const int t = threadIdx.x;
    __shared__ float sv[1024];
    const float* vals = values + (size_t)i * NKVv * Vv;
    float s = 0.f;
    for (int n = 0; n < NKVv; ++n) s += vals[n * Vv + t];
    s *= (1.0f / NKVv);
    sv[t] = s; sv[t + 256] = s; sv[t + 512] = s; sv[t + 768] = s;
    __syncthreads();
    const int d = blockIdx.x * 256 + t;
    const float* row = Wout + (size_t)i * Dv * 1024 + (size_t)d * 1024;
    float a0 = 0.f, a1 = 0.f, a2 = 0.f, a3 = 0.f;
    for (int k = 0; k < 1024; k += 4) {
        a0 = fmaf(sv[k + 0], row[k + 0], a0);
        a1 = fmaf(sv[k + 1], row[k + 1], a1);
        a2 = fmaf(sv[k + 2], row[k + 2], a2);
        a3 = fmaf(sv[k + 3], row[k + 3], a3);
    }
    cvec[i * Dv + d] = (a0 + a1) + (a2 + a3);
}

// ---------------------------------------------------------------------------
// generic contiguous f32 -> bf16 convert, 8 elems/thread
// ---------------------------------------------------------------------------
__global__ void conv_bf16(const float* __restrict__ in, ushort* __restrict__ out, int n8) {
    const int t = blockIdx.x * 256 + threadIdx.x;
    if (t >= n8) return;
    const float4 v0 = *(const float4*)&in[t * 8];
    const float4 v1 = *(const float4*)&in[t * 8 + 4];
    ushort4 o0 = {f2bf(v0.x), f2bf(v0.y), f2bf(v0.z), f2bf(v0.w)};
    ushort4 o1 = {f2bf(v1.x), f2bf(v1.y), f2bf(v1.z), f2bf(v1.w)};
    *(ushort4*)&out[t * 8]     = o0;
    *(ushort4*)&out[t * 8 + 4] = o1;
}

// x (B,1024) f32 -> bf16 into zbuf[:, 2048:3072] (row stride ZLD)
__global__ void conv_x(const float* __restrict__ x, ushort* __restrict__ z) {
    const int t = blockIdx.x * 256 + threadIdx.x;  // B*128 threads
    const int row = t >> 7, c8 = (t & 127) << 3;
    const float4 v0 = *(const float4*)&x[(size_t)row * 1024 + c8];
    const float4 v1 = *(const float4*)&x[(size_t)row * 1024 + c8 + 4];
    ushort4 o0 = {f2bf(v0.x), f2bf(v0.y), f2bf(v0.z), f2bf(v0.w)};
    ushort4 o1 = {f2bf(v1.x), f2bf(v1.y), f2bf(v1.z), f2bf(v1.w)};
    ushort* p = z + (size_t)row * ZLD + 2048 + c8;
    *(ushort4*)p       = o0;
    *(ushort4*)(p + 4) = o1;
}

// ---------------------------------------------------------------------------
// bf16 MFMA NT GEMM (m97 structure): C = A @ Bw^T (+epilogue), f32 out.
// A: (M,K) bf16 row-major, lda elems. Bw: (N,K) bf16 row-major.
// 128x128 tile, BK=32, 256 threads = 4 waves (2x2), 4x4 frags of 16x16x32.
// RELU_C: v = relu(acc+bias[n]) + cvec[n]; else v = acc+bias[n].
// ---------------------------------------------------------------------------
template<bool RELU_C>
__global__ __launch_bounds__(256)
void gemm_bf16(const ushort* __restrict__ A, int lda,
               const ushort* __restrict__ Bw,
               const float* __restrict__ bias,
               const float* __restrict__ cvec,
               float* __restrict__ C, int ldc,
               int K) {
    __shared__ ushort As[128 * 32];
    __shared__ ushort Bs[128 * 32];
    const int tid  = threadIdx.x;
    const int lane = tid & 63;
    const int w    = tid >> 6;       // wave 0..3
    const int wr   = w >> 1, wc = w & 1;
    const int m0 = blockIdx.y * 128;
    const int n0 = blockIdx.x * 128;

    // staging geometry: wave w covers tile rows [32w, 32w+32), 2 instrs each of A,B.
    // gl_lds writes LDS linearly: base + lane*16B -> row 16j+(lane>>2), col 8*(lane&3).
    const int srow = (w << 5) + (lane >> 2);
    const int scol = (lane & 3) << 3;
    const ushort* gA = A  + (size_t)(m0 + srow) * lda + scol;
    const ushort* gB = Bw + (size_t)(n0 + srow) * K   + scol;
    ushort* lA0 = &As[(2 * w)     * 512];
    ushort* lA1 = &As[(2 * w + 1) * 512];
    ushort* lB0 = &Bs[(2 * w)     * 512];
    ushort* lB1 = &Bs[(2 * w + 1) * 512];

    f32x4 acc[4][4] = {};

    // MFMA fragment addressing (A: row=lane&15, k=(lane>>4)*8)
    const int frow = lane & 15;
    const int fcol = (lane >> 4) << 3;
    const int arow = wr * 64 + frow;
    const int brow = wc * 64 + frow;

    for (int k0 = 0; k0 < K; k0 += 32) {
        GLD_LDS16(gA + k0,                 lA0);
        GLD_LDS16(gA + k0 + 16 * lda,      lA1);
        GLD_LDS16(gB + k0,                 lB0);
        GLD_LDS16(gB + k0 + (size_t)16 * K, lB1);
        __syncthreads();   // staging complete (compiler drains vmcnt before barrier)
        bf16x8 af[4], bfr[4];
#pragma unroll
        for (int mf = 0; mf < 4; ++mf)
            af[mf] = *(const bf16x8*)&As[(arow + mf * 16) * 32 + fcol];
#pragma unroll
        for (int nf = 0; nf < 4; ++nf)
            bfr[nf] = *(const bf16x8*)&Bs[(brow + nf * 16) * 32 + fcol];
#pragma unroll
        for (int mf = 0; mf < 4; ++mf)
#pragma unroll
            for (int nf = 0; nf < 4; ++nf)
                acc[mf][nf] = __builtin_amdgcn_mfma_f32_16x16x32_bf16(
                    af[mf], bfr[nf], acc[mf][nf], 0, 0, 0);
        __syncthreads();   // all waves done reading before next stage overwrites
    }

    // epilogue: C/D layout col = lane&15, row = (lane>>4)*4 + r  [m89-verified]
    const int crow0 = m0 + wr * 64 + ((lane >> 4) << 2);
    const int ccol0 = n0 + wc * 64 + (lane & 15);
#pragma unroll
    for (int nf = 0; nf < 4; ++nf) {
        const int col = ccol0 + nf * 16;
        const float bsv = bias[col];
        const float csv = RELU_C ? cvec[col] : 0.f;
#pragma unroll
        for (int mf = 0; mf < 4; ++mf) {
#pragma unroll
            for (int r = 0; r < 4; ++r) {
                float v = acc[mf][nf][r] + bsv;
                if (RELU_C) v = fmaxf(v, 0.f) + csv;
                C[(size_t)(crow0 + mf * 16 + r) * ldc + col] = v;
            }
        }
    }
}

// ---------------------------------------------------------------------------
// LayerNorm over width 1024 reading f32 h (ld 1024), writing bf16 into zbuf
// column slot (row stride ZLD). 256 threads = 1 row, two-pass (ref numerics).
// ---------------------------------------------------------------------------
__global__ void ln_store(const float* __restrict__ h,
                         const float* __restrict__ g,
                         const float* __restrict__ bb,
                         ushort* __restrict__ z) {
    __shared__ float sm[4];
    const int t = threadIdx.x;
    const float* p = h + (size_t)blockIdx.x * 1024;
    float4 v = *(const float4*)&p[t * 4];
    float s = v.x + v.y + v.z + v.w;
#pragma unroll
    for (int o = 1; o < 64; o <<= 1) s += __shfl_xor(s, o, 64);
    const int lane = t & 63, wv = t >> 6;
    if (lane == 0) sm[wv] = s;
    __syncthreads();
    const float mean = (sm[0] + sm[1] + sm[2] + sm[3]) * (1.f / Dv);
    const float d0 = v.x - mean, d1 = v.y - mean, d2 = v.z - mean, d3 = v.w - mean;
    float q = d0 * d0 + d1 * d1 + d2 * d2 + d3 * d3;
#pragma unroll
    for (int o = 1; o < 64; o <<= 1) q += __shfl_xor(q, o, 64);
    __syncthreads();
    if (lane == 0) sm[wv] = q;
    __syncthreads();
    const float var = (sm[0] + sm[1] + sm[2] + sm[3]) * (1.f / Dv);
    const float r = rsqrtf(var + EPS);
    const float4 gg = *(const float4*)&g[t * 4];
    const float4 bv = *(const float4*)&bb[t * 4];
    ushort4 o;
    o.x = f2bf(d0 * r * gg.x + bv.x);
    o.y = f2bf(d1 * r * gg.y + bv.y);
    o.z = f2bf(d2 * r * gg.z + bv.z);
    o.w = f2bf(d3 * r * gg.w + bv.w);
    *(ushort4*)&z[(size_t)blockIdx.x * ZLD + t * 4] = o;
}

// ---------------------------------------------------------------------------
// In-place LayerNorm (width 256) + sigmoid on d_out (f32). 4 rows/block.
// ---------------------------------------------------------------------------
__global__ void ln_sig(float* __restrict__ y,
                       const float* __restrict__ g,
                       const float* __restrict__ bb) {
    const int lane = threadIdx.x & 63;
    const int row = blockIdx.x * 4 + (threadIdx.x >> 6);
    float* p = y + (size_t)row * OUTv;
    float4 v = *(const float4*)&p[lane * 4];
    float s = v.x + v.y + v.z + v.w;
#pragma unroll
    for (int o = 1; o < 64; o <<= 1) s += __shfl_xor(s, o, 64);
    const float mean = s * (1.f / OUTv);
    const float d0 = v.x - mean, d1 = v.y - mean, d2 = v.z - mean, d3 = v.w - mean;
    float q = d0 * d0 + d1 * d1 + d2 * d2 + d3 * d3;
#pragma unroll
    for (int o = 1; o < 64; o <<= 1) q += __shfl_xor(q, o, 64);
    const float r = rsqrtf(q * (1.f / OUTv) + EPS);
    const float4 gg = *(const float4*)&g[lane * 4];
    const float4 bv = *(const float4*)&bb[lane * 4];
    float4 o;
    const float t0 = d0 * r * gg.x + bv.x;
    const float t1 = d1 * r * gg.y + bv.y;
    const float t2 = d2 * r * gg.z + bv.z;
    const float t3 = d3 * r * gg.w + bv.w;
    o.x = 1.f / (1.f + expf(-t0));
    o.y = 1.f / (1.f + expf(-t1));
    o.z = 1.f / (1.f + expf(-t2));
    o.w = 1.f / (1.f + expf(-t3));
    *(float4*)&p[lane * 4] = o;
}

// ---------------------------------------------------------------------------
extern "C" void kernel_launch(void* const* d_in, const int* in_sizes, int n_in,
                              void* d_out, int out_size, void* d_ws, size_t ws_size,
                              hipStream_t stream) {
    const float* x      = (const float*)d_in[0];
    const float* W      = (const float*)d_in[1];
    const float* b      = (const float*)d_in[2];
    // d_in[3] = Wq, d_in[4] = keys : dead code (softmax row-sums are 1)
    const float* values = (const float*)d_in[5];
    const float* Wout   = (const float*)d_in[6];
    const float* ln_g   = (const float*)d_in[7];
    const float* ln_b   = (const float*)d_in[8];
    const float* Wf     = (const float*)d_in[9];
    const float* bf     = (const float*)d_in[10];
    const float* lnf_g  = (const float*)d_in[11];
    const float* lnf_b  = (const float*)d_in[12];
    float* out = (float*)d_out;

    // workspace layout (all 256B-aligned):
    char* ws = (char*)d_ws;
    ushort* zbuf = (ushort*)ws;                                  // (B,3072) bf16: LN outs + xb in cols[2048:)
    ws += (size_t)Bv * ZLD * sizeof(ushort);                     // 100.7 MB
    float* hbuf = (float*)ws;                                    // (B,1024) f32 pre-LN
    ws += (size_t)Bv * Dv * sizeof(float);                       // 67.1 MB
    ushort* Wb = (ushort*)ws;                                    // (L,1024,1024) bf16
    ws += (size_t)Lv * Dv * Dv * sizeof(ushort);                 // 6.3 MB
    ushort* Wfb = (ushort*)ws;                                   // (256,3072) bf16
    ws += (size_t)OUTv * ZLD * sizeof(ushort);                   // 1.6 MB
    float* cvec = (float*)ws;                                    // (L,1024) f32

    // prep: weight converts, x convert, constant vectors
    {
        const int nW = Lv * Dv * Dv / 8;
        conv_bf16<<<(nW + 255) / 256, 256, 0, stream>>>(W, Wb, nW);
        const int nF = OUTv * ZLD / 8;
        conv_bf16<<<(nF + 255) / 256, 256, 0, stream>>>(Wf, Wfb, nF);
        conv_x<<<Bv * 128 / 256, 256, 0, stream>>>(x, zbuf);
        prep_kernel<<<dim3(4, Lv), 256, 0, stream>>>(values, Wout, cvec);
    }

    for (int i = 0; i < Lv; ++i) {
        const ushort* Ain = (i == 0) ? (zbuf + 2048) : (zbuf + (size_t)(i - 1) * Dv);
        dim3 grid(Dv / 128, Bv / 128);
        gemm_bf16<true><<<grid, 256, 0, stream>>>(
            Ain, ZLD, Wb + (size_t)i * Dv * Dv, b + (size_t)i * Dv,
            cvec + (size_t)i * Dv, hbuf, Dv, Dv);
        ln_store<<<Bv, 256, 0, stream>>>(hbuf, ln_g + (size_t)i * Dv,
                                         ln_b + (size_t)i * Dv,
                                         zbuf + (size_t)i * Dv);
    }

    dim3 gridf(OUTv / 128, Bv / 128);
    gemm_bf16<false><<<gridf, 256, 0, stream>>>(zbuf, ZLD, Wfb, bf, nullptr,
                                                out, OUTv, ZLD);
    ln_sig<<<Bv / 4, 256, 0, stream>>>(out, lnf_g, lnf_b);
}

// Round 3
// 364.957 us; speedup vs baseline: 4.9932x; 1.1459x over previous
//
#include <hip/hip_runtime.h>
#include <math.h>

#define EPS 1e-5f

constexpr int Bv   = 16384;   // batch
constexpr int Dv   = 1024;    // hidden
constexpr int Lv   = 3;       // blocks
constexpr int NKVv = 128;
constexpr int Vv   = 256;
constexpr int OUTv = 256;
constexpr int ZLD  = Lv * Dv; // 3072 concat width (bf16 buffer row stride)

typedef short bf16x8 __attribute__((ext_vector_type(8)));
typedef float f32x4  __attribute__((ext_vector_type(4)));

using gas_t = __attribute__((address_space(1))) const void;
using las_t = __attribute__((address_space(3))) void;
#define GLD_LDS16(gp, lp) \
    __builtin_amdgcn_global_load_lds((gas_t*)(gp), (las_t*)(lp), 16, 0, 0)

// round-to-nearest-even f32 -> bf16 bits
static __device__ __forceinline__ ushort f2bf(float f) {
    unsigned u = __float_as_uint(f);
    u = (u + 0x7fffu + ((u >> 16) & 1u)) >> 16;
    return (ushort)u;
}

// ---------------------------------------------------------------------------
// cvec_i[d] = sum_k tile(values[i].mean(0))[k] * Wout[i][d][k]
// (softmax rows sum to exactly 1 -> attention == add constant vector)
// ---------------------------------------------------------------------------
__global__ void prep_kernel(const float* __restrict__ values,
                            const float* __restrict__ Wout,
                            float* __restrict__ cvec) {
    const int i = blockIdx.y;
    const int t = threadIdx.x;
    __shared__ float sv[1024];
    const float* vals = values + (size_t)i * NKVv * Vv;
    float s = 0.f;
    for (int n = 0; n < NKVv; ++n) s += vals[n * Vv + t];
    s *= (1.0f / NKVv);
    sv[t] = s; sv[t + 256] = s; sv[t + 512] = s; sv[t + 768] = s;
    __syncthreads();
    const int d = blockIdx.x * 256 + t;
    const float* row = Wout + (size_t)i * Dv * 1024 + (size_t)d * 1024;
    float a0 = 0.f, a1 = 0.f, a2 = 0.f, a3 = 0.f;
    for (int k = 0; k < 1024; k += 4) {
        a0 = fmaf(sv[k + 0], row[k + 0], a0);
        a1 = fmaf(sv[k + 1], row[k + 1], a1);
        a2 = fmaf(sv[k + 2], row[k + 2], a2);
        a3 = fmaf(sv[k + 3], row[k + 3], a3);
    }
    cvec[i * Dv + d] = (a0 + a1) + (a2 + a3);
}

// ---------------------------------------------------------------------------
// generic contiguous f32 -> bf16 convert, 8 elems/thread
// ---------------------------------------------------------------------------
__global__ void conv_bf16(const float* __restrict__ in, ushort* __restrict__ out, int n8) {
    const int t = blockIdx.x * 256 + threadIdx.x;
    if (t >= n8) return;
    const float4 v0 = *(const float4*)&in[t * 8];
    const float4 v1 = *(const float4*)&in[t * 8 + 4];
    ushort4 o0 = {f2bf(v0.x), f2bf(v0.y), f2bf(v0.z), f2bf(v0.w)};
    ushort4 o1 = {f2bf(v1.x), f2bf(v1.y), f2bf(v1.z), f2bf(v1.w)};
    *(ushort4*)&out[t * 8]     = o0;
    *(ushort4*)&out[t * 8 + 4] = o1;
}

// x (B,1024) f32 -> bf16 into zbuf[:, 2048:3072] (row stride ZLD)
__global__ void conv_x(const float* __restrict__ x, ushort* __restrict__ z) {
    const int t = blockIdx.x * 256 + threadIdx.x;  // B*128 threads
    const int row = t >> 7, c8 = (t & 127) << 3;
    const float4 v0 = *(const float4*)&x[(size_t)row * 1024 + c8];
    const float4 v1 = *(const float4*)&x[(size_t)row * 1024 + c8 + 4];
    ushort4 o0 = {f2bf(v0.x), f2bf(v0.y), f2bf(v0.z), f2bf(v0.w)};
    ushort4 o1 = {f2bf(v1.x), f2bf(v1.y), f2bf(v1.z), f2bf(v1.w)};
    ushort* p = z + (size_t)row * ZLD + 2048 + c8;
    *(ushort4*)p       = o0;
    *(ushort4*)(p + 4) = o1;
}

// ---------------------------------------------------------------------------
// bf16 MFMA NT GEMM, 3-deep counted-vmcnt pipeline (T3/T4 min template +
// T5 setprio + T1 XCD swizzle). C = A @ Bw^T (+epilogue), f32 out.
// 128x128 tile, BK=32, 4 waves (2x2), 4x4 frags of 16x16x32.
// Main-loop sync: stage tile t+2 at top; s_waitcnt vmcnt(4) AFTER the MFMA
// cluster (tile t+1 landed, t+2 still in flight); raw s_barrier. Never
// drains vmcnt to 0 until the tail.
// ---------------------------------------------------------------------------
template<bool RELU_C>
__global__ __launch_bounds__(256)
void gemm_bf16(const ushort* __restrict__ A, int lda,
               const ushort* __restrict__ Bw,
               const float* __restrict__ bias,
               const float* __restrict__ cvec,
               float* __restrict__ C, int ldc,
               int K, int qchunk, int bxmask, int bxshift) {
    __shared__ ushort As[3 * 4096];   // 3 buffers x (128 rows x 32 cols)
    __shared__ ushort Bs[3 * 4096];
    const int tid  = threadIdx.x;
    const int lane = tid & 63;
    const int w    = tid >> 6;       // wave 0..3
    const int wr   = w >> 1, wc = w & 1;

    // T1: XCD-chunked block swizzle (bijective: nwg % 8 == 0 for all our grids)
    const int wg  = blockIdx.x;
    const int swz = (wg & 7) * qchunk + (wg >> 3);
    const int bx  = swz & bxmask;
    const int by  = swz >> bxshift;
    const int m0  = by * 128;
    const int n0  = bx * 128;

    // staging geometry: wave w covers tile rows [32w, 32w+32), 16 rows/instr.
    const int srow = (w << 5) + (lane >> 2);
    const int scol = (lane & 3) << 3;
    const ushort* gA = A  + (size_t)(m0 + srow) * lda + scol;
    const ushort* gB = Bw + (size_t)(n0 + srow) * K   + scol;
    const int lofs = w << 10;        // wave chunk: 2 instrs x 512 ushorts

    f32x4 acc[4][4] = {};

    const int frow = lane & 15;
    const int fcol = (lane >> 4) << 3;
    const int arow = wr * 64 + frow;
    const int brow = wc * 64 + frow;

    auto STAGE = [&](int kt, int bi) {
        const int k0 = kt << 5;
        ushort* lA = As + bi * 4096 + lofs;
        ushort* lB = Bs + bi * 4096 + lofs;
        GLD_LDS16(gA + k0,                    lA);
        GLD_LDS16(gA + k0 + (size_t)16 * lda, lA + 512);
        GLD_LDS16(gB + k0,                    lB);
        GLD_LDS16(gB + k0 + (size_t)16 * K,   lB + 512);
    };

    const int NT = K >> 5;
    STAGE(0, 0);
    STAGE(1, 1);
    asm volatile("s_waitcnt vmcnt(4)" ::: "memory");   // tile 0 landed
    __builtin_amdgcn_s_barrier();

    int bc = 0, bs = 2;
    for (int t = 0; t < NT; ++t) {
        if (t + 2 < NT) STAGE(t + 2, bs);   // buffer bs last read at iter t-1 (pre-barrier)
        const ushort* AsC = As + bc * 4096;
        const ushort* BsC = Bs + bc * 4096;
        bf16x8 af[4], bfr[4];
#pragma unroll
        for (int mf = 0; mf < 4; ++mf)
            af[mf] = *(const bf16x8*)&AsC[(arow + mf * 16) * 32 + fcol];
#pragma unroll
        for (int nf = 0; nf < 4; ++nf)
            bfr[nf] = *(const bf16x8*)&BsC[(brow + nf * 16) * 32 + fcol];
        __builtin_amdgcn_s_setprio(1);
#pragma unroll
        for (int mf = 0; mf < 4; ++mf)
#pragma unroll
            for (int nf = 0; nf < 4; ++nf)
                acc[mf][nf] = __builtin_amdgcn_mfma_f32_16x16x32_bf16(
                    af[mf], bfr[nf], acc[mf][nf], 0, 0, 0);
        __builtin_amdgcn_s_setprio(0);
        // tile t+1 must be resident before anyone reads it next iter;
        // tile t+2 (4 loads) may stay in flight across the barrier.
        if (t + 2 < NT) asm volatile("s_waitcnt vmcnt(4)" ::: "memory");
        else            asm volatile("s_waitcnt vmcnt(0)" ::: "memory");
        __builtin_amdgcn_s_barrier();
        bc = (bc == 2) ? 0 : bc + 1;
        bs = (bs == 2) ? 0 : bs + 1;
    }

    // epilogue: C/D layout col = lane&15, row = (lane>>4)*4 + r  [m89-verified]
    const int crow0 = m0 + wr * 64 + ((lane >> 4) << 2);
    const int ccol0 = n0 + wc * 64 + (lane & 15);
#pragma unroll
    for (int nf = 0; nf < 4; ++nf) {
        const int col = ccol0 + nf * 16;
        const float bsv = bias[col];
        const float csv = RELU_C ? cvec[col] : 0.f;
#pragma unroll
        for (int mf = 0; mf < 4; ++mf) {
#pragma unroll
            for (int r = 0; r < 4; ++r) {
                float v = acc[mf][nf][r] + bsv;
                if (RELU_C) v = fmaxf(v, 0.f) + csv;
                C[(size_t)(crow0 + mf * 16 + r) * ldc + col] = v;
            }
        }
    }
}

// ---------------------------------------------------------------------------
// LayerNorm over width 1024 reading f32 h (ld 1024), writing bf16 into zbuf
// column slot (row stride ZLD). 256 threads = 1 row, two-pass (ref numerics).
// ---------------------------------------------------------------------------
__global__ void ln_store(const float* __restrict__ h,
                         const float* __restrict__ g,
                         const float* __restrict__ bb,
                         ushort* __restrict__ z) {
    __shared__ float sm[4];
    const int t = threadIdx.x;
    const float* p = h + (size_t)blockIdx.x * 1024;
    float4 v = *(const float4*)&p[t * 4];
    float s = v.x + v.y + v.z + v.w;
#pragma unroll
    for (int o = 1; o < 64; o <<= 1) s += __shfl_xor(s, o, 64);
    const int lane = t & 63, wv = t >> 6;
    if (lane == 0) sm[wv] = s;
    __syncthreads();
    const float mean = (sm[0] + sm[1] + sm[2] + sm[3]) * (1.f / Dv);
    const float d0 = v.x - mean, d1 = v.y - mean, d2 = v.z - mean, d3 = v.w - mean;
    float q = d0 * d0 + d1 * d1 + d2 * d2 + d3 * d3;
#pragma unroll
    for (int o = 1; o < 64; o <<= 1) q += __shfl_xor(q, o, 64);
    __syncthreads();
    if (lane == 0) sm[wv] = q;
    __syncthreads();
    const float var = (sm[0] + sm[1] + sm[2] + sm[3]) * (1.f / Dv);
    const float r = rsqrtf(var + EPS);
    const float4 gg = *(const float4*)&g[t * 4];
    const float4 bv = *(const float4*)&bb[t * 4];
    ushort4 o;
    o.x = f2bf(d0 * r * gg.x + bv.x);
    o.y = f2bf(d1 * r * gg.y + bv.y);
    o.z = f2bf(d2 * r * gg.z + bv.z);
    o.w = f2bf(d3 * r * gg.w + bv.w);
    *(ushort4*)&z[(size_t)blockIdx.x * ZLD + t * 4] = o;
}

// ---------------------------------------------------------------------------
// In-place LayerNorm (width 256) + sigmoid on d_out (f32). 4 rows/block.
// ---------------------------------------------------------------------------
__global__ void ln_sig(float* __restrict__ y,
                       const float* __restrict__ g,
                       const float* __restrict__ bb) {
    const int lane = threadIdx.x & 63;
    const int row = blockIdx.x * 4 + (threadIdx.x >> 6);
    float* p = y + (size_t)row * OUTv;
    float4 v = *(const float4*)&p[lane * 4];
    float s = v.x + v.y + v.z + v.w;
#pragma unroll
    for (int o = 1; o < 64; o <<= 1) s += __shfl_xor(s, o, 64);
    const float mean = s * (1.f / OUTv);
    const float d0 = v.x - mean, d1 = v.y - mean, d2 = v.z - mean, d3 = v.w - mean;
    float q = d0 * d0 + d1 * d1 + d2 * d2 + d3 * d3;
#pragma unroll
    for (int o = 1; o < 64; o <<= 1) q += __shfl_xor(q, o, 64);
    const float r = rsqrtf(q * (1.f / OUTv) + EPS);
    const float4 gg = *(const float4*)&g[lane * 4];
    const float4 bv = *(const float4*)&bb[lane * 4];
    float4 o;
    const float t0 = d0 * r * gg.x + bv.x;
    const float t1 = d1 * r * gg.y + bv.y;
    const float t2 = d2 * r * gg.z + bv.z;
    const float t3 = d3 * r * gg.w + bv.w;
    o.x = 1.f / (1.f + expf(-t0));
    o.y = 1.f / (1.f + expf(-t1));
    o.z = 1.f / (1.f + expf(-t2));
    o.w = 1.f / (1.f + expf(-t3));
    *(float4*)&p[lane * 4] = o;
}

// ---------------------------------------------------------------------------
extern "C" void kernel_launch(void* const* d_in, const int* in_sizes, int n_in,
                              void* d_out, int out_size, void* d_ws, size_t ws_size,
                              hipStream_t stream) {
    const float* x      = (const float*)d_in[0];
    const float* W      = (const float*)d_in[1];
    const float* b      = (const float*)d_in[2];
    // d_in[3] = Wq, d_in[4] = keys : dead code (softmax row-sums are 1)
    const float* values = (const float*)d_in[5];
    const float* Wout   = (const float*)d_in[6];
    const float* ln_g   = (const float*)d_in[7];
    const float* ln_b   = (const float*)d_in[8];
    const float* Wf     = (const float*)d_in[9];
    const float* bf     = (const float*)d_in[10];
    const float* lnf_g  = (const float*)d_in[11];
    const float* lnf_b  = (const float*)d_in[12];
    float* out = (float*)d_out;

    // workspace layout (all 256B-aligned):
    char* ws = (char*)d_ws;
    ushort* zbuf = (ushort*)ws;                                  // (B,3072) bf16: LN outs + xb in cols[2048:)
    ws += (size_t)Bv * ZLD * sizeof(ushort);                     // 100.7 MB
    float* hbuf = (float*)ws;                                    // (B,1024) f32 pre-LN
    ws += (size_t)Bv * Dv * sizeof(float);                       // 67.1 MB
    ushort* Wb = (ushort*)ws;                                    // (L,1024,1024) bf16
    ws += (size_t)Lv * Dv * Dv * sizeof(ushort);                 // 6.3 MB
    ushort* Wfb = (ushort*)ws;                                   // (256,3072) bf16
    ws += (size_t)OUTv * ZLD * sizeof(ushort);                   // 1.6 MB
    float* cvec = (float*)ws;                                    // (L,1024) f32

    // prep: weight converts, x convert, constant vectors
    {
        const int nW = Lv * Dv * Dv / 8;
        conv_bf16<<<(nW + 255) / 256, 256, 0, stream>>>(W, Wb, nW);
        const int nF = OUTv * ZLD / 8;
        conv_bf16<<<(nF + 255) / 256, 256, 0, stream>>>(Wf, Wfb, nF);
        conv_x<<<Bv * 128 / 256, 256, 0, stream>>>(x, zbuf);
        prep_kernel<<<dim3(4, Lv), 256, 0, stream>>>(values, Wout, cvec);
    }

    // layer GEMMs: grid 8x128 = 1024 blocks; qchunk = 1024/8 = 128, bx bits = 3
    for (int i = 0; i < Lv; ++i) {
        const ushort* Ain = (i == 0) ? (zbuf + 2048) : (zbuf + (size_t)(i - 1) * Dv);
        gemm_bf16<true><<<dim3(1024), 256, 0, stream>>>(
            Ain, ZLD, Wb + (size_t)i * Dv * Dv, b + (size_t)i * Dv,
            cvec + (size_t)i * Dv, hbuf, Dv, Dv,
            /*qchunk=*/128, /*bxmask=*/7, /*bxshift=*/3);
        ln_store<<<Bv, 256, 0, stream>>>(hbuf, ln_g + (size_t)i * Dv,
                                         ln_b + (size_t)i * Dv,
                                         zbuf + (size_t)i * Dv);
    }

    // final GEMM: grid 2x128 = 256 blocks; qchunk = 256/8 = 32, bx bits = 1
    gemm_bf16<false><<<dim3(256), 256, 0, stream>>>(
        zbuf, ZLD, Wfb, bf, nullptr, out, OUTv, ZLD,
        /*qchunk=*/32, /*bxmask=*/1, /*bxshift=*/1);
    ln_sig<<<Bv / 4, 256, 0, stream>>>(out, lnf_g, lnf_b);
}

// Round 4
// 343.899 us; speedup vs baseline: 5.2989x; 1.0612x over previous
//
#include <hip/hip_runtime.h>
#include <math.h>

#define EPS 1e-5f

constexpr int Bv   = 16384;   // batch
constexpr int Dv   = 1024;    // hidden
constexpr int Lv   = 3;       // blocks
constexpr int NKVv = 128;
constexpr int Vv   = 256;
constexpr int OUTv = 256;
constexpr int ZLD  = Lv * Dv; // 3072 concat width (bf16 buffer row stride)

typedef short bf16x8 __attribute__((ext_vector_type(8)));
typedef float f32x4  __attribute__((ext_vector_type(4)));

using gas_t = __attribute__((address_space(1))) const void;
using las_t = __attribute__((address_space(3))) void;
#define GLD_LDS16(gp, lp) \
    __builtin_amdgcn_global_load_lds((gas_t*)(gp), (las_t*)(lp), 16, 0, 0)

// round-to-nearest-even f32 -> bf16 bits
static __device__ __forceinline__ ushort f2bf(float f) {
    unsigned u = __float_as_uint(f);
    u = (u + 0x7fffu + ((u >> 16) & 1u)) >> 16;
    return (ushort)u;
}

// ---------------------------------------------------------------------------
// cvec_i[d] = sum_k tile(values[i].mean(0))[k] * Wout[i][d][k]
// (softmax rows sum to exactly 1 -> attention == add constant vector)
// ---------------------------------------------------------------------------
__global__ void prep_kernel(const float* __restrict__ values,
                            const float* __restrict__ Wout,
                            float* __restrict__ cvec) {
    const int i = blockIdx.y;
    const int t = threadIdx.x;
    __shared__ float sv[1024];
    const float* vals = values + (size_t)i * NKVv * Vv;
    float s = 0.f;
    for (int n = 0; n < NKVv; ++n) s += vals[n * Vv + t];
    s *= (1.0f / NKVv);
    sv[t] = s; sv[t + 256] = s; sv[t + 512] = s; sv[t + 768] = s;
    __syncthreads();
    const int d = blockIdx.x * 256 + t;
    const float* row = Wout + (size_t)i * Dv * 1024 + (size_t)d * 1024;
    float a0 = 0.f, a1 = 0.f, a2 = 0.f, a3 = 0.f;
    for (int k = 0; k < 1024; k += 4) {
        a0 = fmaf(sv[k + 0], row[k + 0], a0);
        a1 = fmaf(sv[k + 1], row[k + 1], a1);
        a2 = fmaf(sv[k + 2], row[k + 2], a2);
        a3 = fmaf(sv[k + 3], row[k + 3], a3);
    }
    cvec[i * Dv + d] = (a0 + a1) + (a2 + a3);
}

// ---------------------------------------------------------------------------
// generic contiguous f32 -> bf16 convert, 8 elems/thread
// ---------------------------------------------------------------------------
__global__ void conv_bf16(const float* __restrict__ in, ushort* __restrict__ out, int n8) {
    const int t = blockIdx.x * 256 + threadIdx.x;
    if (t >= n8) return;
    const float4 v0 = *(const float4*)&in[t * 8];
    const float4 v1 = *(const float4*)&in[t * 8 + 4];
    ushort4 o0 = {f2bf(v0.x), f2bf(v0.y), f2bf(v0.z), f2bf(v0.w)};
    ushort4 o1 = {f2bf(v1.x), f2bf(v1.y), f2bf(v1.z), f2bf(v1.w)};
    *(ushort4*)&out[t * 8]     = o0;
    *(ushort4*)&out[t * 8 + 4] = o1;
}

// x (B,1024) f32 -> bf16 into zbuf[:, 2048:3072] (row stride ZLD)
__global__ void conv_x(const float* __restrict__ x, ushort* __restrict__ z) {
    const int t = blockIdx.x * 256 + threadIdx.x;  // B*128 threads
    const int row = t >> 7, c8 = (t & 127) << 3;
    const float4 v0 = *(const float4*)&x[(size_t)row * 1024 + c8];
    const float4 v1 = *(const float4*)&x[(size_t)row * 1024 + c8 + 4];
    ushort4 o0 = {f2bf(v0.x), f2bf(v0.y), f2bf(v0.z), f2bf(v0.w)};
    ushort4 o1 = {f2bf(v1.x), f2bf(v1.y), f2bf(v1.z), f2bf(v1.w)};
    ushort* p = z + (size_t)row * ZLD + 2048 + c8;
    *(ushort4*)p       = o0;
    *(ushort4*)(p + 4) = o1;
}

// ---------------------------------------------------------------------------
// 256x256 bf16 MFMA NT GEMM, 8 waves (2Mx4N), BK=32, 4-buffer counted-vmcnt
// pipeline (stage t+3, vmcnt(8)), XOR bank-deswizzle on LDS (both-sides:
// inverse-swizzled GLOBAL source chunk + swizzled READ chunk, linear LDS).
// MODE 0: layer GEMM, epilogue v = relu(acc+bias[n])+cvec[n] -> C (f32, ldc).
// MODE 1: split-K partial, raw acc -> C + bx*(Bv*256), n0=0, koff=bx*ksplit.
// Per-wave output 128x64 (8x4 frags of 16x16). Grid must be 256 blocks.
// ---------------------------------------------------------------------------
template<int MODE>
__global__ __launch_bounds__(512, 2)
void gemm256(const ushort* __restrict__ A, int lda,
             const ushort* __restrict__ Bw, int ldb,
             const float* __restrict__ bias,
             const float* __restrict__ cvec,
             float* __restrict__ C, int ldc,
             int NT, int ksplit) {
    __shared__ ushort As[4 * 8192];   // 4 buffers x (256 rows x 32 cols) = 64KB
    __shared__ ushort Bs[4 * 8192];   // 64KB
    const int tid  = threadIdx.x;
    const int lane = tid & 63;
    const int w    = tid >> 6;        // wave 0..7
    const int wr   = w >> 2, wc = w & 3;

    // XCD-chunked swizzle over the 256-block grid (1 block/CU)
    const int wg  = blockIdx.x;
    const int swz = (wg & 7) * 32 + (wg >> 3);
    const int by  = swz & 63;
    const int bx  = swz >> 6;
    const int m0  = by * 256;
    const int n0  = (MODE == 0) ? bx * 256 : 0;
    const int koff = (MODE == 0) ? 0 : bx * ksplit;

    // staging: wave w stages rows [32w, 32w+32) of A and B tiles.
    // LDS write is linear (base + lane*16B); bank-deswizzle is applied by
    // permuting the per-lane GLOBAL source chunk (rule 21: both-sides).
    const int srow = (w << 5) + (lane >> 2);
    const int scol = (((lane & 3) ^ ((lane >> 3) & 3)) << 3);  // inverse-swz source
    const ushort* gA = A  + (size_t)(m0 + srow) * lda + koff + scol;
    const ushort* gB = Bw + (size_t)(n0 + srow) * ldb + koff + scol;
    const int lofs = w << 10;          // ushort offset of wave's 32-row chunk

    f32x4 acc[8][4] = {};

    // fragment read addressing with matching swizzled chunk
    const int frow  = lane & 15;
    const int e     = (frow >> 1) & 3;
    const int rdcol = ((lane >> 4) ^ e) << 3;
    const int abase = (wr * 128 + frow) * 32 + rdcol;   // + mf*512 + buf*8192
    const int bbase = (wc * 64  + frow) * 32 + rdcol;   // + nf*512 + buf*8192

    auto STAGE = [&](int kt, int bi) {
        const int k0 = kt << 5;
        ushort* lA = As + (bi << 13) + lofs;
        ushort* lB = Bs + (bi << 13) + lofs;
        GLD_LDS16(gA + k0,                    lA);
        GLD_LDS16(gA + k0 + (size_t)16 * lda, lA + 512);
        GLD_LDS16(gB + k0,                    lB);
        GLD_LDS16(gB + k0 + (size_t)16 * ldb, lB + 512);
    };

    STAGE(0, 0); STAGE(1, 1); STAGE(2, 2);
    asm volatile("s_waitcnt vmcnt(8)" ::: "memory");   // tile 0 landed
    __builtin_amdgcn_s_barrier();

    for (int t = 0; t < NT; ++t) {
        if (t + 3 < NT) STAGE(t + 3, (t + 3) & 3);  // buf freed at barrier t-1
        const ushort* AsC = As + ((t & 3) << 13);
        const ushort* BsC = Bs + ((t & 3) << 13);
        bf16x8 bfr[4];
#pragma unroll
        for (int nf = 0; nf < 4; ++nf)
            bfr[nf] = *(const bf16x8*)&BsC[bbase + nf * 512];
        __builtin_amdgcn_s_setprio(1);
#pragma unroll
        for (int mf = 0; mf < 8; ++mf) {
            const bf16x8 af = *(const bf16x8*)&AsC[abase + mf * 512];
#pragma unroll
            for (int nf = 0; nf < 4; ++nf)
                acc[mf][nf] = __builtin_amdgcn_mfma_f32_16x16x32_bf16(
                    af, bfr[nf], acc[mf][nf], 0, 0, 0);
        }
        __builtin_amdgcn_s_setprio(0);
        // tile t+1 must be resident for next iter; tiles t+2,t+3 may fly.
        if (t + 3 < NT)      asm volatile("s_waitcnt vmcnt(8)" ::: "memory");
        else if (t + 2 < NT) asm volatile("s_waitcnt vmcnt(4)" ::: "memory");
        else                 asm volatile("s_waitcnt vmcnt(0)" ::: "memory");
        __builtin_amdgcn_s_barrier();
    }

    // epilogue: C/D layout col = lane&15, row = (lane>>4)*4 + r
    const int crow0 = m0 + wr * 128 + ((lane >> 4) << 2);
    const int ccol0 = n0 + wc * 64 + (lane & 15);
    float* Cb = (MODE == 0) ? C : (C + (size_t)bx * ((size_t)Bv * OUTv));
#pragma unroll
    for (int nf = 0; nf < 4; ++nf) {
        const int col = ccol0 + nf * 16;
        float bsv = 0.f, csv = 0.f;
        if (MODE == 0) { bsv = bias[col]; csv = cvec[col]; }
#pragma unroll
        for (int mf = 0; mf < 8; ++mf) {
#pragma unroll
            for (int r = 0; r < 4; ++r) {
                float v = acc[mf][nf][r];
                if (MODE == 0) v = fmaxf(v + bsv, 0.f) + csv;
                Cb[(size_t)(crow0 + mf * 16 + r) * ldc + col] = v;
            }
        }
    }
}

// ---------------------------------------------------------------------------
// LayerNorm over width 1024 reading f32 h (ld 1024), writing bf16 into zbuf
// column slot (row stride ZLD). 256 threads = 1 row, two-pass (ref numerics).
// ---------------------------------------------------------------------------
__global__ void ln_store(const float* __restrict__ h,
                         const float* __restrict__ g,
                         const float* __restrict__ bb,
                         ushort* __restrict__ z) {
    __shared__ float sm[4];
    const int t = threadIdx.x;
    const float* p = h + (size_t)blockIdx.x * 1024;
    float4 v = *(const float4*)&p[t * 4];
    float s = v.x + v.y + v.z + v.w;
#pragma unroll
    for (int o = 1; o < 64; o <<= 1) s += __shfl_xor(s, o, 64);
    const int lane = t & 63, wv = t >> 6;
    if (lane == 0) sm[wv] = s;
    __syncthreads();
    const float mean = (sm[0] + sm[1] + sm[2] + sm[3]) * (1.f / Dv);
    const float d0 = v.x - mean, d1 = v.y - mean, d2 = v.z - mean, d3 = v.w - mean;
    float q = d0 * d0 + d1 * d1 + d2 * d2 + d3 * d3;
#pragma unroll
    for (int o = 1; o < 64; o <<= 1) q += __shfl_xor(q, o, 64);
    __syncthreads();
    if (lane == 0) sm[wv] = q;
    __syncthreads();
    const float var = (sm[0] + sm[1] + sm[2] + sm[3]) * (1.f / Dv);
    const float r = rsqrtf(var + EPS);
    const float4 gg = *(const float4*)&g[t * 4];
    const float4 bv = *(const float4*)&bb[t * 4];
    ushort4 o;
    o.x = f2bf(d0 * r * gg.x + bv.x);
    o.y = f2bf(d1 * r * gg.y + bv.y);
    o.z = f2bf(d2 * r * gg.z + bv.z);
    o.w = f2bf(d3 * r * gg.w + bv.w);
    *(ushort4*)&z[(size_t)blockIdx.x * ZLD + t * 4] = o;
}

// ---------------------------------------------------------------------------
// Fused split-K reduce (+bias) + LayerNorm(256) + sigmoid -> d_out (f32).
// 4 rows/block, 1 wave per row, 4 cols/lane.
// ---------------------------------------------------------------------------
__global__ void ln_sig_reduce(const float* __restrict__ ps,
                              const float* __restrict__ bf_,
                              const float* __restrict__ g,
                              const float* __restrict__ bb,
                              float* __restrict__ y) {
    const int lane = threadIdx.x & 63;
    const int row  = blockIdx.x * 4 + (threadIdx.x >> 6);
    const size_t base = (size_t)row * OUTv + lane * 4;
    const size_t SP = (size_t)Bv * OUTv;
    const float4 s0 = *(const float4*)&ps[base];
    const float4 s1 = *(const float4*)&ps[base + SP];
    const float4 s2 = *(const float4*)&ps[base + 2 * SP];
    const float4 s3 = *(const float4*)&ps[base + 3 * SP];
    const float4 bv4 = *(const float4*)&bf_[lane * 4];
    const float v0 = (s0.x + s1.x) + (s2.x + s3.x) + bv4.x;
    const float v1 = (s0.y + s1.y) + (s2.y + s3.y) + bv4.y;
    const float v2 = (s0.z + s1.z) + (s2.z + s3.z) + bv4.z;
    const float v3 = (s0.w + s1.w) + (s2.w + s3.w) + bv4.w;
    float s = v0 + v1 + v2 + v3;
#pragma unroll
    for (int o = 1; o < 64; o <<= 1) s += __shfl_xor(s, o, 64);
    const float mean = s * (1.f / OUTv);
    const float d0 = v0 - mean, d1 = v1 - mean, d2 = v2 - mean, d3 = v3 - mean;
    float q = d0 * d0 + d1 * d1 + d2 * d2 + d3 * d3;
#pragma unroll
    for (int o = 1; o < 64; o <<= 1) q += __shfl_xor(q, o, 64);
    const float r = rsqrtf(q * (1.f / OUTv) + EPS);
    const float4 gg = *(const float4*)&g[lane * 4];
    const float4 bv = *(const float4*)&bb[lane * 4];
    float4 o;
    const float t0 = d0 * r * gg.x + bv.x;
    const float t1 = d1 * r * gg.y + bv.y;
    const float t2 = d2 * r * gg.z + bv.z;
    const float t3 = d3 * r * gg.w + bv.w;
    o.x = 1.f / (1.f + expf(-t0));
    o.y = 1.f / (1.f + expf(-t1));
    o.z = 1.f / (1.f + expf(-t2));
    o.w = 1.f / (1.f + expf(-t3));
    *(float4*)&y[base] = o;
}

// ---------------------------------------------------------------------------
extern "C" void kernel_launch(void* const* d_in, const int* in_sizes, int n_in,
                              void* d_out, int out_size, void* d_ws, size_t ws_size,
                              hipStream_t stream) {
    const float* x      = (const float*)d_in[0];
    const float* W      = (const float*)d_in[1];
    const float* b      = (const float*)d_in[2];
    // d_in[3] = Wq, d_in[4] = keys : dead code (softmax row-sums are 1)
    const float* values = (const float*)d_in[5];
    const float* Wout   = (const float*)d_in[6];
    const float* ln_g   = (const float*)d_in[7];
    const float* ln_b   = (const float*)d_in[8];
    const float* Wf     = (const float*)d_in[9];
    const float* bf     = (const float*)d_in[10];
    const float* lnf_g  = (const float*)d_in[11];
    const float* lnf_b  = (const float*)d_in[12];
    float* out = (float*)d_out;

    // workspace layout (same footprint as round 2/3, ~176 MB):
    char* ws = (char*)d_ws;
    ushort* zbuf = (ushort*)ws;                                  // (B,3072) bf16
    ws += (size_t)Bv * ZLD * sizeof(ushort);                     // 100.7 MB
    float* hbuf = (float*)ws;                                    // (B,1024) f32 pre-LN; reused as psum(4,B,256) for final split-K
    ws += (size_t)Bv * Dv * sizeof(float);                       // 67.1 MB
    ushort* Wb = (ushort*)ws;                                    // (L,1024,1024) bf16
    ws += (size_t)Lv * Dv * Dv * sizeof(ushort);                 // 6.3 MB
    ushort* Wfb = (ushort*)ws;                                   // (256,3072) bf16
    ws += (size_t)OUTv * ZLD * sizeof(ushort);                   // 1.6 MB
    float* cvec = (float*)ws;                                    // (L,1024) f32

    // prep: weight converts, x convert, constant vectors
    {
        const int nW = Lv * Dv * Dv / 8;
        conv_bf16<<<(nW + 255) / 256, 256, 0, stream>>>(W, Wb, nW);
        const int nF = OUTv * ZLD / 8;
        conv_bf16<<<(nF + 255) / 256, 256, 0, stream>>>(Wf, Wfb, nF);
        conv_x<<<Bv * 128 / 256, 256, 0, stream>>>(x, zbuf);
        prep_kernel<<<dim3(4, Lv), 256, 0, stream>>>(values, Wout, cvec);
    }

    // layer GEMMs: grid 256 blocks (64 m-tiles x 4 n-tiles), 1/CU, NT=32
    for (int i = 0; i < Lv; ++i) {
        const ushort* Ain = (i == 0) ? (zbuf + 2048) : (zbuf + (size_t)(i - 1) * Dv);
        gemm256<0><<<dim3(256), 512, 0, stream>>>(
            Ain, ZLD, Wb + (size_t)i * Dv * Dv, Dv,
            b + (size_t)i * Dv, cvec + (size_t)i * Dv,
            hbuf, Dv, /*NT=*/32, /*ksplit=*/0);
        ln_store<<<Bv, 256, 0, stream>>>(hbuf, ln_g + (size_t)i * Dv,
                                         ln_b + (size_t)i * Dv,
                                         zbuf + (size_t)i * Dv);
    }

    // final GEMM: split-K=4 (64 m-tiles x 4 splits = 256 blocks), K=768 each,
    // raw partials into psum (= hbuf, free after last ln_store)
    float* psum = hbuf;
    gemm256<1><<<dim3(256), 512, 0, stream>>>(
        zbuf, ZLD, Wfb, ZLD, nullptr, nullptr,
        psum, OUTv, /*NT=*/24, /*ksplit=*/768);

    ln_sig_reduce<<<Bv / 4, 256, 0, stream>>>(psum, bf, lnf_g, lnf_b, out);
}

// Round 5
// 309.154 us; speedup vs baseline: 5.8944x; 1.1124x over previous
//
#include <hip/hip_runtime.h>
#include <math.h>

#define EPS 1e-5f

constexpr int Bv   = 16384;   // batch
constexpr int Dv   = 1024;    // hidden
constexpr int Lv   = 3;       // blocks
constexpr int NKVv = 128;
constexpr int Vv   = 256;
constexpr int OUTv = 256;
constexpr int ZLD  = Lv * Dv; // 3072 concat width (bf16 buffer row stride)

typedef short bf16x8 __attribute__((ext_vector_type(8)));
typedef float f32x4  __attribute__((ext_vector_type(4)));

using gas_t = __attribute__((address_space(1))) const void;
using las_t = __attribute__((address_space(3))) void;
#define GLD_LDS16(gp, lp) \
    __builtin_amdgcn_global_load_lds((gas_t*)(gp), (las_t*)(lp), 16, 0, 0)

// round-to-nearest-even f32 -> bf16 bits
static __device__ __forceinline__ ushort f2bf(float f) {
    unsigned u = __float_as_uint(f);
    u = (u + 0x7fffu + ((u >> 16) & 1u)) >> 16;
    return (ushort)u;
}

// ---------------------------------------------------------------------------
// cvec_i[d] = sum_k tile(values[i].mean(0))[k] * Wout[i][d][k]
// (softmax rows sum to exactly 1 -> attention == add constant vector)
// ---------------------------------------------------------------------------
__global__ void prep_kernel(const float* __restrict__ values,
                            const float* __restrict__ Wout,
                            float* __restrict__ cvec) {
    const int i = blockIdx.y;
    const int t = threadIdx.x;
    __shared__ float sv[1024];
    const float* vals = values + (size_t)i * NKVv * Vv;
    float s = 0.f;
    for (int n = 0; n < NKVv; ++n) s += vals[n * Vv + t];
    s *= (1.0f / NKVv);
    sv[t] = s; sv[t + 256] = s; sv[t + 512] = s; sv[t + 768] = s;
    __syncthreads();
    const int d = blockIdx.x * 256 + t;
    const float* row = Wout + (size_t)i * Dv * 1024 + (size_t)d * 1024;
    float a0 = 0.f, a1 = 0.f, a2 = 0.f, a3 = 0.f;
    for (int k = 0; k < 1024; k += 4) {
        a0 = fmaf(sv[k + 0], row[k + 0], a0);
        a1 = fmaf(sv[k + 1], row[k + 1], a1);
        a2 = fmaf(sv[k + 2], row[k + 2], a2);
        a3 = fmaf(sv[k + 3], row[k + 3], a3);
    }
    cvec[i * Dv + d] = (a0 + a1) + (a2 + a3);
}

// ---------------------------------------------------------------------------
// generic contiguous f32 -> bf16 convert, 8 elems/thread
// ---------------------------------------------------------------------------
__global__ void conv_bf16(const float* __restrict__ in, ushort* __restrict__ out, int n8) {
    const int t = blockIdx.x * 256 + threadIdx.x;
    if (t >= n8) return;
    const float4 v0 = *(const float4*)&in[t * 8];
    const float4 v1 = *(const float4*)&in[t * 8 + 4];
    ushort4 o0 = {f2bf(v0.x), f2bf(v0.y), f2bf(v0.z), f2bf(v0.w)};
    ushort4 o1 = {f2bf(v1.x), f2bf(v1.y), f2bf(v1.z), f2bf(v1.w)};
    *(ushort4*)&out[t * 8]     = o0;
    *(ushort4*)&out[t * 8 + 4] = o1;
}

// x (B,1024) f32 -> bf16 into zbuf[:, 2048:3072] (row stride ZLD)
__global__ void conv_x(const float* __restrict__ x, ushort* __restrict__ z) {
    const int t = blockIdx.x * 256 + threadIdx.x;  // B*128 threads
    const int row = t >> 7, c8 = (t & 127) << 3;
    const float4 v0 = *(const float4*)&x[(size_t)row * 1024 + c8];
    const float4 v1 = *(const float4*)&x[(size_t)row * 1024 + c8 + 4];
    ushort4 o0 = {f2bf(v0.x), f2bf(v0.y), f2bf(v0.z), f2bf(v0.w)};
    ushort4 o1 = {f2bf(v1.x), f2bf(v1.y), f2bf(v1.z), f2bf(v1.w)};
    ushort* p = z + (size_t)row * ZLD + 2048 + c8;
    *(ushort4*)p       = o0;
    *(ushort4*)(p + 4) = o1;
}

// ---------------------------------------------------------------------------
// 256x256 bf16 MFMA NT GEMM — 8-phase (4 phases per BK=64 K-tile, block-level
// 128x128 C-quadrants), counted vmcnt (never 0 mid-loop), XOR bank-swizzle
// (linear LDS dest; inverse-swizzled global source; swizzled ds_read).
//
// LDS: As/Bs[2 dbuf][2 half][128 rows][64 cols] bf16 = 128 KiB total.
// Stage order per tile t (into buf t+1&1): ph0:A-h0 ph1:B-h0 ph2:B-h1 ph3:A-h1
// Quadrant order:  ph0:Q(0,0)  ph1:Q(0,1)  ph2:Q(1,1)  ph3:Q(1,0)
// Phase-start {vmcnt(4); s_barrier} == "all but newest 2 half-tiles resident"
// collectively. Tail tile uses vmcnt(2)/vmcnt(0). Hazard trace in comments.
//
// MODE 0: epilogue v = relu(acc+bias[n])+cvec[n] -> C (f32, ldc).
// MODE 1: split-K partial, raw acc -> C + bx*(Bv*256), n0=0, koff=bx*ksplit.
// Grid must be 256 blocks x 512 threads (8 waves, 2Mx4N per quadrant).
// ---------------------------------------------------------------------------
#define READ_A(QR, DD)                                                        \
    do { _Pragma("unroll")                                                    \
        for (int mf = 0; mf < 4; ++mf) {                                      \
            const int _o = (DD) * 16384 + (QR) * 8192 + (arow_l + mf * 16) * 64; \
            aR[mf][0] = *(const bf16x8*)&As[_o + ck0];                        \
            aR[mf][1] = *(const bf16x8*)&As[_o + ck1];                        \
        } } while (0)

#define READ_B(QC, DD, BR)                                                    \
    do { _Pragma("unroll")                                                    \
        for (int nf = 0; nf < 2; ++nf) {                                      \
            const int _o = (DD) * 16384 + (QC) * 8192 + (brow_l + nf * 16) * 64; \
            BR[nf][0] = *(const bf16x8*)&Bs[_o + ck0];                        \
            BR[nf][1] = *(const bf16x8*)&Bs[_o + ck1];                        \
        } } while (0)

#define STAGE_A(KT, H, DD)                                                    \
    do { const ushort* _p = gAs + (size_t)((H) * 128 + w16) * lda + (KT) * 64; \
         ushort* _l = (ushort*)As + (DD) * 16384 + (H) * 8192 + w16 * 64;     \
         GLD_LDS16(_p, _l);                                                   \
         GLD_LDS16(_p + (size_t)8 * lda, _l + 512); } while (0)

#define STAGE_B(KT, H, DD)                                                    \
    do { const ushort* _p = gBs + (size_t)((H) * 128 + w16) * ldb + (KT) * 64; \
         ushort* _l = (ushort*)Bs + (DD) * 16384 + (H) * 8192 + w16 * 64;     \
         GLD_LDS16(_p, _l);                                                   \
         GLD_LDS16(_p + (size_t)8 * ldb, _l + 512); } while (0)

#define MFMA_Q(QR, QC, BR)                                                    \
    do { __builtin_amdgcn_s_setprio(1);                                       \
        _Pragma("unroll")                                                     \
        for (int mf = 0; mf < 4; ++mf) {                                      \
            _Pragma("unroll")                                                 \
            for (int nf = 0; nf < 2; ++nf) {                                  \
                acc[QR][QC][mf][nf] = __builtin_amdgcn_mfma_f32_16x16x32_bf16( \
                    aR[mf][0], BR[nf][0], acc[QR][QC][mf][nf], 0, 0, 0);      \
                acc[QR][QC][mf][nf] = __builtin_amdgcn_mfma_f32_16x16x32_bf16( \
                    aR[mf][1], BR[nf][1], acc[QR][QC][mf][nf], 0, 0, 0);      \
            }                                                                 \
        }                                                                     \
        __builtin_amdgcn_s_setprio(0); } while (0)

template<int MODE>
__global__ __launch_bounds__(512, 1)
void gemm256(const ushort* __restrict__ A, int lda,
             const ushort* __restrict__ Bw, int ldb,
             const float* __restrict__ bias,
             const float* __restrict__ cvec,
             float* __restrict__ C, int ldc,
             int NT, int ksplit) {
    __shared__ ushort As[32768];   // [2][2][128][64]
    __shared__ ushort Bs[32768];
    const int tid  = threadIdx.x;
    const int lane = tid & 63;
    const int w    = tid >> 6;        // wave 0..7
    const int wr2  = w >> 2, wc2 = w & 3;
    const int w16  = w * 16;

    // XCD-chunked swizzle over the 256-block grid (1 block/CU)
    const int wg  = blockIdx.x;
    const int swz = (wg & 7) * 32 + (wg >> 3);
    const int by  = swz & 63;
    const int bx  = swz >> 6;
    const int m0  = by * 256;
    const int n0  = (MODE == 0) ? bx * 256 : 0;
    const int koff = (MODE == 0) ? 0 : bx * ksplit;

    // staging source (inverse-XOR-swizzled column chunk; LDS dest is linear):
    // LDS(row, chunk c) holds global(row, c ^ (row&7)); row&7 == (lane>>3)&7.
    const int swzc = ((lane & 7) ^ ((lane >> 3) & 7)) << 3;
    const ushort* gAs = A  + (size_t)(m0 + (lane >> 3)) * lda + koff + swzc;
    const ushort* gBs = Bw + (size_t)(n0 + (lane >> 3)) * ldb + koff + swzc;

    // fragment read addressing: global chunk g at row r lives at LDS chunk
    // g ^ (r&7); r&7 == lane&7 (frag row bases are multiples of 16).
    const int arow_l = wr2 * 64 + (lane & 15);
    const int brow_l = wc2 * 32 + (lane & 15);
    const int ck0 = (((lane >> 4))     ^ (lane & 7)) << 3;   // ks=0 chunk
    const int ck1 = ((4 + (lane >> 4)) ^ (lane & 7)) << 3;   // ks=1 chunk

    f32x4 acc[2][2][4][2] = {};
    bf16x8 aR[4][2], bR0[2][2], bR1[2][2];

    // prologue: tile 0 halves in steady-state stage order a0,b0,b1,a1
    STAGE_A(0, 0, 0);
    STAGE_B(0, 0, 0);
    STAGE_B(0, 1, 0);
    STAGE_A(0, 1, 0);

    for (int t = 0; t < NT; ++t) {
        const int d  = t & 1;
        const int e2 = d ^ 1;
        const bool pf = (t + 1) < NT;
        // ---- phase 0: Q(0,0); needs A-h0(t),B-h0(t) (staged 4 & 3 stages ago)
        asm volatile("s_waitcnt vmcnt(4)" ::: "memory");
        __builtin_amdgcn_s_barrier();
        READ_A(0, d);
        READ_B(0, d, bR0);
        if (pf) STAGE_A(t + 1, 0, e2);   // overwrites A-h0(t-1), last read ph(t-1,0)
        MFMA_Q(0, 0, bR0);
        // ---- phase 1: Q(0,1); needs B-h1(t) (staged ph(t-1,2))
        if (pf) asm volatile("s_waitcnt vmcnt(4)" ::: "memory");
        else    asm volatile("s_waitcnt vmcnt(2)" ::: "memory");
        __builtin_amdgcn_s_barrier();
        READ_B(1, d, bR1);
        if (pf) STAGE_B(t + 1, 0, e2);   // overwrites B-h0(t-1), last read ph(t-1,0)
        MFMA_Q(0, 1, bR1);
        // ---- phase 2: Q(1,1); needs A-h1(t) (staged ph(t-1,3))
        if (pf) asm volatile("s_waitcnt vmcnt(4)" ::: "memory");
        else    asm volatile("s_waitcnt vmcnt(0)" ::: "memory");
        __builtin_amdgcn_s_barrier();
        READ_A(1, d);
        if (pf) STAGE_B(t + 1, 1, e2);   // overwrites B-h1(t-1), last read ph(t-1,1)
        MFMA_Q(1, 1, bR1);
        // ---- phase 3: Q(1,0); no reads (aR, bR0 reused) -> no wait/barrier
        if (pf) STAGE_A(t + 1, 1, e2);   // overwrites A-h1(t-1), last read ph(t-1,2)
        MFMA_Q(1, 0, bR0);
    }

    // epilogue: C/D layout col = lane&15, row = (lane>>4)*4 + r  [m89-verified]
    const int rbase = (lane >> 4) << 2;
    const int cbase = lane & 15;
    float* Cb = (MODE == 0) ? C : (C + (size_t)bx * ((size_t)Bv * OUTv));
#pragma unroll
    for (int qr = 0; qr < 2; ++qr) {
#pragma unroll
        for (int qc = 0; qc < 2; ++qc) {
#pragma unroll
            for (int nf = 0; nf < 2; ++nf) {
                const int col = n0 + qc * 128 + wc2 * 32 + nf * 16 + cbase;
                float bsv = 0.f, csv = 0.f;
                if (MODE == 0) { bsv = bias[col]; csv = cvec[col]; }
#pragma unroll
                for (int mf = 0; mf < 4; ++mf) {
                    const int row = m0 + qr * 128 + wr2 * 64 + mf * 16 + rbase;
#pragma unroll
                    for (int r = 0; r < 4; ++r) {
                        float v = acc[qr][qc][mf][nf][r];
                        if (MODE == 0) v = fmaxf(v + bsv, 0.f) + csv;
                        Cb[(size_t)(row + r) * ldc + col] = v;
                    }
                }
            }
        }
    }
}

// ---------------------------------------------------------------------------
// LayerNorm over width 1024 reading f32 h (ld 1024), writing bf16 into zbuf
// column slot (row stride ZLD). 256 threads = 1 row, two-pass (ref numerics).
// ---------------------------------------------------------------------------
__global__ void ln_store(const float* __restrict__ h,
                         const float* __restrict__ g,
                         const float* __restrict__ bb,
                         ushort* __restrict__ z) {
    __shared__ float sm[4];
    const int t = threadIdx.x;
    const float* p = h + (size_t)blockIdx.x * 1024;
    float4 v = *(const float4*)&p[t * 4];
    float s = v.x + v.y + v.z + v.w;
#pragma unroll
    for (int o = 1; o < 64; o <<= 1) s += __shfl_xor(s, o, 64);
    const int lane = t & 63, wv = t >> 6;
    if (lane == 0) sm[wv] = s;
    __syncthreads();
    const float mean = (sm[0] + sm[1] + sm[2] + sm[3]) * (1.f / Dv);
    const float d0 = v.x - mean, d1 = v.y - mean, d2 = v.z - mean, d3 = v.w - mean;
    float q = d0 * d0 + d1 * d1 + d2 * d2 + d3 * d3;
#pragma unroll
    for (int o = 1; o < 64; o <<= 1) q += __shfl_xor(q, o, 64);
    __syncthreads();
    if (lane == 0) sm[wv] = q;
    __syncthreads();
    const float var = (sm[0] + sm[1] + sm[2] + sm[3]) * (1.f / Dv);
    const float r = rsqrtf(var + EPS);
    const float4 gg = *(const float4*)&g[t * 4];
    const float4 bv = *(const float4*)&bb[t * 4];
    ushort4 o;
    o.x = f2bf(d0 * r * gg.x + bv.x);
    o.y = f2bf(d1 * r * gg.y + bv.y);
    o.z = f2bf(d2 * r * gg.z + bv.z);
    o.w = f2bf(d3 * r * gg.w + bv.w);
    *(ushort4*)&z[(size_t)blockIdx.x * ZLD + t * 4] = o;
}

// ---------------------------------------------------------------------------
// Fused split-K reduce (+bias) + LayerNorm(256) + sigmoid -> d_out (f32).
// 4 rows/block, 1 wave per row, 4 cols/lane.
// ---------------------------------------------------------------------------
__global__ void ln_sig_reduce(const float* __restrict__ ps,
                              const float* __restrict__ bf_,
                              const float* __restrict__ g,
                              const float* __restrict__ bb,
                              float* __restrict__ y) {
    const int lane = threadIdx.x & 63;
    const int row  = blockIdx.x * 4 + (threadIdx.x >> 6);
    const size_t base = (size_t)row * OUTv + lane * 4;
    const size_t SP = (size_t)Bv * OUTv;
    const float4 s0 = *(const float4*)&ps[base];
    const float4 s1 = *(const float4*)&ps[base + SP];
    const float4 s2 = *(const float4*)&ps[base + 2 * SP];
    const float4 s3 = *(const float4*)&ps[base + 3 * SP];
    const float4 bv4 = *(const float4*)&bf_[lane * 4];
    const float v0 = (s0.x + s1.x) + (s2.x + s3.x) + bv4.x;
    const float v1 = (s0.y + s1.y) + (s2.y + s3.y) + bv4.y;
    const float v2 = (s0.z + s1.z) + (s2.z + s3.z) + bv4.z;
    const float v3 = (s0.w + s1.w) + (s2.w + s3.w) + bv4.w;
    float s = v0 + v1 + v2 + v3;
#pragma unroll
    for (int o = 1; o < 64; o <<= 1) s += __shfl_xor(s, o, 64);
    const float mean = s * (1.f / OUTv);
    const float d0 = v0 - mean, d1 = v1 - mean, d2 = v2 - mean, d3 = v3 - mean;
    float q = d0 * d0 + d1 * d1 + d2 * d2 + d3 * d3;
#pragma unroll
    for (int o = 1; o < 64; o <<= 1) q += __shfl_xor(q, o, 64);
    const float r = rsqrtf(q * (1.f / OUTv) + EPS);
    const float4 gg = *(const float4*)&g[lane * 4];
    const float4 bv = *(const float4*)&bb[lane * 4];
    float4 o;
    const float t0 = d0 * r * gg.x + bv.x;
    const float t1 = d1 * r * gg.y + bv.y;
    const float t2 = d2 * r * gg.z + bv.z;
    const float t3 = d3 * r * gg.w + bv.w;
    o.x = 1.f / (1.f + expf(-t0));
    o.y = 1.f / (1.f + expf(-t1));
    o.z = 1.f / (1.f + expf(-t2));
    o.w = 1.f / (1.f + expf(-t3));
    *(float4*)&y[base] = o;
}

// ---------------------------------------------------------------------------
extern "C" void kernel_launch(void* const* d_in, const int* in_sizes, int n_in,
                              void* d_out, int out_size, void* d_ws, size_t ws_size,
                              hipStream_t stream) {
    const float* x      = (const float*)d_in[0];
    const float* W      = (const float*)d_in[1];
    const float* b      = (const float*)d_in[2];
    // d_in[3] = Wq, d_in[4] = keys : dead code (softmax row-sums are 1)
    const float* values = (const float*)d_in[5];
    const float* Wout   = (const float*)d_in[6];
    const float* ln_g   = (const float*)d_in[7];
    const float* ln_b   = (const float*)d_in[8];
    const float* Wf     = (const float*)d_in[9];
    const float* bf     = (const float*)d_in[10];
    const float* lnf_g  = (const float*)d_in[11];
    const float* lnf_b  = (const float*)d_in[12];
    float* out = (float*)d_out;

    // workspace layout (~176 MB):
    char* ws = (char*)d_ws;
    ushort* zbuf = (ushort*)ws;                                  // (B,3072) bf16
    ws += (size_t)Bv * ZLD * sizeof(ushort);                     // 100.7 MB
    float* hbuf = (float*)ws;                                    // (B,1024) f32 pre-LN; reused as psum(4,B,256)
    ws += (size_t)Bv * Dv * sizeof(float);                       // 67.1 MB
    ushort* Wb = (ushort*)ws;                                    // (L,1024,1024) bf16
    ws += (size_t)Lv * Dv * Dv * sizeof(ushort);                 // 6.3 MB
    ushort* Wfb = (ushort*)ws;                                   // (256,3072) bf16
    ws += (size_t)OUTv * ZLD * sizeof(ushort);                   // 1.6 MB
    float* cvec = (float*)ws;                                    // (L,1024) f32

    // prep: weight converts, x convert, constant vectors
    {
        const int nW = Lv * Dv * Dv / 8;
        conv_bf16<<<(nW + 255) / 256, 256, 0, stream>>>(W, Wb, nW);
        const int nF = OUTv * ZLD / 8;
        conv_bf16<<<(nF + 255) / 256, 256, 0, stream>>>(Wf, Wfb, nF);
        conv_x<<<Bv * 128 / 256, 256, 0, stream>>>(x, zbuf);
        prep_kernel<<<dim3(4, Lv), 256, 0, stream>>>(values, Wout, cvec);
    }

    // layer GEMMs: 256 blocks (64 m-tiles x 4 n-tiles), 1/CU, NT = 1024/64 = 16
    for (int i = 0; i < Lv; ++i) {
        const ushort* Ain = (i == 0) ? (zbuf + 2048) : (zbuf + (size_t)(i - 1) * Dv);
        gemm256<0><<<dim3(256), 512, 0, stream>>>(
            Ain, ZLD, Wb + (size_t)i * Dv * Dv, Dv,
            b + (size_t)i * Dv, cvec + (size_t)i * Dv,
            hbuf, Dv, /*NT=*/16, /*ksplit=*/0);
        ln_store<<<Bv, 256, 0, stream>>>(hbuf, ln_g + (size_t)i * Dv,
                                         ln_b + (size_t)i * Dv,
                                         zbuf + (size_t)i * Dv);
    }

    // final GEMM: split-K=4 (64 m-tiles x 4 splits = 256 blocks), K=768 each,
    // NT = 768/64 = 12; raw partials into psum (= hbuf, free after last ln_store)
    float* psum = hbuf;
    gemm256<1><<<dim3(256), 512, 0, stream>>>(
        zbuf, ZLD, Wfb, ZLD, nullptr, nullptr,
        psum, OUTv, /*NT=*/12, /*ksplit=*/768);

    ln_sig_reduce<<<Bv / 4, 256, 0, stream>>>(psum, bf, lnf_g, lnf_b, out);
}

// Round 6
// 289.503 us; speedup vs baseline: 6.2946x; 1.0679x over previous
//
#include <hip/hip_runtime.h>
#include <math.h>

#define EPS 1e-5f

constexpr int Bv   = 16384;   // batch
constexpr int Dv   = 1024;    // hidden
constexpr int Lv   = 3;       // blocks
constexpr int NKVv = 128;
constexpr int Vv   = 256;
constexpr int OUTv = 256;
constexpr int ZLD  = Lv * Dv; // 3072 concat width (bf16 buffer row stride)

typedef short bf16x8 __attribute__((ext_vector_type(8)));
typedef float f32x4  __attribute__((ext_vector_type(4)));

using gas_t = __attribute__((address_space(1))) const void;
using las_t = __attribute__((address_space(3))) void;
#define GLD_LDS16(gp, lp) \
    __builtin_amdgcn_global_load_lds((gas_t*)(gp), (las_t*)(lp), 16, 0, 0)

// round-to-nearest-even f32 -> bf16 bits
static __device__ __forceinline__ ushort f2bf(float f) {
    unsigned u = __float_as_uint(f);
    u = (u + 0x7fffu + ((u >> 16) & 1u)) >> 16;
    return (ushort)u;
}

// ---------------------------------------------------------------------------
// prep (fast): vmean_i[v] = mean_n values[i][n][v]  (3 blocks)
// then cvec[i*1024+d] = sum_k vmean[i][k&255] * Wout[i][d][k]  (wave per row)
// (softmax rows sum to exactly 1 -> attention == add constant vector)
// ---------------------------------------------------------------------------
__global__ void vmean_kernel(const float* __restrict__ values,
                             float* __restrict__ vmean) {
    const int i = blockIdx.x, t = threadIdx.x;
    const float* vals = values + (size_t)i * NKVv * Vv;
    float s = 0.f;
    for (int n = 0; n < NKVv; ++n) s += vals[n * Vv + t];
    vmean[i * Vv + t] = s * (1.0f / NKVv);
}

__global__ void cvec_kernel(const float* __restrict__ vmean,
                            const float* __restrict__ Wout,
                            float* __restrict__ cvec) {
    const int w = threadIdx.x >> 6, lane = threadIdx.x & 63;
    const int r = blockIdx.x * 8 + w;          // 0..L*1024-1
    const int i = r >> 10;
    const float4 mv = *(const float4*)&vmean[i * Vv + lane * 4];
    const float* row = Wout + (size_t)r * 1024;
    float acc = 0.f;
#pragma unroll
    for (int c = 0; c < 4; ++c) {
        const float4 rv = *(const float4*)&row[c * 256 + lane * 4];
        acc += mv.x * rv.x + mv.y * rv.y + mv.z * rv.z + mv.w * rv.w;
    }
#pragma unroll
    for (int o = 1; o < 64; o <<= 1) acc += __shfl_xor(acc, o, 64);
    if (lane == 0) cvec[r] = acc;
}

// ---------------------------------------------------------------------------
// generic contiguous f32 -> bf16 convert, 8 elems/thread
// ---------------------------------------------------------------------------
__global__ void conv_bf16(const float* __restrict__ in, ushort* __restrict__ out, int n8) {
    const int t = blockIdx.x * 256 + threadIdx.x;
    if (t >= n8) return;
    const float4 v0 = *(const float4*)&in[t * 8];
    const float4 v1 = *(const float4*)&in[t * 8 + 4];
    ushort4 o0 = {f2bf(v0.x), f2bf(v0.y), f2bf(v0.z), f2bf(v0.w)};
    ushort4 o1 = {f2bf(v1.x), f2bf(v1.y), f2bf(v1.z), f2bf(v1.w)};
    *(ushort4*)&out[t * 8]     = o0;
    *(ushort4*)&out[t * 8 + 4] = o1;
}

// x (B,1024) f32 -> bf16 into zbuf[:, 2048:3072] (row stride ZLD)
__global__ void conv_x(const float* __restrict__ x, ushort* __restrict__ z) {
    const int t = blockIdx.x * 256 + threadIdx.x;  // B*128 threads
    const int row = t >> 7, c8 = (t & 127) << 3;
    const float4 v0 = *(const float4*)&x[(size_t)row * 1024 + c8];
    const float4 v1 = *(const float4*)&x[(size_t)row * 1024 + c8 + 4];
    ushort4 o0 = {f2bf(v0.x), f2bf(v0.y), f2bf(v0.z), f2bf(v0.w)};
    ushort4 o1 = {f2bf(v1.x), f2bf(v1.y), f2bf(v1.z), f2bf(v1.w)};
    ushort* p = z + (size_t)row * ZLD + 2048 + c8;
    *(ushort4*)p       = o0;
    *(ushort4*)(p + 4) = o1;
}

// ---------------------------------------------------------------------------
// 256x256 bf16 MFMA NT GEMM — 8-phase, counted vmcnt, XOR bank-swizzle,
// ASYMMETRIC pipeline depth: As 3-deep (A streams from HBM, ~900cy latency,
// use-distance 6-7 phases), Bs 2-deep (B-panel is L2-resident, 4 phases).
// LDS = 96 + 64 = 160 KiB (full CU pool, 1 block/CU).
//
// Stage order per tile t: ph0:B0(t+1) ph1:B1(t+1) ph2:A0(t+2) ph3:A1(t+2)
// Quadrant order:         ph0:Q(0,0)  ph1:Q(0,1)  ph2:Q(1,1)  ph3:Q(1,0)
// FIFO-derived waits: ph0 vmcnt(6) [binds B0(t)+A0/A1(t)], ph1 vmcnt(6)
// [binds B1(t)], ph2 none (A1(t) transitively bound at ph1; barrier kept for
// WAR). Tail (t==NT-1): ph0 vmcnt(2), ph1 vmcnt(0). All LDS overwrites are
// >=2 barriers after the last read of the previous occupant (traced).
//
// MODE 0: epilogue v = relu(acc+bias[n])+cvec[n] -> C (f32, ldc).
// MODE 1: split-K partial, raw acc -> C + bx*(Bv*256), n0=0, koff=bx*ksplit.
// Grid must be 256 blocks x 512 threads (8 waves, 2Mx4N per quadrant).
// ---------------------------------------------------------------------------
#define READ_A(QR, DD)                                                        \
    do { _Pragma("unroll")                                                    \
        for (int mf = 0; mf < 4; ++mf) {                                      \
            const int _o = (DD) * 16384 + (QR) * 8192 + (arow_l + mf * 16) * 64; \
            aR[mf][0] = *(const bf16x8*)&As[_o + ck0];                        \
            aR[mf][1] = *(const bf16x8*)&As[_o + ck1];                        \
        } } while (0)

#define READ_B(QC, DD, BR)                                                    \
    do { _Pragma("unroll")                                                    \
        for (int nf = 0; nf < 2; ++nf) {                                      \
            const int _o = (DD) * 16384 + (QC) * 8192 + (brow_l + nf * 16) * 64; \
            BR[nf][0] = *(const bf16x8*)&Bs[_o + ck0];                        \
            BR[nf][1] = *(const bf16x8*)&Bs[_o + ck1];                        \
        } } while (0)

#define STAGE_A(KT, H, DD)                                                    \
    do { const ushort* _p = gAs + (size_t)((H) * 128 + w16) * lda + (KT) * 64; \
         ushort* _l = (ushort*)As + (DD) * 16384 + (H) * 8192 + w16 * 64;     \
         GLD_LDS16(_p, _l);                                                   \
         GLD_LDS16(_p + (size_t)8 * lda, _l + 512); } while (0)

#define STAGE_B(KT, H, DD)                                                    \
    do { const ushort* _p = gBs + (size_t)((H) * 128 + w16) * ldb + (KT) * 64; \
         ushort* _l = (ushort*)Bs + (DD) * 16384 + (H) * 8192 + w16 * 64;     \
         GLD_LDS16(_p, _l);                                                   \
         GLD_LDS16(_p + (size_t)8 * ldb, _l + 512); } while (0)

#define MFMA_Q(QR, QC, BR)                                                    \
    do { __builtin_amdgcn_s_setprio(1);                                       \
        _Pragma("unroll")                                                     \
        for (int mf = 0; mf < 4; ++mf) {                                      \
            _Pragma("unroll")                                                 \
            for (int nf = 0; nf < 2; ++nf) {                                  \
                acc[QR][QC][mf][nf] = __builtin_amdgcn_mfma_f32_16x16x32_bf16( \
                    aR[mf][0], BR[nf][0], acc[QR][QC][mf][nf], 0, 0, 0);      \
                acc[QR][QC][mf][nf] = __builtin_amdgcn_mfma_f32_16x16x32_bf16( \
                    aR[mf][1], BR[nf][1], acc[QR][QC][mf][nf], 0, 0, 0);      \
            }                                                                 \
        }                                                                     \
        __builtin_amdgcn_s_setprio(0); } while (0)

template<int MODE>
__global__ __launch_bounds__(512, 1)
void gemm256(const ushort* __restrict__ A, int lda,
             const ushort* __restrict__ Bw, int ldb,
             const float* __restrict__ bias,
             const float* __restrict__ cvec,
             float* __restrict__ C, int ldc,
             int NT, int ksplit) {
    __shared__ ushort As[3 * 16384];   // [3][2][128][64] = 96 KiB
    __shared__ ushort Bs[2 * 16384];   // [2][2][128][64] = 64 KiB
    const int tid  = threadIdx.x;
    const int lane = tid & 63;
    const int w    = tid >> 6;        // wave 0..7
    const int wr2  = w >> 2, wc2 = w & 3;
    const int w16  = w * 16;

    // XCD-chunked swizzle over the 256-block grid (1 block/CU)
    const int wg  = blockIdx.x;
    const int swz = (wg & 7) * 32 + (wg >> 3);
    const int by  = swz & 63;
    const int bx  = swz >> 6;
    const int m0  = by * 256;
    const int n0  = (MODE == 0) ? bx * 256 : 0;
    const int koff = (MODE == 0) ? 0 : bx * ksplit;

    // staging source (inverse-XOR-swizzled column chunk; LDS dest is linear):
    // LDS(row, chunk c) holds global(row, c ^ (row&7)); row&7 == (lane>>3)&7.
    const int swzc = ((lane & 7) ^ ((lane >> 3) & 7)) << 3;
    const ushort* gAs = A  + (size_t)(m0 + (lane >> 3)) * lda + koff + swzc;
    const ushort* gBs = Bw + (size_t)(n0 + (lane >> 3)) * ldb + koff + swzc;

    // fragment read addressing: global chunk g at row r lives at LDS chunk
    // g ^ (r&7); r&7 == lane&7 (frag row bases are multiples of 16).
    const int arow_l = wr2 * 64 + (lane & 15);
    const int brow_l = wc2 * 32 + (lane & 15);
    const int ck0 = (((lane >> 4))     ^ (lane & 7)) << 3;   // ks=0 chunk
    const int ck1 = ((4 + (lane >> 4)) ^ (lane & 7)) << 3;   // ks=1 chunk

    f32x4 acc[2][2][4][2] = {};
    bf16x8 aR[4][2], bR0[2][2], bR1[2][2];

    // prologue (issue order must match steady-state relative order):
    // A0(0), A1(0), B0(0), B1(0), A0(1), A1(1)
    STAGE_A(0, 0, 0);
    STAGE_A(0, 1, 0);
    STAGE_B(0, 0, 0);
    STAGE_B(0, 1, 0);
    STAGE_A(1, 0, 1);
    STAGE_A(1, 1, 1);

    for (int t = 0; t < NT; ++t) {
        const int da = t % 3;          // A buffer of tile t
        const int db = t & 1;          // B buffer of tile t
        const bool pf1 = (t + 1) < NT;
        const bool pf2 = (t + 2) < NT;
        // ---- phase 0: Q(0,0); reads A0(t) [6 ph old], B0(t) [4 ph old, L2]
        if (pf1) asm volatile("s_waitcnt vmcnt(6)" ::: "memory");
        else     asm volatile("s_waitcnt vmcnt(2)" ::: "memory");
        __builtin_amdgcn_s_barrier();
        READ_A(0, da);
        READ_B(0, db, bR0);
        if (pf1) STAGE_B(t + 1, 0, (t + 1) & 1);  // overwrites B0(t-1), read ph0(t-1)
        MFMA_Q(0, 0, bR0);
        // ---- phase 1: Q(0,1); reads B1(t) [4 ph old, L2]
        if (pf1) asm volatile("s_waitcnt vmcnt(6)" ::: "memory");
        else     asm volatile("s_waitcnt vmcnt(0)" ::: "memory");
        __builtin_amdgcn_s_barrier();
        READ_B(1, db, bR1);
        if (pf1) STAGE_B(t + 1, 1, (t + 1) & 1);  // overwrites B1(t-1), read ph1(t-1)
        MFMA_Q(0, 1, bR1);
        // ---- phase 2: Q(1,1); reads A1(t) (completion already forced at ph1)
        __builtin_amdgcn_s_barrier();
        READ_A(1, da);
        if (pf2) STAGE_A(t + 2, 0, (t + 2) % 3);  // overwrites A0(t-1), read ph0(t-1)
        MFMA_Q(1, 1, bR1);
        // ---- phase 3: Q(1,0); register reuse, no reads -> no wait/barrier
        if (pf2) STAGE_A(t + 2, 1, (t + 2) % 3);  // overwrites A1(t-1), read ph2(t-1)
        MFMA_Q(1, 0, bR0);
    }

    // epilogue: C/D layout col = lane&15, row = (lane>>4)*4 + r  [m89-verified]
    const int rbase = (lane >> 4) << 2;
    const int cbase = lane & 15;
    float* Cb = (MODE == 0) ? C : (C + (size_t)bx * ((size_t)Bv * OUTv));
#pragma unroll
    for (int qr = 0; qr < 2; ++qr) {
#pragma unroll
        for (int qc = 0; qc < 2; ++qc) {
#pragma unroll
            for (int nf = 0; nf < 2; ++nf) {
                const int col = n0 + qc * 128 + wc2 * 32 + nf * 16 + cbase;
                float bsv = 0.f, csv = 0.f;
                if (MODE == 0) { bsv = bias[col]; csv = cvec[col]; }
#pragma unroll
                for (int mf = 0; mf < 4; ++mf) {
                    const int row = m0 + qr * 128 + wr2 * 64 + mf * 16 + rbase;
#pragma unroll
                    for (int r = 0; r < 4; ++r) {
                        float v = acc[qr][qc][mf][nf][r];
                        if (MODE == 0) v = fmaxf(v + bsv, 0.f) + csv;
                        Cb[(size_t)(row + r) * ldc + col] = v;
                    }
                }
            }
        }
    }
}

// ---------------------------------------------------------------------------
// LayerNorm over width 1024 reading f32 h (ld 1024), writing bf16 into zbuf
// column slot (row stride ZLD). 256 threads = 1 row, two-pass (ref numerics).
// ---------------------------------------------------------------------------
__global__ void ln_store(const float* __restrict__ h,
                         const float* __restrict__ g,
                         const float* __restrict__ bb,
                         ushort* __restrict__ z) {
    __shared__ float sm[4];
    const int t = threadIdx.x;
    const float* p = h + (size_t)blockIdx.x * 1024;
    float4 v = *(const float4*)&p[t * 4];
    float s = v.x + v.y + v.z + v.w;
#pragma unroll
    for (int o = 1; o < 64; o <<= 1) s += __shfl_xor(s, o, 64);
    const int lane = t & 63, wv = t >> 6;
    if (lane == 0) sm[wv] = s;
    __syncthreads();
    const float mean = (sm[0] + sm[1] + sm[2] + sm[3]) * (1.f / Dv);
    const float d0 = v.x - mean, d1 = v.y - mean, d2 = v.z - mean, d3 = v.w - mean;
    float q = d0 * d0 + d1 * d1 + d2 * d2 + d3 * d3;
#pragma unroll
    for (int o = 1; o < 64; o <<= 1) q += __shfl_xor(q, o, 64);
    __syncthreads();
    if (lane == 0) sm[wv] = q;
    __syncthreads();
    const float var = (sm[0] + sm[1] + sm[2] + sm[3]) * (1.f / Dv);
    const float r = rsqrtf(var + EPS);
    const float4 gg = *(const float4*)&g[t * 4];
    const float4 bv = *(const float4*)&bb[t * 4];
    ushort4 o;
    o.x = f2bf(d0 * r * gg.x + bv.x);
    o.y = f2bf(d1 * r * gg.y + bv.y);
    o.z = f2bf(d2 * r * gg.z + bv.z);
    o.w = f2bf(d3 * r * gg.w + bv.w);
    *(ushort4*)&z[(size_t)blockIdx.x * ZLD + t * 4] = o;
}

// ---------------------------------------------------------------------------
// Fused split-K reduce (+bias) + LayerNorm(256) + sigmoid -> d_out (f32).
// 4 rows/block, 1 wave per row, 4 cols/lane.
// ---------------------------------------------------------------------------
__global__ void ln_sig_reduce(const float* __restrict__ ps,
                              const float* __restrict__ bf_,
                              const float* __restrict__ g,
                              const float* __restrict__ bb,
                              float* __restrict__ y) {
    const int lane = threadIdx.x & 63;
    const int row  = blockIdx.x * 4 + (threadIdx.x >> 6);
    const size_t base = (size_t)row * OUTv + lane * 4;
    const size_t SP = (size_t)Bv * OUTv;
    const float4 s0 = *(const float4*)&ps[base];
    const float4 s1 = *(const float4*)&ps[base + SP];
    const float4 s2 = *(const float4*)&ps[base + 2 * SP];
    const float4 s3 = *(const float4*)&ps[base + 3 * SP];
    const float4 bv4 = *(const float4*)&bf_[lane * 4];
    const float v0 = (s0.x + s1.x) + (s2.x + s3.x) + bv4.x;
    const float v1 = (s0.y + s1.y) + (s2.y + s3.y) + bv4.y;
    const float v2 = (s0.z + s1.z) + (s2.z + s3.z) + bv4.z;
    const float v3 = (s0.w + s1.w) + (s2.w + s3.w) + bv4.w;
    float s = v0 + v1 + v2 + v3;
#pragma unroll
    for (int o = 1; o < 64; o <<= 1) s += __shfl_xor(s, o, 64);
    const float mean = s * (1.f / OUTv);
    const float d0 = v0 - mean, d1 = v1 - mean, d2 = v2 - mean, d3 = v3 - mean;
    float q = d0 * d0 + d1 * d1 + d2 * d2 + d3 * d3;
#pragma unroll
    for (int o = 1; o < 64; o <<= 1) q += __shfl_xor(q, o, 64);
    const float r = rsqrtf(q * (1.f / OUTv) + EPS);
    const float4 gg = *(const float4*)&g[lane * 4];
    const float4 bv = *(const float4*)&bb[lane * 4];
    float4 o;
    const float t0 = d0 * r * gg.x + bv.x;
    const float t1 = d1 * r * gg.y + bv.y;
    const float t2 = d2 * r * gg.z + bv.z;
    const float t3 = d3 * r * gg.w + bv.w;
    o.x = 1.f / (1.f + expf(-t0));
    o.y = 1.f / (1.f + expf(-t1));
    o.z = 1.f / (1.f + expf(-t2));
    o.w = 1.f / (1.f + expf(-t3));
    *(float4*)&y[base] = o;
}

// ---------------------------------------------------------------------------
extern "C" void kernel_launch(void* const* d_in, const int* in_sizes, int n_in,
                              void* d_out, int out_size, void* d_ws, size_t ws_size,
                              hipStream_t stream) {
    const float* x      = (const float*)d_in[0];
    const float* W      = (const float*)d_in[1];
    const float* b      = (const float*)d_in[2];
    // d_in[3] = Wq, d_in[4] = keys : dead code (softmax row-sums are 1)
    const float* values = (const float*)d_in[5];
    const float* Wout   = (const float*)d_in[6];
    const float* ln_g   = (const float*)d_in[7];
    const float* ln_b   = (const float*)d_in[8];
    const float* Wf     = (const float*)d_in[9];
    const float* bf     = (const float*)d_in[10];
    const float* lnf_g  = (const float*)d_in[11];
    const float* lnf_b  = (const float*)d_in[12];
    float* out = (float*)d_out;

    // workspace layout (~176 MB):
    char* ws = (char*)d_ws;
    ushort* zbuf = (ushort*)ws;                                  // (B,3072) bf16
    ws += (size_t)Bv * ZLD * sizeof(ushort);                     // 100.7 MB
    float* hbuf = (float*)ws;                                    // (B,1024) f32 pre-LN; reused as psum(4,B,256)
    ws += (size_t)Bv * Dv * sizeof(float);                       // 67.1 MB
    ushort* Wb = (ushort*)ws;                                    // (L,1024,1024) bf16
    ws += (size_t)Lv * Dv * Dv * sizeof(ushort);                 // 6.3 MB
    ushort* Wfb = (ushort*)ws;                                   // (256,3072) bf16
    ws += (size_t)OUTv * ZLD * sizeof(ushort);                   // 1.6 MB
    float* cvec = (float*)ws;                                    // (L,1024) f32
    ws += (size_t)Lv * Dv * sizeof(float);
    float* vmean = (float*)ws;                                   // (L,256) f32

    // prep: weight converts, x convert, constant vectors
    {
        const int nW = Lv * Dv * Dv / 8;
        conv_bf16<<<(nW + 255) / 256, 256, 0, stream>>>(W, Wb, nW);
        const int nF = OUTv * ZLD / 8;
        conv_bf16<<<(nF + 255) / 256, 256, 0, stream>>>(Wf, Wfb, nF);
        conv_x<<<Bv * 128 / 256, 256, 0, stream>>>(x, zbuf);
        vmean_kernel<<<Lv, 256, 0, stream>>>(values, vmean);
        cvec_kernel<<<Lv * Dv / 8, 512, 0, stream>>>(vmean, Wout, cvec);
    }

    // layer GEMMs: 256 blocks (64 m-tiles x 4 n-tiles), 1/CU, NT = 1024/64 = 16
    for (int i = 0; i < Lv; ++i) {
        const ushort* Ain = (i == 0) ? (zbuf + 2048) : (zbuf + (size_t)(i - 1) * Dv);
        gemm256<0><<<dim3(256), 512, 0, stream>>>(
            Ain, ZLD, Wb + (size_t)i * Dv * Dv, Dv,
            b + (size_t)i * Dv, cvec + (size_t)i * Dv,
            hbuf, Dv, /*NT=*/16, /*ksplit=*/0);
        ln_store<<<Bv, 256, 0, stream>>>(hbuf, ln_g + (size_t)i * Dv,
                                         ln_b + (size_t)i * Dv,
                                         zbuf + (size_t)i * Dv);
    }

    // final GEMM: split-K=4 (64 m-tiles x 4 splits = 256 blocks), K=768 each,
    // NT = 768/64 = 12; raw partials into psum (= hbuf, free after last ln_store)
    float* psum = hbuf;
    gemm256<1><<<dim3(256), 512, 0, stream>>>(
        zbuf, ZLD, Wfb, ZLD, nullptr, nullptr,
        psum, OUTv, /*NT=*/12, /*ksplit=*/768);

    ln_sig_reduce<<<Bv / 4, 256, 0, stream>>>(psum, bf, lnf_g, lnf_b, out);
}

// Round 7
// 248.654 us; speedup vs baseline: 7.3286x; 1.1643x over previous
//
#include <hip/hip_runtime.h>
#include <math.h>

#define EPS 1e-5f

constexpr int Bv   = 16384;   // batch
constexpr int Dv   = 1024;    // hidden
constexpr int Lv   = 3;       // blocks
constexpr int NKVv = 128;
constexpr int Vv   = 256;
constexpr int OUTv = 256;
constexpr int ZLD  = Lv * Dv; // 3072 concat width (bf16 buffer row stride)

typedef short bf16x8 __attribute__((ext_vector_type(8)));
typedef float f32x4  __attribute__((ext_vector_type(4)));

using gas_t = __attribute__((address_space(1))) const void;
using las_t = __attribute__((address_space(3))) void;
#define GLD_LDS16(gp, lp) \
    __builtin_amdgcn_global_load_lds((gas_t*)(gp), (las_t*)(lp), 16, 0, 0)

// round-to-nearest-even f32 -> bf16 bits
static __device__ __forceinline__ ushort f2bf(float f) {
    unsigned u = __float_as_uint(f);
    u = (u + 0x7fffu + ((u >> 16) & 1u)) >> 16;
    return (ushort)u;
}
static __device__ __forceinline__ float bf2f(short s) {
    return __uint_as_float(((unsigned)(ushort)s) << 16);
}

// ---------------------------------------------------------------------------
// prep: vmean_i[v] = mean_n values[i][n][v]; cvec[r] = <vmean tile, Wout row r>
// (softmax rows sum to exactly 1 -> attention == add constant vector)
// ---------------------------------------------------------------------------
__global__ void vmean_kernel(const float* __restrict__ values,
                             float* __restrict__ vmean) {
    const int i = blockIdx.x, t = threadIdx.x;
    const float* vals = values + (size_t)i * NKVv * Vv;
    float s = 0.f;
    for (int n = 0; n < NKVv; ++n) s += vals[n * Vv + t];
    vmean[i * Vv + t] = s * (1.0f / NKVv);
}

__global__ void cvec_kernel(const float* __restrict__ vmean,
                            const float* __restrict__ Wout,
                            float* __restrict__ cvec) {
    const int w = threadIdx.x >> 6, lane = threadIdx.x & 63;
    const int r = blockIdx.x * 8 + w;          // 0..L*1024-1
    const int i = r >> 10;
    const float4 mv = *(const float4*)&vmean[i * Vv + lane * 4];
    const float* row = Wout + (size_t)r * 1024;
    float acc = 0.f;
#pragma unroll
    for (int c = 0; c < 4; ++c) {
        const float4 rv = *(const float4*)&row[c * 256 + lane * 4];
        acc += mv.x * rv.x + mv.y * rv.y + mv.z * rv.z + mv.w * rv.w;
    }
#pragma unroll
    for (int o = 1; o < 64; o <<= 1) acc += __shfl_xor(acc, o, 64);
    if (lane == 0) cvec[r] = acc;
}

// ---------------------------------------------------------------------------
// generic contiguous f32 -> bf16 convert, 8 elems/thread
// ---------------------------------------------------------------------------
__global__ void conv_bf16(const float* __restrict__ in, ushort* __restrict__ out, int n8) {
    const int t = blockIdx.x * 256 + threadIdx.x;
    if (t >= n8) return;
    const float4 v0 = *(const float4*)&in[t * 8];
    const float4 v1 = *(const float4*)&in[t * 8 + 4];
    ushort4 o0 = {f2bf(v0.x), f2bf(v0.y), f2bf(v0.z), f2bf(v0.w)};
    ushort4 o1 = {f2bf(v1.x), f2bf(v1.y), f2bf(v1.z), f2bf(v1.w)};
    *(ushort4*)&out[t * 8]     = o0;
    *(ushort4*)&out[t * 8 + 4] = o1;
}

// x (B,1024) f32 -> bf16 into zbuf[:, 2048:3072] (row stride ZLD)
__global__ void conv_x(const float* __restrict__ x, ushort* __restrict__ z) {
    const int t = blockIdx.x * 256 + threadIdx.x;  // B*128 threads
    const int row = t >> 7, c8 = (t & 127) << 3;
    const float4 v0 = *(const float4*)&x[(size_t)row * 1024 + c8];
    const float4 v1 = *(const float4*)&x[(size_t)row * 1024 + c8 + 4];
    ushort4 o0 = {f2bf(v0.x), f2bf(v0.y), f2bf(v0.z), f2bf(v0.w)};
    ushort4 o1 = {f2bf(v1.x), f2bf(v1.y), f2bf(v1.z), f2bf(v1.w)};
    ushort* p = z + (size_t)row * ZLD + 2048 + c8;
    *(ushort4*)p       = o0;
    *(ushort4*)(p + 4) = o1;
}

// ---------------------------------------------------------------------------
// 256x256 bf16 MFMA NT GEMM — 8-phase, counted vmcnt (round-5 symmetric
// 2-deep schedule, measured fastest), XOR bank-swizzle (linear LDS dest;
// inverse-swizzled global source; swizzled ds_read).
//
// MODE 0 (layer): epilogue v = relu(acc+bias)+cvec; per-row (sum,sumsq) over
//   the block's 256 cols -> pstats[row][bx*4+wc2]; bf16(v) stored COALESCED
//   via LDS transpose (512B row bursts) into C (ushort, ldc). LN finishes in
//   ln_finish (first LN pass fused here).
// MODE 1 (final, split-K): raw f32 acc -> C + bx*(Bv*256), n0=0, koff=bx*ksplit.
// Grid must be 256 blocks x 512 threads (8 waves, 2Mx4N per 128x128 quadrant).
// ---------------------------------------------------------------------------
#define READ_A(QR, DD)                                                        \
    do { _Pragma("unroll")                                                    \
        for (int mf = 0; mf < 4; ++mf) {                                      \
            const int _o = (DD) * 16384 + (QR) * 8192 + (arow_l + mf * 16) * 64; \
            aR[mf][0] = *(const bf16x8*)&As[_o + ck0];                        \
            aR[mf][1] = *(const bf16x8*)&As[_o + ck1];                        \
        } } while (0)

#define READ_B(QC, DD, BR)                                                    \
    do { _Pragma("unroll")                                                    \
        for (int nf = 0; nf < 2; ++nf) {                                      \
            const int _o = (DD) * 16384 + (QC) * 8192 + (brow_l + nf * 16) * 64; \
            BR[nf][0] = *(const bf16x8*)&Bs[_o + ck0];                        \
            BR[nf][1] = *(const bf16x8*)&Bs[_o + ck1];                        \
        } } while (0)

#define STAGE_A(KT, H, DD)                                                    \
    do { const ushort* _p = gAs + (size_t)((H) * 128 + w16) * lda + (KT) * 64; \
         ushort* _l = As + (DD) * 16384 + (H) * 8192 + w16 * 64;              \
         GLD_LDS16(_p, _l);                                                   \
         GLD_LDS16(_p + (size_t)8 * lda, _l + 512); } while (0)

#define STAGE_B(KT, H, DD)                                                    \
    do { const ushort* _p = gBs + (size_t)((H) * 128 + w16) * ldb + (KT) * 64; \
         ushort* _l = Bs + (DD) * 16384 + (H) * 8192 + w16 * 64;              \
         GLD_LDS16(_p, _l);                                                   \
         GLD_LDS16(_p + (size_t)8 * ldb, _l + 512); } while (0)

#define MFMA_Q(QR, QC, BR)                                                    \
    do { __builtin_amdgcn_s_setprio(1);                                       \
        _Pragma("unroll")                                                     \
        for (int mf = 0; mf < 4; ++mf) {                                      \
            _Pragma("unroll")                                                 \
            for (int nf = 0; nf < 2; ++nf) {                                  \
                acc[QR][QC][mf][nf] = __builtin_amdgcn_mfma_f32_16x16x32_bf16( \
                    aR[mf][0], BR[nf][0], acc[QR][QC][mf][nf], 0, 0, 0);      \
                acc[QR][QC][mf][nf] = __builtin_amdgcn_mfma_f32_16x16x32_bf16( \
                    aR[mf][1], BR[nf][1], acc[QR][QC][mf][nf], 0, 0, 0);      \
            }                                                                 \
        }                                                                     \
        __builtin_amdgcn_s_setprio(0); } while (0)

template<int MODE>
__global__ __launch_bounds__(512, 1)
void gemm256(const ushort* __restrict__ A, int lda,
             const ushort* __restrict__ Bw, int ldb,
             const float* __restrict__ bias,
             const float* __restrict__ cvec,
             void* __restrict__ Cv, int ldc,
             int NT, int ksplit,
             float2* __restrict__ pstats) {
    // 132 KiB union: main loop As(64K)+Bs(64K); epilogue bf16 tile [256][264]
    __shared__ __align__(16) char smem[135168];
    ushort* As = (ushort*)smem;            // [2][2][128][64]
    ushort* Bs = (ushort*)(smem + 65536);  // [2][2][128][64]
    const int tid  = threadIdx.x;
    const int lane = tid & 63;
    const int w    = tid >> 6;        // wave 0..7
    const int wr2  = w >> 2, wc2 = w & 3;
    const int w16  = w * 16;

    // XCD-chunked swizzle over the 256-block grid (1 block/CU)
    const int wg  = blockIdx.x;
    const int swz = (wg & 7) * 32 + (wg >> 3);
    const int by  = swz & 63;
    const int bx  = swz >> 6;
    const int m0  = by * 256;
    const int n0  = (MODE == 0) ? bx * 256 : 0;
    const int koff = (MODE == 0) ? 0 : bx * ksplit;

    // staging source (inverse-XOR-swizzled column chunk; LDS dest is linear):
    // LDS(row, chunk c) holds global(row, c ^ (row&7)); row&7 == (lane>>3)&7.
    const int swzc = ((lane & 7) ^ ((lane >> 3) & 7)) << 3;
    const ushort* gAs = A  + (size_t)(m0 + (lane >> 3)) * lda + koff + swzc;
    const ushort* gBs = Bw + (size_t)(n0 + (lane >> 3)) * ldb + koff + swzc;

    // fragment read addressing: global chunk g at row r lives at LDS chunk
    // g ^ (r&7); r&7 == lane&7 (frag row bases are multiples of 16).
    const int arow_l = wr2 * 64 + (lane & 15);
    const int brow_l = wc2 * 32 + (lane & 15);
    const int ck0 = (((lane >> 4))     ^ (lane & 7)) << 3;   // ks=0 chunk
    const int ck1 = ((4 + (lane >> 4)) ^ (lane & 7)) << 3;   // ks=1 chunk

    f32x4 acc[2][2][4][2] = {};
    bf16x8 aR[4][2], bR0[2][2], bR1[2][2];

    // prologue: tile 0 halves in steady-state stage order a0,b0,b1,a1
    STAGE_A(0, 0, 0);
    STAGE_B(0, 0, 0);
    STAGE_B(0, 1, 0);
    STAGE_A(0, 1, 0);

    for (int t = 0; t < NT; ++t) {
        const int d  = t & 1;
        const int e2 = d ^ 1;
        const bool pf = (t + 1) < NT;
        // ---- phase 0: Q(0,0); needs A-h0(t),B-h0(t) (staged 4 & 3 stages ago)
        asm volatile("s_waitcnt vmcnt(4)" ::: "memory");
        __builtin_amdgcn_s_barrier();
        READ_A(0, d);
        READ_B(0, d, bR0);
        if (pf) STAGE_A(t + 1, 0, e2);   // overwrites A-h0(t-1), last read ph(t-1,0)
        MFMA_Q(0, 0, bR0);
        // ---- phase 1: Q(0,1); needs B-h1(t) (staged ph(t-1,2))
        if (pf) asm volatile("s_waitcnt vmcnt(4)" ::: "memory");
        else    asm volatile("s_waitcnt vmcnt(2)" ::: "memory");
        __builtin_amdgcn_s_barrier();
        READ_B(1, d, bR1);
        if (pf) STAGE_B(t + 1, 0, e2);   // overwrites B-h0(t-1), last read ph(t-1,0)
        MFMA_Q(0, 1, bR1);
        // ---- phase 2: Q(1,1); needs A-h1(t) (staged ph(t-1,3))
        if (pf) asm volatile("s_waitcnt vmcnt(4)" ::: "memory");
        else    asm volatile("s_waitcnt vmcnt(0)" ::: "memory");
        __builtin_amdgcn_s_barrier();
        READ_A(1, d);
        if (pf) STAGE_B(t + 1, 1, e2);   // overwrites B-h1(t-1), last read ph(t-1,1)
        MFMA_Q(1, 1, bR1);
        // ---- phase 3: Q(1,0); no reads (aR, bR0 reused) -> no wait/barrier
        if (pf) STAGE_A(t + 1, 1, e2);   // overwrites A-h1(t-1), last read ph(t-1,2)
        MFMA_Q(1, 0, bR0);
    }

    // epilogue: C/D layout col = lane&15, row = (lane>>4)*4 + r  [m89-verified]
    const int lg4 = (lane >> 4) << 2;
    if (MODE == 0) {
        // hoisted per-lane bias/cvec (4 cols each)
        float bsv[2][2], csv[2][2];
#pragma unroll
        for (int qc = 0; qc < 2; ++qc)
#pragma unroll
            for (int nf = 0; nf < 2; ++nf) {
                const int col = n0 + qc * 128 + wc2 * 32 + nf * 16 + (lane & 15);
                bsv[qc][nf] = bias[col];
                csv[qc][nf] = cvec[col];
            }
        // epilogue values + fused LN pass 1 (row partial sums over 256 cols)
#pragma unroll
        for (int qr = 0; qr < 2; ++qr)
#pragma unroll
            for (int mf = 0; mf < 4; ++mf)
#pragma unroll
                for (int r = 0; r < 4; ++r) {
                    float sum = 0.f, sq = 0.f;
#pragma unroll
                    for (int qc = 0; qc < 2; ++qc)
#pragma unroll
                        for (int nf = 0; nf < 2; ++nf) {
                            float v = fmaxf(acc[qr][qc][mf][nf][r] + bsv[qc][nf], 0.f)
                                      + csv[qc][nf];
                            acc[qr][qc][mf][nf][r] = v;
                            sum += v; sq += v * v;
                        }
#pragma unroll
                    for (int o = 1; o < 16; o <<= 1) {
                        sum += __shfl_xor(sum, o, 64);
                        sq  += __shfl_xor(sq,  o, 64);
                    }
                    if ((lane & 15) == 0) {
                        const int rloc = qr * 128 + wr2 * 64 + mf * 16 + lg4 + r;
                        pstats[(((size_t)(m0 + rloc)) << 4) + (bx << 2) + wc2] =
                            make_float2(sum, sq);
                    }
                }
        __syncthreads();                       // staging LDS dead in all waves
        ushort* tile = (ushort*)smem;          // [256][264], 528B rows (16B-mult)
#pragma unroll
        for (int qr = 0; qr < 2; ++qr)
#pragma unroll
            for (int qc = 0; qc < 2; ++qc)
#pragma unroll
                for (int mf = 0; mf < 4; ++mf)
#pragma unroll
                    for (int nf = 0; nf < 2; ++nf)
#pragma unroll
                        for (int r = 0; r < 4; ++r) {
                            const int rloc = qr * 128 + wr2 * 64 + mf * 16 + lg4 + r;
                            const int cloc = qc * 128 + wc2 * 32 + nf * 16 + (lane & 15);
                            tile[rloc * 264 + cloc] = f2bf(acc[qr][qc][mf][nf][r]);
                        }
        __syncthreads();
        ushort* C16 = (ushort*)Cv;
        for (int c = tid; c < 256 * 32; c += 512) {
            const int row = c >> 5, ch = (c & 31) << 3;
            const bf16x8 v = *(const bf16x8*)&tile[row * 264 + ch];
            *(bf16x8*)&C16[(size_t)(m0 + row) * ldc + n0 + ch] = v;
        }
    } else {
        // MODE 1: raw f32 split-K partials
        const int cbase = lane & 15;
        float* Cb = (float*)Cv + (size_t)bx * ((size_t)Bv * OUTv);
#pragma unroll
        for (int qr = 0; qr < 2; ++qr)
#pragma unroll
            for (int qc = 0; qc < 2; ++qc)
#pragma unroll
                for (int nf = 0; nf < 2; ++nf) {
                    const int col = qc * 128 + wc2 * 32 + nf * 16 + cbase;
#pragma unroll
                    for (int mf = 0; mf < 4; ++mf) {
                        const int row = m0 + qr * 128 + wr2 * 64 + mf * 16 + lg4;
#pragma unroll
                        for (int r = 0; r < 4; ++r)
                            Cb[(size_t)(row + r) * ldc + col] = acc[qr][qc][mf][nf][r];
                    }
                }
    }
}

// ---------------------------------------------------------------------------
// LN pass 2: combine 16 per-row partials, normalize bf16 h in place (width
// 1024, row stride ZLD). 4 waves/block, 1 wave per row, 16 cols/lane.
// var = E[x^2]-m^2: denominator is EPS-dominated here (var<<eps), safe.
// ---------------------------------------------------------------------------
__global__ void ln_finish(ushort* __restrict__ z,
                          const float2* __restrict__ pstats,
                          const float* __restrict__ g,
                          const float* __restrict__ bb) {
    const int lane = threadIdx.x & 63;
    const int row  = blockIdx.x * 4 + (threadIdx.x >> 6);
    float sum = 0.f, sq = 0.f;
    if (lane < 16) {
        const float2 p = pstats[((size_t)row << 4) + lane];
        sum = p.x; sq = p.y;
    }
#pragma unroll
    for (int o = 1; o < 16; o <<= 1) {
        sum += __shfl_xor(sum, o, 64);
        sq  += __shfl_xor(sq,  o, 64);
    }
    sum = __shfl(sum, lane & 15, 64);   // broadcast group-0 totals
    sq  = __shfl(sq,  lane & 15, 64);
    const float mean = sum * (1.f / Dv);
    const float var  = sq * (1.f / Dv) - mean * mean;
    const float rr   = rsqrtf(var + EPS);
    const float* gp = g  + lane * 16;
    const float* bp = bb + lane * 16;
    ushort* zr = z + (size_t)row * ZLD + lane * 16;
    bf16x8 h0 = *(const bf16x8*)zr;
    bf16x8 h1 = *(const bf16x8*)(zr + 8);
    bf16x8 o0, o1;
#pragma unroll
    for (int j = 0; j < 8; ++j) {
        o0[j] = (short)f2bf((bf2f(h0[j]) - mean) * rr * gp[j]     + bp[j]);
        o1[j] = (short)f2bf((bf2f(h1[j]) - mean) * rr * gp[j + 8] + bp[j + 8]);
    }
    *(bf16x8*)zr       = o0;
    *(bf16x8*)(zr + 8) = o1;
}

// ---------------------------------------------------------------------------
// Fused split-K reduce (+bias) + LayerNorm(256) + sigmoid -> d_out (f32).
// 4 rows/block, 1 wave per row, 4 cols/lane.
// ---------------------------------------------------------------------------
__global__ void ln_sig_reduce(const float* __restrict__ ps,
                              const float* __restrict__ bf_,
                              const float* __restrict__ g,
                              const float* __restrict__ bb,
                              float* __restrict__ y) {
    const int lane = threadIdx.x & 63;
    const int row  = blockIdx.x * 4 + (threadIdx.x >> 6);
    const size_t base = (size_t)row * OUTv + lane * 4;
    const size_t SP = (size_t)Bv * OUTv;
    const float4 s0 = *(const float4*)&ps[base];
    const float4 s1 = *(const float4*)&ps[base + SP];
    const float4 s2 = *(const float4*)&ps[base + 2 * SP];
    const float4 s3 = *(const float4*)&ps[base + 3 * SP];
    const float4 bv4 = *(const float4*)&bf_[lane * 4];
    const float v0 = (s0.x + s1.x) + (s2.x + s3.x) + bv4.x;
    const float v1 = (s0.y + s1.y) + (s2.y + s3.y) + bv4.y;
    const float v2 = (s0.z + s1.z) + (s2.z + s3.z) + bv4.z;
    const float v3 = (s0.w + s1.w) + (s2.w + s3.w) + bv4.w;
    float s = v0 + v1 + v2 + v3;
#pragma unroll
    for (int o = 1; o < 64; o <<= 1) s += __shfl_xor(s, o, 64);
    const float mean = s * (1.f / OUTv);
    const float d0 = v0 - mean, d1 = v1 - mean, d2 = v2 - mean, d3 = v3 - mean;
    float q = d0 * d0 + d1 * d1 + d2 * d2 + d3 * d3;
#pragma unroll
    for (int o = 1; o < 64; o <<= 1) q += __shfl_xor(q, o, 64);
    const float r = rsqrtf(q * (1.f / OUTv) + EPS);
    const float4 gg = *(const float4*)&g[lane * 4];
    const float4 bv = *(const float4*)&bb[lane * 4];
    float4 o;
    const float t0 = d0 * r * gg.x + bv.x;
    const float t1 = d1 * r * gg.y + bv.y;
    const float t2 = d2 * r * gg.z + bv.z;
    const float t3 = d3 * r * gg.w + bv.w;
    o.x = 1.f / (1.f + expf(-t0));
    o.y = 1.f / (1.f + expf(-t1));
    o.z = 1.f / (1.f + expf(-t2));
    o.w = 1.f / (1.f + expf(-t3));
    *(float4*)&y[base] = o;
}

// ---------------------------------------------------------------------------
extern "C" void kernel_launch(void* const* d_in, const int* in_sizes, int n_in,
                              void* d_out, int out_size, void* d_ws, size_t ws_size,
                              hipStream_t stream) {
    const float* x      = (const float*)d_in[0];
    const float* W      = (const float*)d_in[1];
    const float* b      = (const float*)d_in[2];
    // d_in[3] = Wq, d_in[4] = keys : dead code (softmax row-sums are 1)
    const float* values = (const float*)d_in[5];
    const float* Wout   = (const float*)d_in[6];
    const float* ln_g   = (const float*)d_in[7];
    const float* ln_b   = (const float*)d_in[8];
    const float* Wf     = (const float*)d_in[9];
    const float* bf     = (const float*)d_in[10];
    const float* lnf_g  = (const float*)d_in[11];
    const float* lnf_b  = (const float*)d_in[12];
    float* out = (float*)d_out;

    // workspace layout (~178 MB):
    char* ws = (char*)d_ws;
    ushort* zbuf = (ushort*)ws;                                  // (B,3072) bf16
    ws += (size_t)Bv * ZLD * sizeof(ushort);                     // 100.7 MB
    float* psum = (float*)ws;                                    // (4,B,256) f32 split-K partials
    ws += (size_t)Bv * Dv * sizeof(float);                       // 67.1 MB
    ushort* Wb = (ushort*)ws;                                    // (L,1024,1024) bf16
    ws += (size_t)Lv * Dv * Dv * sizeof(ushort);                 // 6.3 MB
    ushort* Wfb = (ushort*)ws;                                   // (256,3072) bf16
    ws += (size_t)OUTv * ZLD * sizeof(ushort);                   // 1.6 MB
    float* cvec = (float*)ws;                                    // (L,1024) f32
    ws += (size_t)Lv * Dv * sizeof(float);
    float* vmean = (float*)ws;                                   // (L,256) f32
    ws += (size_t)Lv * Vv * sizeof(float);
    float2* pstats = (float2*)ws;                                // (B,16) f32x2 = 2 MB

    // prep: weight converts, x convert, constant vectors
    {
        const int nW = Lv * Dv * Dv / 8;
        conv_bf16<<<(nW + 255) / 256, 256, 0, stream>>>(W, Wb, nW);
        const int nF = OUTv * ZLD / 8;
        conv_bf16<<<(nF + 255) / 256, 256, 0, stream>>>(Wf, Wfb, nF);
        conv_x<<<Bv * 128 / 256, 256, 0, stream>>>(x, zbuf);
        vmean_kernel<<<Lv, 256, 0, stream>>>(values, vmean);
        cvec_kernel<<<Lv * Dv / 8, 512, 0, stream>>>(vmean, Wout, cvec);
    }

    // layer GEMMs: 256 blocks (64 m-tiles x 4 n-tiles), 1/CU, NT = 1024/64 = 16
    // GEMM writes pre-LN bf16 h + row partial stats directly into zbuf slot;
    // ln_finish normalizes the slot in place.
    for (int i = 0; i < Lv; ++i) {
        const ushort* Ain = (i == 0) ? (zbuf + 2048) : (zbuf + (size_t)(i - 1) * Dv);
        gemm256<0><<<dim3(256), 512, 0, stream>>>(
            Ain, ZLD, Wb + (size_t)i * Dv * Dv, Dv,
            b + (size_t)i * Dv, cvec + (size_t)i * Dv,
            (void*)(zbuf + (size_t)i * Dv), ZLD, /*NT=*/16, /*ksplit=*/0, pstats);
        ln_finish<<<Bv / 4, 256, 0, stream>>>(zbuf + (size_t)i * Dv, pstats,
                                              ln_g + (size_t)i * Dv,
                                              ln_b + (size_t)i * Dv);
    }

    // final GEMM: split-K=4 (64 m-tiles x 4 splits = 256 blocks), K=768 each,
    // NT = 768/64 = 12; raw partials into psum
    gemm256<1><<<dim3(256), 512, 0, stream>>>(
        zbuf, ZLD, Wfb, ZLD, nullptr, nullptr,
        (void*)psum, OUTv, /*NT=*/12, /*ksplit=*/768, pstats);

    ln_sig_reduce<<<Bv / 4, 256, 0, stream>>>(psum, bf, lnf_g, lnf_b, out);
}

// Round 8
// 218.743 us; speedup vs baseline: 8.3307x; 1.1367x over previous
//
#include <hip/hip_runtime.h>
#include <math.h>

#define EPS 1e-5f

constexpr int Bv   = 16384;   // batch
constexpr int Dv   = 1024;    // hidden
constexpr int Lv   = 3;       // blocks
constexpr int NKVv = 128;
constexpr int Vv   = 256;
constexpr int OUTv = 256;
constexpr int ZLD  = Lv * Dv; // 3072 concat width (bf16 buffer row stride)

typedef short bf16x8 __attribute__((ext_vector_type(8)));
typedef float f32x4  __attribute__((ext_vector_type(4)));

using gas_t = __attribute__((address_space(1))) const void;
using las_t = __attribute__((address_space(3))) void;
#define GLD_LDS16(gp, lp) \
    __builtin_amdgcn_global_load_lds((gas_t*)(gp), (las_t*)(lp), 16, 0, 0)

// round-to-nearest-even f32 -> bf16 bits
static __device__ __forceinline__ ushort f2bf(float f) {
    unsigned u = __float_as_uint(f);
    u = (u + 0x7fffu + ((u >> 16) & 1u)) >> 16;
    return (ushort)u;
}

// ---------------------------------------------------------------------------
// prep: vmean_i[v] = mean_n values[i][n][v]; cvec[r] = <vmean tile, Wout row r>
// (softmax rows sum to exactly 1 -> attention == add constant vector)
// ---------------------------------------------------------------------------
__global__ void vmean_kernel(const float* __restrict__ values,
                             float* __restrict__ vmean) {
    const int i = blockIdx.x, t = threadIdx.x;
    const float* vals = values + (size_t)i * NKVv * Vv;
    float s = 0.f;
    for (int n = 0; n < NKVv; ++n) s += vals[n * Vv + t];
    vmean[i * Vv + t] = s * (1.0f / NKVv);
}

__global__ void cvec_kernel(const float* __restrict__ vmean,
                            const float* __restrict__ Wout,
                            float* __restrict__ cvec) {
    const int w = threadIdx.x >> 6, lane = threadIdx.x & 63;
    const int r = blockIdx.x * 8 + w;          // 0..L*1024-1
    const int i = r >> 10;
    const float4 mv = *(const float4*)&vmean[i * Vv + lane * 4];
    const float* row = Wout + (size_t)r * 1024;
    float acc = 0.f;
#pragma unroll
    for (int c = 0; c < 4; ++c) {
        const float4 rv = *(const float4*)&row[c * 256 + lane * 4];
        acc += mv.x * rv.x + mv.y * rv.y + mv.z * rv.z + mv.w * rv.w;
    }
#pragma unroll
    for (int o = 1; o < 64; o <<= 1) acc += __shfl_xor(acc, o, 64);
    if (lane == 0) cvec[r] = acc;
}

// ---------------------------------------------------------------------------
// W (L,1024,1024) f32 -> bf16, folding LN gain of the PREVIOUS layer into the
// K-columns: W'_i[n,k] = W_i[n,k] * g_{i-1}[k] (layer 0 unscaled).
// ---------------------------------------------------------------------------
__global__ void conv_wg(const float* __restrict__ W,
                        const float* __restrict__ lng,
                        ushort* __restrict__ out) {
    const int t = blockIdx.x * 256 + threadIdx.x;   // 393216 threads
    const size_t f = (size_t)t * 8;
    const int i = (int)(f >> 20);
    const int k = (int)(f & 1023);
    const float4 v0 = *(const float4*)&W[f];
    const float4 v1 = *(const float4*)&W[f + 4];
    float4 s0 = make_float4(1.f, 1.f, 1.f, 1.f), s1 = s0;
    if (i > 0) {
        s0 = *(const float4*)&lng[(i - 1) * 1024 + k];
        s1 = *(const float4*)&lng[(i - 1) * 1024 + k + 4];
    }
    ushort4 o0 = {f2bf(v0.x * s0.x), f2bf(v0.y * s0.y), f2bf(v0.z * s0.z), f2bf(v0.w * s0.w)};
    ushort4 o1 = {f2bf(v1.x * s1.x), f2bf(v1.y * s1.y), f2bf(v1.z * s1.z), f2bf(v1.w * s1.w)};
    *(ushort4*)&out[f]     = o0;
    *(ushort4*)&out[f + 4] = o1;
}

// Wf (256,3072) f32 -> bf16 with column scale concat(g_0,g_1,g_2) = ln_g flat.
__global__ void conv_wfg(const float* __restrict__ Wf,
                         const float* __restrict__ lng,
                         ushort* __restrict__ out) {
    const int t = blockIdx.x * 256 + threadIdx.x;   // 98304 threads
    const size_t f = (size_t)t * 8;
    const int c = (int)(f % ZLD);
    const float4 v0 = *(const float4*)&Wf[f];
    const float4 v1 = *(const float4*)&Wf[f + 4];
    const float4 s0 = *(const float4*)&lng[c];
    const float4 s1 = *(const float4*)&lng[c + 4];
    ushort4 o0 = {f2bf(v0.x * s0.x), f2bf(v0.y * s0.y), f2bf(v0.z * s0.z), f2bf(v0.w * s0.w)};
    ushort4 o1 = {f2bf(v1.x * s1.x), f2bf(v1.y * s1.y), f2bf(v1.z * s1.z), f2bf(v1.w * s1.w)};
    *(ushort4*)&out[f]     = o0;
    *(ushort4*)&out[f + 4] = o1;
}

// u_i[n] = <g_{i-1}, W_i[n,:]>, v_i[n] = <lnb_{i-1}, W_i[n,:]>  (i = 1,2)
__global__ void uv_kernel(const float* __restrict__ W,
                          const float* __restrict__ lng,
                          const float* __restrict__ lnb,
                          float* __restrict__ ub, float* __restrict__ vb) {
    const int w = threadIdx.x >> 6, lane = threadIdx.x & 63;
    const int gw = blockIdx.x * 8 + w;        // 0..2047
    const int i = 1 + (gw >> 10), n = gw & 1023;
    const float* Wr = W + ((size_t)i << 20) + ((size_t)n << 10);
    const float* g  = lng + (i - 1) * 1024;
    const float* bb = lnb + (i - 1) * 1024;
    float su = 0.f, sv = 0.f;
#pragma unroll
    for (int c = 0; c < 4; ++c) {
        const int k = c * 256 + lane * 4;
        const float4 wv = *(const float4*)&Wr[k];
        const float4 gv = *(const float4*)&g[k];
        const float4 bv = *(const float4*)&bb[k];
        su += wv.x * gv.x + wv.y * gv.y + wv.z * gv.z + wv.w * gv.w;
        sv += wv.x * bv.x + wv.y * bv.y + wv.z * bv.z + wv.w * bv.w;
    }
#pragma unroll
    for (int o = 1; o < 64; o <<= 1) {
        su += __shfl_xor(su, o, 64);
        sv += __shfl_xor(sv, o, 64);
    }
    if (lane == 0) { ub[(i - 1) * 1024 + n] = su; vb[(i - 1) * 1024 + n] = sv; }
}

// uf_i[n] = <g_i, Wf[n, i-slice]>, vf_i[n] = <lnb_i, Wf[n, i-slice]>  (i=0..2)
__global__ void ufvf_kernel(const float* __restrict__ Wf,
                            const float* __restrict__ lng,
                            const float* __restrict__ lnb,
                            float* __restrict__ uf, float* __restrict__ vf) {
    const int w = threadIdx.x >> 6, lane = threadIdx.x & 63;
    const int gw = blockIdx.x * 8 + w;        // 0..767
    const int i = gw >> 8, n = gw & 255;
    const float* Wr = Wf + (size_t)n * ZLD + i * 1024;
    const float* g  = lng + i * 1024;
    const float* bb = lnb + i * 1024;
    float su = 0.f, sv = 0.f;
#pragma unroll
    for (int c = 0; c < 4; ++c) {
        const int k = c * 256 + lane * 4;
        const float4 wv = *(const float4*)&Wr[k];
        const float4 gv = *(const float4*)&g[k];
        const float4 bv = *(const float4*)&bb[k];
        su += wv.x * gv.x + wv.y * gv.y + wv.z * gv.z + wv.w * gv.w;
        sv += wv.x * bv.x + wv.y * bv.y + wv.z * bv.z + wv.w * bv.w;
    }
#pragma unroll
    for (int o = 1; o < 64; o <<= 1) {
        su += __shfl_xor(su, o, 64);
        sv += __shfl_xor(sv, o, 64);
    }
    if (lane == 0) { uf[i * 256 + n] = su; vf[i * 256 + n] = sv; }
}

// pstats (B,16 float2) -> per-row (mean, rsqrt(var+eps))
__global__ void mr_kernel(const float2* __restrict__ pstats,
                          float2* __restrict__ mr) {
    const int row = blockIdx.x * 256 + threadIdx.x;
    const float4* p = (const float4*)(pstats + ((size_t)row << 4));
    float sum = 0.f, sq = 0.f;
#pragma unroll
    for (int j = 0; j < 8; ++j) {
        const float4 t = p[j];
        sum += t.x + t.z; sq += t.y + t.w;
    }
    const float m = sum * (1.f / Dv);
    const float var = sq * (1.f / Dv) - m * m;
    mr[row] = make_float2(m, rsqrtf(var + EPS));
}

// x (B,1024) f32 -> bf16 into zbuf[:, 2048:3072] (row stride ZLD)
__global__ void conv_x(const float* __restrict__ x, ushort* __restrict__ z) {
    const int t = blockIdx.x * 256 + threadIdx.x;  // B*128 threads
    const int row = t >> 7, c8 = (t & 127) << 3;
    const float4 v0 = *(const float4*)&x[(size_t)row * 1024 + c8];
    const float4 v1 = *(const float4*)&x[(size_t)row * 1024 + c8 + 4];
    ushort4 o0 = {f2bf(v0.x), f2bf(v0.y), f2bf(v0.z), f2bf(v0.w)};
    ushort4 o1 = {f2bf(v1.x), f2bf(v1.y), f2bf(v1.z), f2bf(v1.w)};
    ushort* p = z + (size_t)row * ZLD + 2048 + c8;
    *(ushort4*)p       = o0;
    *(ushort4*)(p + 4) = o1;
}

// ---------------------------------------------------------------------------
// 256x256 bf16 MFMA NT GEMM — 8-phase, counted vmcnt (round-5 symmetric
// 2-deep schedule), XOR bank-swizzle (linear LDS dest; inverse-swizzled
// global source; swizzled ds_read).
//
// MODE 0 (layer 0): val = relu(acc+bias)+cvec; row (sum,sq) -> pstats;
//   bf16 stored coalesced (LDS transpose) into zbuf slot (raw pre-LN h).
// MODE 2 (layers 1,2): LN of the PREVIOUS layer folded in:
//   val = relu(r*acc - r*m*u[col] + v[col] + bias[col]) + cvec[col],
//   (m,r) per row from mrp (preloaded to LDS). Rest as MODE 0.
// MODE 1 (final, split-K by layer): raw f32 acc -> psum + bx*(Bv*256),
//   n0=0, koff=bx*1024; LN fold applied later in ln_sig_reduce.
// Grid: 256 blocks (MODE 0/2) or 192 blocks (MODE 1), 512 threads.
// ---------------------------------------------------------------------------
#define READ_A(QR, DD)                                                        \
    do { _Pragma("unroll")                                                    \
        for (int mf = 0; mf < 4; ++mf) {                                      \
            const int _o = (DD) * 16384 + (QR) * 8192 + (arow_l + mf * 16) * 64; \
            aR[mf][0] = *(const bf16x8*)&As[_o + ck0];                        \
            aR[mf][1] = *(const bf16x8*)&As[_o + ck1];                        \
        } } while (0)

#define READ_B(QC, DD, BR)                                                    \
    do { _Pragma("unroll")                                                    \
        for (int nf = 0; nf < 2; ++nf) {                                      \
            const int _o = (DD) * 16384 + (QC) * 8192 + (brow_l + nf * 16) * 64; \
            BR[nf][0] = *(const bf16x8*)&Bs[_o + ck0];                        \
            BR[nf][1] = *(const bf16x8*)&Bs[_o + ck1];                        \
        } } while (0)

#define STAGE_A(KT, H, DD)                                                    \
    do { const ushort* _p = gAs + (size_t)((H) * 128 + w16) * lda + (KT) * 64; \
         ushort* _l = As + (DD) * 16384 + (H) * 8192 + w16 * 64;              \
         GLD_LDS16(_p, _l);                                                   \
         GLD_LDS16(_p + (size_t)8 * lda, _l + 512); } while (0)

#define STAGE_B(KT, H, DD)                                                    \
    do { const ushort* _p = gBs + (size_t)((H) * 128 + w16) * ldb + (KT) * 64; \
         ushort* _l = Bs + (DD) * 16384 + (H) * 8192 + w16 * 64;              \
         GLD_LDS16(_p, _l);                                                   \
         GLD_LDS16(_p + (size_t)8 * ldb, _l + 512); } while (0)

#define MFMA_Q(QR, QC, BR)                                                    \
    do { __builtin_amdgcn_s_setprio(1);                                       \
        _Pragma("unroll")                                                     \
        for (int mf = 0; mf < 4; ++mf) {                                      \
            _Pragma("unroll")                                                 \
            for (int nf = 0; nf < 2; ++nf) {                                  \
                acc[QR][QC][mf][nf] = __builtin_amdgcn_mfma_f32_16x16x32_bf16( \
                    aR[mf][0], BR[nf][0], acc[QR][QC][mf][nf], 0, 0, 0);      \
                acc[QR][QC][mf][nf] = __builtin_amdgcn_mfma_f32_16x16x32_bf16( \
                    aR[mf][1], BR[nf][1], acc[QR][QC][mf][nf], 0, 0, 0);      \
            }                                                                 \
        }                                                                     \
        __builtin_amdgcn_s_setprio(0); } while (0)

template<int MODE>
__global__ __launch_bounds__(512, 1)
void gemm256(const ushort* __restrict__ A, int lda,
             const ushort* __restrict__ Bw, int ldb,
             const float* __restrict__ bias,
             const float* __restrict__ cvec,
             const float* __restrict__ u_,
             const float* __restrict__ v_,
             const float2* __restrict__ mrp,
             void* __restrict__ Cv, int ldc,
             int NT, int ksplit,
             float2* __restrict__ pstats) {
    // 134 KiB: main loop As(64K)+Bs(64K); epilogue mr(2K) + bf16 tile [256][264]
    __shared__ __align__(16) char smem[137216];
    ushort* As = (ushort*)smem;            // [2][2][128][64]
    ushort* Bs = (ushort*)(smem + 65536);  // [2][2][128][64]
    const int tid  = threadIdx.x;
    const int lane = tid & 63;
    const int w    = tid >> 6;        // wave 0..7
    const int wr2  = w >> 2, wc2 = w & 3;
    const int w16  = w * 16;

    // XCD-chunked swizzle (bijective: nwg % 8 == 0)
    const int wg  = blockIdx.x;
    const int qchunk = (MODE == 1) ? 24 : 32;
    const int swz = (wg & 7) * qchunk + (wg >> 3);
    const int by  = swz & 63;
    const int bx  = swz >> 6;
    const int m0  = by * 256;
    const int n0  = (MODE == 1) ? 0 : bx * 256;
    const int koff = (MODE == 1) ? bx * ksplit : 0;

    // staging source (inverse-XOR-swizzled column chunk; LDS dest is linear)
    const int swzc = ((lane & 7) ^ ((lane >> 3) & 7)) << 3;
    const ushort* gAs = A  + (size_t)(m0 + (lane >> 3)) * lda + koff + swzc;
    const ushort* gBs = Bw + (size_t)(n0 + (lane >> 3)) * ldb + koff + swzc;

    const int arow_l = wr2 * 64 + (lane & 15);
    const int brow_l = wc2 * 32 + (lane & 15);
    const int ck0 = (((lane >> 4))     ^ (lane & 7)) << 3;   // ks=0 chunk
    const int ck1 = ((4 + (lane >> 4)) ^ (lane & 7)) << 3;   // ks=1 chunk

    f32x4 acc[2][2][4][2] = {};
    bf16x8 aR[4][2], bR0[2][2], bR1[2][2];

    // prologue: tile 0 halves in steady-state stage order a0,b0,b1,a1
    STAGE_A(0, 0, 0);
    STAGE_B(0, 0, 0);
    STAGE_B(0, 1, 0);
    STAGE_A(0, 1, 0);

    for (int t = 0; t < NT; ++t) {
        const int d  = t & 1;
        const int e2 = d ^ 1;
        const bool pf = (t + 1) < NT;
        // ---- phase 0: Q(0,0)
        asm volatile("s_waitcnt vmcnt(4)" ::: "memory");
        __builtin_amdgcn_s_barrier();
        READ_A(0, d);
        READ_B(0, d, bR0);
        if (pf) STAGE_A(t + 1, 0, e2);
        MFMA_Q(0, 0, bR0);
        // ---- phase 1: Q(0,1)
        if (pf) asm volatile("s_waitcnt vmcnt(4)" ::: "memory");
        else    asm volatile("s_waitcnt vmcnt(2)" ::: "memory");
        __builtin_amdgcn_s_barrier();
        READ_B(1, d, bR1);
        if (pf) STAGE_B(t + 1, 0, e2);
        MFMA_Q(0, 1, bR1);
        // ---- phase 2: Q(1,1)
        if (pf) asm volatile("s_waitcnt vmcnt(4)" ::: "memory");
        else    asm volatile("s_waitcnt vmcnt(0)" ::: "memory");
        __builtin_amdgcn_s_barrier();
        READ_A(1, d);
        if (pf) STAGE_B(t + 1, 1, e2);
        MFMA_Q(1, 1, bR1);
        // ---- phase 3: Q(1,0); register reuse, no reads
        if (pf) STAGE_A(t + 1, 1, e2);
        MFMA_Q(1, 0, bR0);
    }

    // epilogue: C/D layout col = lane&15, row = (lane>>4)*4 + r  [m89-verified]
    const int lg4 = (lane >> 4) << 2;
    if (MODE != 1) {
        float bsv[2][2], csv[2][2], uu[2][2], vv[2][2];
#pragma unroll
        for (int qc = 0; qc < 2; ++qc)
#pragma unroll
            for (int nf = 0; nf < 2; ++nf) {
                const int col = n0 + qc * 128 + wc2 * 32 + nf * 16 + (lane & 15);
                bsv[qc][nf] = bias[col];
                csv[qc][nf] = cvec[col];
                if (MODE == 2) { uu[qc][nf] = u_[col]; vv[qc][nf] = v_[col]; }
            }
        __syncthreads();                       // staging LDS dead in all waves
        float2* mrs = (float2*)smem;           // [256] (m,r) of this block's rows
        if (MODE == 2) {
            if (tid < 256) mrs[tid] = mrp[m0 + tid];
            __syncthreads();
        }
        // fused epilogue + LN pass 1 (row partials over this block's 256 cols)
#pragma unroll
        for (int qr = 0; qr < 2; ++qr)
#pragma unroll
            for (int mf = 0; mf < 4; ++mf)
#pragma unroll
                for (int r = 0; r < 4; ++r) {
                    const int rloc = qr * 128 + wr2 * 64 + mf * 16 + lg4 + r;
                    float rw = 1.f, rmw = 0.f;
                    if (MODE == 2) {
                        const float2 q = mrs[rloc];
                        rw = q.y; rmw = q.y * q.x;
                    }
                    float sum = 0.f, sq = 0.f;
#pragma unroll
                    for (int qc = 0; qc < 2; ++qc)
#pragma unroll
                        for (int nf = 0; nf < 2; ++nf) {
                            float a = acc[qr][qc][mf][nf][r];
                            float val;
                            if (MODE == 2)
                                val = fmaf(rw, a, fmaf(-rmw, uu[qc][nf],
                                          vv[qc][nf] + bsv[qc][nf]));
                            else
                                val = a + bsv[qc][nf];
                            val = fmaxf(val, 0.f) + csv[qc][nf];
                            acc[qr][qc][mf][nf][r] = val;
                            sum += val; sq += val * val;
                        }
#pragma unroll
                    for (int o = 1; o < 16; o <<= 1) {
                        sum += __shfl_xor(sum, o, 64);
                        sq  += __shfl_xor(sq,  o, 64);
                    }
                    if ((lane & 15) == 0)
                        pstats[(((size_t)(m0 + rloc)) << 4) + (bx << 2) + wc2] =
                            make_float2(sum, sq);
                }
        // bf16 transpose tile (at +2048, no overlap with mrs) + coalesced store
        ushort* tile = (ushort*)(smem + 2048);   // [256][264], 528B rows
#pragma unroll
        for (int qr = 0; qr < 2; ++qr)
#pragma unroll
            for (int qc = 0; qc < 2; ++qc)
#pragma unroll
                for (int mf = 0; mf < 4; ++mf)
#pragma unroll
                    for (int nf = 0; nf < 2; ++nf)
#pragma unroll
                        for (int r = 0; r < 4; ++r) {
                            const int rloc = qr * 128 + wr2 * 64 + mf * 16 + lg4 + r;
                            const int cloc = qc * 128 + wc2 * 32 + nf * 16 + (lane & 15);
                            tile[rloc * 264 + cloc] = f2bf(acc[qr][qc][mf][nf][r]);
                        }
        __syncthreads();
        ushort* C16 = (ushort*)Cv;
        for (int c = tid; c < 256 * 32; c += 512) {
            const int row = c >> 5, ch = (c & 31) << 3;
            const bf16x8 v = *(const bf16x8*)&tile[row * 264 + ch];
            *(bf16x8*)&C16[(size_t)(m0 + row) * ldc + n0 + ch] = v;
        }
    } else {
        // MODE 1: raw f32 split-K partials (layer-aligned)
        const int cbase = lane & 15;
        float* Cb = (float*)Cv + (size_t)bx * ((size_t)Bv * OUTv);
#pragma unroll
        for (int qr = 0; qr < 2; ++qr)
#pragma unroll
            for (int qc = 0; qc < 2; ++qc)
#pragma unroll
                for (int nf = 0; nf < 2; ++nf) {
                    const int col = qc * 128 + wc2 * 32 + nf * 16 + cbase;
#pragma unroll
                    for (int mf = 0; mf < 4; ++mf) {
                        const int row = m0 + qr * 128 + wr2 * 64 + mf * 16 + lg4;
#pragma unroll
                        for (int r = 0; r < 4; ++r)
                            Cb[(size_t)(row + r) * ldc + col] = acc[qr][qc][mf][nf][r];
                    }
                }
    }
}

// ---------------------------------------------------------------------------
// Final: per-layer LN-folded reduce + bias + LayerNorm(256) + sigmoid.
// val[n] = sum_i r_i*(ps_i[n] - m_i*uf_i[n]) + sum_i vf_i[n] + bf[n]
// 4 rows/block, 1 wave per row, 4 cols/lane.
// ---------------------------------------------------------------------------
__global__ void ln_sig_reduce(const float* __restrict__ ps,
                              const float2* __restrict__ mr,   // (3,B)
                              const float* __restrict__ uf,    // (3,256)
                              const float* __restrict__ vf,    // (3,256)
                              const float* __restrict__ bf_,
                              const float* __restrict__ g,
                              const float* __restrict__ bb,
                              float* __restrict__ y) {
    const int lane = threadIdx.x & 63;
    const int row  = blockIdx.x * 4 + (threadIdx.x >> 6);
    const size_t base = (size_t)row * OUTv + lane * 4;
    const size_t SP = (size_t)Bv * OUTv;
    const float2 q0 = mr[row];
    const float2 q1 = mr[Bv + row];
    const float2 q2 = mr[2 * Bv + row];
    const float4 p0 = *(const float4*)&ps[base];
    const float4 p1 = *(const float4*)&ps[base + SP];
    const float4 p2 = *(const float4*)&ps[base + 2 * SP];
    const float4 u0 = *(const float4*)&uf[lane * 4];
    const float4 u1 = *(const float4*)&uf[256 + lane * 4];
    const float4 u2 = *(const float4*)&uf[512 + lane * 4];
    const float4 f0 = *(const float4*)&vf[lane * 4];
    const float4 f1 = *(const float4*)&vf[256 + lane * 4];
    const float4 f2 = *(const float4*)&vf[512 + lane * 4];
    const float4 bv4 = *(const float4*)&bf_[lane * 4];
    const float cst_x = f0.x + f1.x + f2.x + bv4.x;
    const float cst_y = f0.y + f1.y + f2.y + bv4.y;
    const float cst_z = f0.z + f1.z + f2.z + bv4.z;
    const float cst_w = f0.w + f1.w + f2.w + bv4.w;
    const float v0 = q0.y * (p0.x - q0.x * u0.x) + q1.y * (p1.x - q1.x * u1.x)
                   + q2.y * (p2.x - q2.x * u2.x) + cst_x;
    const float v1 = q0.y * (p0.y - q0.x * u0.y) + q1.y * (p1.y - q1.x * u1.y)
                   + q2.y * (p2.y - q2.x * u2.y) + cst_y;
    const float v2 = q0.y * (p0.z - q0.x * u0.z) + q1.y * (p1.z - q1.x * u1.z)
                   + q2.y * (p2.z - q2.x * u2.z) + cst_z;
    const float v3 = q0.y * (p0.w - q0.x * u0.w) + q1.y * (p1.w - q1.x * u1.w)
                   + q2.y * (p2.w - q2.x * u2.w) + cst_w;
    float s = v0 + v1 + v2 + v3;
#pragma unroll
    for (int o = 1; o < 64; o <<= 1) s += __shfl_xor(s, o, 64);
    const float mean = s * (1.f / OUTv);
    const float d0 = v0 - mean, d1 = v1 - mean, d2 = v2 - mean, d3 = v3 - mean;
    float q = d0 * d0 + d1 * d1 + d2 * d2 + d3 * d3;
#pragma unroll
    for (int o = 1; o < 64; o <<= 1) q += __shfl_xor(q, o, 64);
    const float r = rsqrtf(q * (1.f / OUTv) + EPS);
    const float4 gg = *(const float4*)&g[lane * 4];
    const float4 bv = *(const float4*)&bb[lane * 4];
    float4 o;
    const float t0 = d0 * r * gg.x + bv.x;
    const float t1 = d1 * r * gg.y + bv.y;
    const float t2 = d2 * r * gg.z + bv.z;
    const float t3 = d3 * r * gg.w + bv.w;
    o.x = 1.f / (1.f + expf(-t0));
    o.y = 1.f / (1.f + expf(-t1));
    o.z = 1.f / (1.f + expf(-t2));
    o.w = 1.f / (1.f + expf(-t3));
    *(float4*)&y[base] = o;
}

// ---------------------------------------------------------------------------
extern "C" void kernel_launch(void* const* d_in, const int* in_sizes, int n_in,
                              void* d_out, int out_size, void* d_ws, size_t ws_size,
                              hipStream_t stream) {
    const float* x      = (const float*)d_in[0];
    const float* W      = (const float*)d_in[1];
    const float* b      = (const float*)d_in[2];
    // d_in[3] = Wq, d_in[4] = keys : dead code (softmax row-sums are 1)
    const float* values = (const float*)d_in[5];
    const float* Wout   = (const float*)d_in[6];
    const float* ln_g   = (const float*)d_in[7];
    const float* ln_b   = (const float*)d_in[8];
    const float* Wf     = (const float*)d_in[9];
    const float* bf     = (const float*)d_in[10];
    const float* lnf_g  = (const float*)d_in[11];
    const float* lnf_b  = (const float*)d_in[12];
    float* out = (float*)d_out;

    // workspace layout (~179 MB):
    char* ws = (char*)d_ws;
    ushort* zbuf = (ushort*)ws;                                  // (B,3072) bf16 RAW h + xb
    ws += (size_t)Bv * ZLD * sizeof(ushort);                     // 100.7 MB
    float* psum = (float*)ws;                                    // (3,B,256) f32 split-K partials
    ws += (size_t)Bv * Dv * sizeof(float);                       // 67.1 MB (50.3 used)
    ushort* Wb = (ushort*)ws;                                    // (L,1024,1024) bf16 g-folded
    ws += (size_t)Lv * Dv * Dv * sizeof(ushort);                 // 6.3 MB
    ushort* Wfb = (ushort*)ws;                                   // (256,3072) bf16 g-folded
    ws += (size_t)OUTv * ZLD * sizeof(ushort);                   // 1.6 MB
    float* cvec = (float*)ws;                                    // (L,1024)
    ws += (size_t)Lv * Dv * sizeof(float);
    float* vmean = (float*)ws;                                   // (L,256)
    ws += (size_t)Lv * Vv * sizeof(float);
    float2* pstats = (float2*)ws;                                // (B,16) = 2 MB
    ws += (size_t)Bv * 16 * sizeof(float2);
    float2* mr3 = (float2*)ws;                                   // (3,B) = 384 KB
    ws += (size_t)3 * Bv * sizeof(float2);
    float* ub = (float*)ws; ws += 2 * Dv * sizeof(float);        // (2,1024)
    float* vb = (float*)ws; ws += 2 * Dv * sizeof(float);
    float* uf = (float*)ws; ws += 3 * OUTv * sizeof(float);      // (3,256)
    float* vf = (float*)ws; ws += 3 * OUTv * sizeof(float);

    // prep
    conv_wg<<<1536, 256, 0, stream>>>(W, ln_g, Wb);
    conv_wfg<<<384, 256, 0, stream>>>(Wf, ln_g, Wfb);
    conv_x<<<Bv * 128 / 256, 256, 0, stream>>>(x, zbuf);
    vmean_kernel<<<Lv, 256, 0, stream>>>(values, vmean);
    cvec_kernel<<<Lv * Dv / 8, 512, 0, stream>>>(vmean, Wout, cvec);
    uv_kernel<<<256, 512, 0, stream>>>(W, ln_g, ln_b, ub, vb);
    ufvf_kernel<<<96, 512, 0, stream>>>(Wf, ln_g, ln_b, uf, vf);

    // layer 0: A = xb (cols 2048:3072), plain epilogue
    gemm256<0><<<dim3(256), 512, 0, stream>>>(
        zbuf + 2048, ZLD, Wb, Dv,
        b, cvec, nullptr, nullptr, nullptr,
        (void*)(zbuf + 0), ZLD, /*NT=*/16, 0, pstats);
    mr_kernel<<<Bv / 256, 256, 0, stream>>>(pstats, mr3);

    // layers 1,2: LN of previous layer folded into the GEMM
    for (int i = 1; i < Lv; ++i) {
        gemm256<2><<<dim3(256), 512, 0, stream>>>(
            zbuf + (size_t)(i - 1) * Dv, ZLD, Wb + (size_t)i * Dv * Dv, Dv,
            b + (size_t)i * Dv, cvec + (size_t)i * Dv,
            ub + (size_t)(i - 1) * Dv, vb + (size_t)(i - 1) * Dv,
            mr3 + (size_t)(i - 1) * Bv,
            (void*)(zbuf + (size_t)i * Dv), ZLD, /*NT=*/16, 0, pstats);
        mr_kernel<<<Bv / 256, 256, 0, stream>>>(pstats, mr3 + (size_t)i * Bv);
    }

    // final GEMM: split-K aligned to layers (3 x K=1024), 192 blocks,
    // raw partials; LN folds applied in the reduce.
    gemm256<1><<<dim3(192), 512, 0, stream>>>(
        zbuf, ZLD, Wfb, ZLD, nullptr, nullptr,
        nullptr, nullptr, nullptr,
        (void*)psum, OUTv, /*NT=*/16, /*ksplit=*/1024, pstats);

    ln_sig_reduce<<<Bv / 4, 256, 0, stream>>>(psum, mr3, uf, vf, bf,
                                              lnf_g, lnf_b, out);
}

// Round 9
// 218.406 us; speedup vs baseline: 8.3436x; 1.0015x over previous
//
#include <hip/hip_runtime.h>
#include <math.h>

#define EPS 1e-5f

constexpr int Bv   = 16384;   // batch
constexpr int Dv   = 1024;    // hidden
constexpr int Lv   = 3;       // blocks
constexpr int NKVv = 128;
constexpr int Vv   = 256;
constexpr int OUTv = 256;
constexpr int ZLD  = Lv * Dv; // 3072 concat width (bf16 buffer row stride)

typedef short bf16x8 __attribute__((ext_vector_type(8)));
typedef float f32x4  __attribute__((ext_vector_type(4)));

using gas_t = __attribute__((address_space(1))) const void;
using las_t = __attribute__((address_space(3))) void;
#define GLD_LDS16(gp, lp) \
    __builtin_amdgcn_global_load_lds((gas_t*)(gp), (las_t*)(lp), 16, 0, 0)

// round-to-nearest-even f32 -> bf16 bits
static __device__ __forceinline__ ushort f2bf(float f) {
    unsigned u = __float_as_uint(f);
    u = (u + 0x7fffu + ((u >> 16) & 1u)) >> 16;
    return (ushort)u;
}

// ---------------------------------------------------------------------------
// prep: vmean_i[v] = mean_n values[i][n][v]; cvec[r] = <vmean tile, Wout row r>
// (softmax rows sum to exactly 1 -> attention == add constant vector)
// ---------------------------------------------------------------------------
__global__ void vmean_kernel(const float* __restrict__ values,
                             float* __restrict__ vmean) {
    const int i = blockIdx.x, t = threadIdx.x;
    const float* vals = values + (size_t)i * NKVv * Vv;
    float s = 0.f;
    for (int n = 0; n < NKVv; ++n) s += vals[n * Vv + t];
    vmean[i * Vv + t] = s * (1.0f / NKVv);
}

__global__ void cvec_kernel(const float* __restrict__ vmean,
                            const float* __restrict__ Wout,
                            float* __restrict__ cvec) {
    const int w = threadIdx.x >> 6, lane = threadIdx.x & 63;
    const int r = blockIdx.x * 8 + w;          // 0..L*1024-1
    const int i = r >> 10;
    const float4 mv = *(const float4*)&vmean[i * Vv + lane * 4];
    const float* row = Wout + (size_t)r * 1024;
    float acc = 0.f;
#pragma unroll
    for (int c = 0; c < 4; ++c) {
        const float4 rv = *(const float4*)&row[c * 256 + lane * 4];
        acc += mv.x * rv.x + mv.y * rv.y + mv.z * rv.z + mv.w * rv.w;
    }
#pragma unroll
    for (int o = 1; o < 64; o <<= 1) acc += __shfl_xor(acc, o, 64);
    if (lane == 0) cvec[r] = acc;
}

// ---------------------------------------------------------------------------
// W (L,1024,1024) f32 -> bf16, folding LN gain of the PREVIOUS layer into the
// K-columns: W'_i[n,k] = W_i[n,k] * g_{i-1}[k] (layer 0 unscaled).
// ---------------------------------------------------------------------------
__global__ void conv_wg(const float* __restrict__ W,
                        const float* __restrict__ lng,
                        ushort* __restrict__ out) {
    const int t = blockIdx.x * 256 + threadIdx.x;   // 393216 threads
    const size_t f = (size_t)t * 8;
    const int i = (int)(f >> 20);
    const int k = (int)(f & 1023);
    const float4 v0 = *(const float4*)&W[f];
    const float4 v1 = *(const float4*)&W[f + 4];
    float4 s0 = make_float4(1.f, 1.f, 1.f, 1.f), s1 = s0;
    if (i > 0) {
        s0 = *(const float4*)&lng[(i - 1) * 1024 + k];
        s1 = *(const float4*)&lng[(i - 1) * 1024 + k + 4];
    }
    ushort4 o0 = {f2bf(v0.x * s0.x), f2bf(v0.y * s0.y), f2bf(v0.z * s0.z), f2bf(v0.w * s0.w)};
    ushort4 o1 = {f2bf(v1.x * s1.x), f2bf(v1.y * s1.y), f2bf(v1.z * s1.z), f2bf(v1.w * s1.w)};
    *(ushort4*)&out[f]     = o0;
    *(ushort4*)&out[f + 4] = o1;
}

// Wf (256,3072) f32 -> bf16 with column scale concat(g_0,g_1,g_2) = ln_g flat.
__global__ void conv_wfg(const float* __restrict__ Wf,
                         const float* __restrict__ lng,
                         ushort* __restrict__ out) {
    const int t = blockIdx.x * 256 + threadIdx.x;   // 98304 threads
    const size_t f = (size_t)t * 8;
    const int c = (int)(f % ZLD);
    const float4 v0 = *(const float4*)&Wf[f];
    const float4 v1 = *(const float4*)&Wf[f + 4];
    const float4 s0 = *(const float4*)&lng[c];
    const float4 s1 = *(const float4*)&lng[c + 4];
    ushort4 o0 = {f2bf(v0.x * s0.x), f2bf(v0.y * s0.y), f2bf(v0.z * s0.z), f2bf(v0.w * s0.w)};
    ushort4 o1 = {f2bf(v1.x * s1.x), f2bf(v1.y * s1.y), f2bf(v1.z * s1.z), f2bf(v1.w * s1.w)};
    *(ushort4*)&out[f]     = o0;
    *(ushort4*)&out[f + 4] = o1;
}

// u_i[n] = <g_{i-1}, W_i[n,:]>, v_i[n] = <lnb_{i-1}, W_i[n,:]>  (i = 1,2)
__global__ void uv_kernel(const float* __restrict__ W,
                          const float* __restrict__ lng,
                          const float* __restrict__ lnb,
                          float* __restrict__ ub, float* __restrict__ vb) {
    const int w = threadIdx.x >> 6, lane = threadIdx.x & 63;
    const int gw = blockIdx.x * 8 + w;        // 0..2047
    const int i = 1 + (gw >> 10), n = gw & 1023;
    const float* Wr = W + ((size_t)i << 20) + ((size_t)n << 10);
    const float* g  = lng + (i - 1) * 1024;
    const float* bb = lnb + (i - 1) * 1024;
    float su = 0.f, sv = 0.f;
#pragma unroll
    for (int c = 0; c < 4; ++c) {
        const int k = c * 256 + lane * 4;
        const float4 wv = *(const float4*)&Wr[k];
        const float4 gv = *(const float4*)&g[k];
        const float4 bv = *(const float4*)&bb[k];
        su += wv.x * gv.x + wv.y * gv.y + wv.z * gv.z + wv.w * gv.w;
        sv += wv.x * bv.x + wv.y * bv.y + wv.z * bv.z + wv.w * bv.w;
    }
#pragma unroll
    for (int o = 1; o < 64; o <<= 1) {
        su += __shfl_xor(su, o, 64);
        sv += __shfl_xor(sv, o, 64);
    }
    if (lane == 0) { ub[(i - 1) * 1024 + n] = su; vb[(i - 1) * 1024 + n] = sv; }
}

// uf_i[n] = <g_i, Wf[n, i-slice]>, vf_i[n] = <lnb_i, Wf[n, i-slice]>  (i=0..2)
__global__ void ufvf_kernel(const float* __restrict__ Wf,
                            const float* __restrict__ lng,
                            const float* __restrict__ lnb,
                            float* __restrict__ uf, float* __restrict__ vf) {
    const int w = threadIdx.x >> 6, lane = threadIdx.x & 63;
    const int gw = blockIdx.x * 8 + w;        // 0..767
    const int i = gw >> 8, n = gw & 255;
    const float* Wr = Wf + (size_t)n * ZLD + i * 1024;
    const float* g  = lng + i * 1024;
    const float* bb = lnb + i * 1024;
    float su = 0.f, sv = 0.f;
#pragma unroll
    for (int c = 0; c < 4; ++c) {
        const int k = c * 256 + lane * 4;
        const float4 wv = *(const float4*)&Wr[k];
        const float4 gv = *(const float4*)&g[k];
        const float4 bv = *(const float4*)&bb[k];
        su += wv.x * gv.x + wv.y * gv.y + wv.z * gv.z + wv.w * gv.w;
        sv += wv.x * bv.x + wv.y * bv.y + wv.z * bv.z + wv.w * bv.w;
    }
#pragma unroll
    for (int o = 1; o < 64; o <<= 1) {
        su += __shfl_xor(su, o, 64);
        sv += __shfl_xor(sv, o, 64);
    }
    if (lane == 0) { uf[i * 256 + n] = su; vf[i * 256 + n] = sv; }
}

// pstats (B,16 float2) -> per-row (mean, rsqrt(var+eps))
__global__ void mr_kernel(const float2* __restrict__ pstats,
                          float2* __restrict__ mr) {
    const int row = blockIdx.x * 256 + threadIdx.x;
    const float4* p = (const float4*)(pstats + ((size_t)row << 4));
    float sum = 0.f, sq = 0.f;
#pragma unroll
    for (int j = 0; j < 8; ++j) {
        const float4 t = p[j];
        sum += t.x + t.z; sq += t.y + t.w;
    }
    const float m = sum * (1.f / Dv);
    const float var = sq * (1.f / Dv) - m * m;
    mr[row] = make_float2(m, rsqrtf(var + EPS));
}

// x (B,1024) f32 -> bf16 into zbuf[:, 2048:3072] (row stride ZLD)
__global__ void conv_x(const float* __restrict__ x, ushort* __restrict__ z) {
    const int t = blockIdx.x * 256 + threadIdx.x;  // B*128 threads
    const int row = t >> 7, c8 = (t & 127) << 3;
    const float4 v0 = *(const float4*)&x[(size_t)row * 1024 + c8];
    const float4 v1 = *(const float4*)&x[(size_t)row * 1024 + c8 + 4];
    ushort4 o0 = {f2bf(v0.x), f2bf(v0.y), f2bf(v0.z), f2bf(v0.w)};
    ushort4 o1 = {f2bf(v1.x), f2bf(v1.y), f2bf(v1.z), f2bf(v1.w)};
    ushort* p = z + (size_t)row * ZLD + 2048 + c8;
    *(ushort4*)p       = o0;
    *(ushort4*)(p + 4) = o1;
}

// ---------------------------------------------------------------------------
// 256x256 bf16 MFMA NT GEMM — read-early phase schedule: per phase
// {ds_reads(this phase's MFMA operands); stage; counted vmcnt; barrier; MFMA}.
// Each read-set's residency is bound by the PREVIOUS phase's vmcnt+barrier,
// so LDS-read latency hides in the barrier wait (m201's key trick).
// 3 barriers/tile (ph2+ph3 merged — ph2's barrier guarded nothing).
// XOR bank-swizzle: linear LDS dest, inverse-swizzled global source,
// swizzled ds_read (round-trip verified).
//
// FIFO trace (steady state, stage order A0,B0,B1,A1 @ 2 loads/phase):
//  ph0 end: vmcnt(4) -> binds B1(t)   [newest4: A1(t), A0(t+1)]
//  ph1 end: vmcnt(4) -> binds A1(t)   [newest4: A0(t+1), B0(t+1)]
//  ph23end: vmcnt(4) -> binds A0,B0(t+1) [newest4: B1(t+1), A1(t+1)]
//  prologue: 4 stages + vmcnt(4)+bar == same guarantee as ph23 end.
//  tail (t==NT-1): ph0 vmcnt(2), ph1 vmcnt(0).
//
// MODE 0 (layer 0): val = relu(acc+bias)+cvec; row (sum,sq) -> pstats;
//   bf16 stored coalesced (LDS transpose) into zbuf slot (raw pre-LN h).
// MODE 2 (layers 1,2): LN of previous layer folded:
//   val = relu(r*acc - r*m*u[col] + v[col] + bias[col]) + cvec[col].
// MODE 1 (final, split-K by layer): raw f32 acc -> psum + bx*(Bv*256).
// Grid: 256 blocks (MODE 0/2) or 192 blocks (MODE 1), 512 threads.
// ---------------------------------------------------------------------------
#define READ_A(QR, DD)                                                        \
    do { _Pragma("unroll")                                                    \
        for (int mf = 0; mf < 4; ++mf) {                                      \
            const int _o = (DD) * 16384 + (QR) * 8192 + (arow_l + mf * 16) * 64; \
            aR[mf][0] = *(const bf16x8*)&As[_o + ck0];                        \
            aR[mf][1] = *(const bf16x8*)&As[_o + ck1];                        \
        } } while (0)

#define READ_B(QC, DD, BR)                                                    \
    do { _Pragma("unroll")                                                    \
        for (int nf = 0; nf < 2; ++nf) {                                      \
            const int _o = (DD) * 16384 + (QC) * 8192 + (brow_l + nf * 16) * 64; \
            BR[nf][0] = *(const bf16x8*)&Bs[_o + ck0];                        \
            BR[nf][1] = *(const bf16x8*)&Bs[_o + ck1];                        \
        } } while (0)

#define STAGE_A(KT, H, DD)                                                    \
    do { const ushort* _p = gAs + (size_t)((H) * 128 + w16) * lda + (KT) * 64; \
         ushort* _l = As + (DD) * 16384 + (H) * 8192 + w16 * 64;              \
         GLD_LDS16(_p, _l);                                                   \
         GLD_LDS16(_p + (size_t)8 * lda, _l + 512); } while (0)

#define STAGE_B(KT, H, DD)                                                    \
    do { const ushort* _p = gBs + (size_t)((H) * 128 + w16) * ldb + (KT) * 64; \
         ushort* _l = Bs + (DD) * 16384 + (H) * 8192 + w16 * 64;              \
         GLD_LDS16(_p, _l);                                                   \
         GLD_LDS16(_p + (size_t)8 * ldb, _l + 512); } while (0)

#define MFMA_Q(QR, QC, BR)                                                    \
    do { __builtin_amdgcn_s_setprio(1);                                       \
        _Pragma("unroll")                                                     \
        for (int mf = 0; mf < 4; ++mf) {                                      \
            _Pragma("unroll")                                                 \
            for (int nf = 0; nf < 2; ++nf) {                                  \
                acc[QR][QC][mf][nf] = __builtin_amdgcn_mfma_f32_16x16x32_bf16( \
                    aR[mf][0], BR[nf][0], acc[QR][QC][mf][nf], 0, 0, 0);      \
                acc[QR][QC][mf][nf] = __builtin_amdgcn_mfma_f32_16x16x32_bf16( \
                    aR[mf][1], BR[nf][1], acc[QR][QC][mf][nf], 0, 0, 0);      \
            }                                                                 \
        }                                                                     \
        __builtin_amdgcn_s_setprio(0); } while (0)

template<int MODE>
__global__ __launch_bounds__(512, 1)
void gemm256(const ushort* __restrict__ A, int lda,
             const ushort* __restrict__ Bw, int ldb,
             const float* __restrict__ bias,
             const float* __restrict__ cvec,
             const float* __restrict__ u_,
             const float* __restrict__ v_,
             const float2* __restrict__ mrp,
             void* __restrict__ Cv, int ldc,
             int NT, int ksplit,
             float2* __restrict__ pstats) {
    // 134 KiB: main loop As(64K)+Bs(64K); epilogue mr(2K) + bf16 tile [256][264]
    __shared__ __align__(16) char smem[137216];
    ushort* As = (ushort*)smem;            // [2][2][128][64]
    ushort* Bs = (ushort*)(smem + 65536);  // [2][2][128][64]
    const int tid  = threadIdx.x;
    const int lane = tid & 63;
    const int w    = tid >> 6;        // wave 0..7
    const int wr2  = w >> 2, wc2 = w & 3;
    const int w16  = w * 16;

    // XCD-chunked swizzle (bijective: nwg % 8 == 0)
    const int wg  = blockIdx.x;
    const int qchunk = (MODE == 1) ? 24 : 32;
    const int swz = (wg & 7) * qchunk + (wg >> 3);
    const int by  = swz & 63;
    const int bx  = swz >> 6;
    const int m0  = by * 256;
    const int n0  = (MODE == 1) ? 0 : bx * 256;
    const int koff = (MODE == 1) ? bx * ksplit : 0;

    // staging source (inverse-XOR-swizzled column chunk; LDS dest is linear)
    const int swzc = ((lane & 7) ^ ((lane >> 3) & 7)) << 3;
    const ushort* gAs = A  + (size_t)(m0 + (lane >> 3)) * lda + koff + swzc;
    const ushort* gBs = Bw + (size_t)(n0 + (lane >> 3)) * ldb + koff + swzc;

    const int arow_l = wr2 * 64 + (lane & 15);
    const int brow_l = wc2 * 32 + (lane & 15);
    const int ck0 = (((lane >> 4))     ^ (lane & 7)) << 3;   // ks=0 chunk
    const int ck1 = ((4 + (lane >> 4)) ^ (lane & 7)) << 3;   // ks=1 chunk

    f32x4 acc[2][2][4][2] = {};
    bf16x8 aR[4][2], bR0[2][2], bR1[2][2];

    // prologue: tile 0 halves in steady-state stage order a0,b0,b1,a1;
    // vmcnt(4)+barrier binds A0(0),B0(0) == steady-state entry condition.
    STAGE_A(0, 0, 0);
    STAGE_B(0, 0, 0);
    STAGE_B(0, 1, 0);
    STAGE_A(0, 1, 0);
    asm volatile("s_waitcnt vmcnt(4)" ::: "memory");
    __builtin_amdgcn_s_barrier();

    for (int t = 0; t < NT; ++t) {
        const int d  = t & 1;
        const int e2 = d ^ 1;
        const bool pf = (t + 1) < NT;
        // ---- ph0: Q(0,0). A0(t),B0(t) bound by previous vmcnt+barrier.
        READ_A(0, d);
        READ_B(0, d, bR0);
        if (pf) STAGE_A(t + 1, 0, e2);
        if (pf) asm volatile("s_waitcnt vmcnt(4)" ::: "memory");  // binds B1(t)
        else    asm volatile("s_waitcnt vmcnt(2)" ::: "memory");
        __builtin_amdgcn_s_barrier();
        MFMA_Q(0, 0, bR0);
        // ---- ph1: Q(0,1). B1(t) bound by ph0's vmcnt+barrier.
        READ_B(1, d, bR1);
        if (pf) STAGE_B(t + 1, 0, e2);
        if (pf) asm volatile("s_waitcnt vmcnt(4)" ::: "memory");  // binds A1(t)
        else    asm volatile("s_waitcnt vmcnt(0)" ::: "memory");
        __builtin_amdgcn_s_barrier();
        MFMA_Q(0, 1, bR1);
        // ---- ph2+3 merged: Q(1,1) then Q(1,0). A1(t) bound by ph1's barrier.
        READ_A(1, d);
        if (pf) STAGE_B(t + 1, 1, e2);
        MFMA_Q(1, 1, bR1);
        if (pf) STAGE_A(t + 1, 1, e2);
        if (pf) asm volatile("s_waitcnt vmcnt(4)" ::: "memory");  // binds A0,B0(t+1)
        __builtin_amdgcn_s_barrier();
        MFMA_Q(1, 0, bR0);
    }

    // epilogue: C/D layout col = lane&15, row = (lane>>4)*4 + r  [m89-verified]
    const int lg4 = (lane >> 4) << 2;
    if (MODE != 1) {
        float bsv[2][2], csv[2][2], uu[2][2], vv[2][2];
#pragma unroll
        for (int qc = 0; qc < 2; ++qc)
#pragma unroll
            for (int nf = 0; nf < 2; ++nf) {
                const int col = n0 + qc * 128 + wc2 * 32 + nf * 16 + (lane & 15);
                bsv[qc][nf] = bias[col];
                csv[qc][nf] = cvec[col];
                if (MODE == 2) { uu[qc][nf] = u_[col]; vv[qc][nf] = v_[col]; }
            }
        __syncthreads();                       // drain LDS reads; staging LDS dead
        float2* mrs = (float2*)smem;           // [256] (m,r) of this block's rows
        if (MODE == 2) {
            if (tid < 256) mrs[tid] = mrp[m0 + tid];
            __syncthreads();
        }
        // fused epilogue + LN pass 1 (row partials over this block's 256 cols)
#pragma unroll
        for (int qr = 0; qr < 2; ++qr)
#pragma unroll
            for (int mf = 0; mf < 4; ++mf)
#pragma unroll
                for (int r = 0; r < 4; ++r) {
                    const int rloc = qr * 128 + wr2 * 64 + mf * 16 + lg4 + r;
                    float rw = 1.f, rmw = 0.f;
                    if (MODE == 2) {
                        const float2 q = mrs[rloc];
                        rw = q.y; rmw = q.y * q.x;
                    }
                    float sum = 0.f, sq = 0.f;
#pragma unroll
                    for (int qc = 0; qc < 2; ++qc)
#pragma unroll
                        for (int nf = 0; nf < 2; ++nf) {
                            float a = acc[qr][qc][mf][nf][r];
                            float val;
                            if (MODE == 2)
                                val = fmaf(rw, a, fmaf(-rmw, uu[qc][nf],
                                          vv[qc][nf] + bsv[qc][nf]));
                            else
                                val = a + bsv[qc][nf];
                            val = fmaxf(val, 0.f) + csv[qc][nf];
                            acc[qr][qc][mf][nf][r] = val;
                            sum += val; sq += val * val;
                        }
#pragma unroll
                    for (int o = 1; o < 16; o <<= 1) {
                        sum += __shfl_xor(sum, o, 64);
                        sq  += __shfl_xor(sq,  o, 64);
                    }
                    if ((lane & 15) == 0)
                        pstats[(((size_t)(m0 + rloc)) << 4) + (bx << 2) + wc2] =
                            make_float2(sum, sq);
                }
        // bf16 transpose tile (at +2048, no overlap with mrs) + coalesced store
        ushort* tile = (ushort*)(smem + 2048);   // [256][264], 528B rows
#pragma unroll
        for (int qr = 0; qr < 2; ++qr)
#pragma unroll
            for (int qc = 0; qc < 2; ++qc)
#pragma unroll
                for (int mf = 0; mf < 4; ++mf)
#pragma unroll
                    for (int nf = 0; nf < 2; ++nf)
#pragma unroll
                        for (int r = 0; r < 4; ++r) {
                            const int rloc = qr * 128 + wr2 * 64 + mf * 16 + lg4 + r;
                            const int cloc = qc * 128 + wc2 * 32 + nf * 16 + (lane & 15);
                            tile[rloc * 264 + cloc] = f2bf(acc[qr][qc][mf][nf][r]);
                        }
        __syncthreads();
        ushort* C16 = (ushort*)Cv;
        for (int c = tid; c < 256 * 32; c += 512) {
            const int row = c >> 5, ch = (c & 31) << 3;
            const bf16x8 v = *(const bf16x8*)&tile[row * 264 + ch];
            *(bf16x8*)&C16[(size_t)(m0 + row) * ldc + n0 + ch] = v;
        }
    } else {
        // MODE 1: raw f32 split-K partials (layer-aligned)
        const int cbase = lane & 15;
        float* Cb = (float*)Cv + (size_t)bx * ((size_t)Bv * OUTv);
#pragma unroll
        for (int qr = 0; qr < 2; ++qr)
#pragma unroll
            for (int qc = 0; qc < 2; ++qc)
#pragma unroll
                for (int nf = 0; nf < 2; ++nf) {
                    const int col = qc * 128 + wc2 * 32 + nf * 16 + cbase;
#pragma unroll
                    for (int mf = 0; mf < 4; ++mf) {
                        const int row = m0 + qr * 128 + wr2 * 64 + mf * 16 + lg4;
#pragma unroll
                        for (int r = 0; r < 4; ++r)
                            Cb[(size_t)(row + r) * ldc + col] = acc[qr][qc][mf][nf][r];
                    }
                }
    }
}

// ---------------------------------------------------------------------------
// Final: per-layer LN-folded reduce + bias + LayerNorm(256) + sigmoid.
// val[n] = sum_i r_i*(ps_i[n] - m_i*uf_i[n]) + sum_i vf_i[n] + bf[n]
// 4 rows/block, 1 wave per row, 4 cols/lane.
// ---------------------------------------------------------------------------
__global__ void ln_sig_reduce(const float* __restrict__ ps,
                              const float2* __restrict__ mr,   // (3,B)
                              const float* __restrict__ uf,    // (3,256)
                              const float* __restrict__ vf,    // (3,256)
                              const float* __restrict__ bf_,
                              const float* __restrict__ g,
                              const float* __restrict__ bb,
                              float* __restrict__ y) {
    const int lane = threadIdx.x & 63;
    const int row  = blockIdx.x * 4 + (threadIdx.x >> 6);
    const size_t base = (size_t)row * OUTv + lane * 4;
    const size_t SP = (size_t)Bv * OUTv;
    const float2 q0 = mr[row];
    const float2 q1 = mr[Bv + row];
    const float2 q2 = mr[2 * Bv + row];
    const float4 p0 = *(const float4*)&ps[base];
    const float4 p1 = *(const float4*)&ps[base + SP];
    const float4 p2 = *(const float4*)&ps[base + 2 * SP];
    const float4 u0 = *(const float4*)&uf[lane * 4];
    const float4 u1 = *(const float4*)&uf[256 + lane * 4];
    const float4 u2 = *(const float4*)&uf[512 + lane * 4];
    const float4 f0 = *(const float4*)&vf[lane * 4];
    const float4 f1 = *(const float4*)&vf[256 + lane * 4];
    const float4 f2 = *(const float4*)&vf[512 + lane * 4];
    const float4 bv4 = *(const float4*)&bf_[lane * 4];
    const float cst_x = f0.x + f1.x + f2.x + bv4.x;
    const float cst_y = f0.y + f1.y + f2.y + bv4.y;
    const float cst_z = f0.z + f1.z + f2.z + bv4.z;
    const float cst_w = f0.w + f1.w + f2.w + bv4.w;
    const float v0 = q0.y * (p0.x - q0.x * u0.x) + q1.y * (p1.x - q1.x * u1.x)
                   + q2.y * (p2.x - q2.x * u2.x) + cst_x;
    const float v1 = q0.y * (p0.y - q0.x * u0.y) + q1.y * (p1.y - q1.x * u1.y)
                   + q2.y * (p2.y - q2.x * u2.y) + cst_y;
    const float v2 = q0.y * (p0.z - q0.x * u0.z) + q1.y * (p1.z - q1.x * u1.z)
                   + q2.y * (p2.z - q2.x * u2.z) + cst_z;
    const float v3 = q0.y * (p0.w - q0.x * u0.w) + q1.y * (p1.w - q1.x * u1.w)
                   + q2.y * (p2.w - q2.x * u2.w) + cst_w;
    float s = v0 + v1 + v2 + v3;
#pragma unroll
    for (int o = 1; o < 64; o <<= 1) s += __shfl_xor(s, o, 64);
    const float mean = s * (1.f / OUTv);
    const float d0 = v0 - mean, d1 = v1 - mean, d2 = v2 - mean, d3 = v3 - mean;
    float q = d0 * d0 + d1 * d1 + d2 * d2 + d3 * d3;
#pragma unroll
    for (int o = 1; o < 64; o <<= 1) q += __shfl_xor(q, o, 64);
    const float r = rsqrtf(q * (1.f / OUTv) + EPS);
    const float4 gg = *(const float4*)&g[lane * 4];
    const float4 bv = *(const float4*)&bb[lane * 4];
    float4 o;
    const float t0 = d0 * r * gg.x + bv.x;
    const float t1 = d1 * r * gg.y + bv.y;
    const float t2 = d2 * r * gg.z + bv.z;
    const float t3 = d3 * r * gg.w + bv.w;
    o.x = 1.f / (1.f + expf(-t0));
    o.y = 1.f / (1.f + expf(-t1));
    o.z = 1.f / (1.f + expf(-t2));
    o.w = 1.f / (1.f + expf(-t3));
    *(float4*)&y[base] = o;
}

// ---------------------------------------------------------------------------
extern "C" void kernel_launch(void* const* d_in, const int* in_sizes, int n_in,
                              void* d_out, int out_size, void* d_ws, size_t ws_size,
                              hipStream_t stream) {
    const float* x      = (const float*)d_in[0];
    const float* W      = (const float*)d_in[1];
    const float* b      = (const float*)d_in[2];
    // d_in[3] = Wq, d_in[4] = keys : dead code (softmax row-sums are 1)
    const float* values = (const float*)d_in[5];
    const float* Wout   = (const float*)d_in[6];
    const float* ln_g   = (const float*)d_in[7];
    const float* ln_b   = (const float*)d_in[8];
    const float* Wf     = (const float*)d_in[9];
    const float* bf     = (const float*)d_in[10];
    const float* lnf_g  = (const float*)d_in[11];
    const float* lnf_b  = (const float*)d_in[12];
    float* out = (float*)d_out;

    // workspace layout (~179 MB):
    char* ws = (char*)d_ws;
    ushort* zbuf = (ushort*)ws;                                  // (B,3072) bf16 RAW h + xb
    ws += (size_t)Bv * ZLD * sizeof(ushort);                     // 100.7 MB
    float* psum = (float*)ws;                                    // (3,B,256) f32 split-K partials
    ws += (size_t)Bv * Dv * sizeof(float);                       // 67.1 MB (50.3 used)
    ushort* Wb = (ushort*)ws;                                    // (L,1024,1024) bf16 g-folded
    ws += (size_t)Lv * Dv * Dv * sizeof(ushort);                 // 6.3 MB
    ushort* Wfb = (ushort*)ws;                                   // (256,3072) bf16 g-folded
    ws += (size_t)OUTv * ZLD * sizeof(ushort);                   // 1.6 MB
    float* cvec = (float*)ws;                                    // (L,1024)
    ws += (size_t)Lv * Dv * sizeof(float);
    float* vmean = (float*)ws;                                   // (L,256)
    ws += (size_t)Lv * Vv * sizeof(float);
    float2* pstats = (float2*)ws;                                // (B,16) = 2 MB
    ws += (size_t)Bv * 16 * sizeof(float2);
    float2* mr3 = (float2*)ws;                                   // (3,B) = 384 KB
    ws += (size_t)3 * Bv * sizeof(float2);
    float* ub = (float*)ws; ws += 2 * Dv * sizeof(float);        // (2,1024)
    float* vb = (float*)ws; ws += 2 * Dv * sizeof(float);
    float* uf = (float*)ws; ws += 3 * OUTv * sizeof(float);      // (3,256)
    float* vf = (float*)ws; ws += 3 * OUTv * sizeof(float);

    // prep
    conv_wg<<<1536, 256, 0, stream>>>(W, ln_g, Wb);
    conv_wfg<<<384, 256, 0, stream>>>(Wf, ln_g, Wfb);
    conv_x<<<Bv * 128 / 256, 256, 0, stream>>>(x, zbuf);
    vmean_kernel<<<Lv, 256, 0, stream>>>(values, vmean);
    cvec_kernel<<<Lv * Dv / 8, 512, 0, stream>>>(vmean, Wout, cvec);
    uv_kernel<<<256, 512, 0, stream>>>(W, ln_g, ln_b, ub, vb);
    ufvf_kernel<<<96, 512, 0, stream>>>(Wf, ln_g, ln_b, uf, vf);

    // layer 0: A = xb (cols 2048:3072), plain epilogue
    gemm256<0><<<dim3(256), 512, 0, stream>>>(
        zbuf + 2048, ZLD, Wb, Dv,
        b, cvec, nullptr, nullptr, nullptr,
        (void*)(zbuf + 0), ZLD, /*NT=*/16, 0, pstats);
    mr_kernel<<<Bv / 256, 256, 0, stream>>>(pstats, mr3);

    // layers 1,2: LN of previous layer folded into the GEMM
    for (int i = 1; i < Lv; ++i) {
        gemm256<2><<<dim3(256), 512, 0, stream>>>(
            zbuf + (size_t)(i - 1) * Dv, ZLD, Wb + (size_t)i * Dv * Dv, Dv,
            b + (size_t)i * Dv, cvec + (size_t)i * Dv,
            ub + (size_t)(i - 1) * Dv, vb + (size_t)(i - 1) * Dv,
            mr3 + (size_t)(i - 1) * Bv,
            (void*)(zbuf + (size_t)i * Dv), ZLD, /*NT=*/16, 0, pstats);
        mr_kernel<<<Bv / 256, 256, 0, stream>>>(pstats, mr3 + (size_t)i * Bv);
    }

    // final GEMM: split-K aligned to layers (3 x K=1024), 192 blocks,
    // raw partials; LN folds applied in the reduce.
    gemm256<1><<<dim3(192), 512, 0, stream>>>(
        zbuf, ZLD, Wfb, ZLD, nullptr, nullptr,
        nullptr, nullptr, nullptr,
        (void*)psum, OUTv, /*NT=*/16, /*ksplit=*/1024, pstats);

    ln_sig_reduce<<<Bv / 4, 256, 0, stream>>>(psum, mr3, uf, vf, bf,
                                              lnf_g, lnf_b, out);
}

// Round 10
// 205.243 us; speedup vs baseline: 8.8787x; 1.0641x over previous
//
#include <hip/hip_runtime.h>
#include <math.h>

#define EPS 1e-5f

constexpr int Bv   = 16384;   // batch
constexpr int Dv   = 1024;    // hidden
constexpr int Lv   = 3;       // blocks
constexpr int NKVv = 128;
constexpr int Vv   = 256;
constexpr int OUTv = 256;
constexpr int ZLD  = Lv * Dv; // 3072 concat width (bf16 buffer row stride)

typedef short bf16x8 __attribute__((ext_vector_type(8)));
typedef float f32x4  __attribute__((ext_vector_type(4)));

using gas_t = __attribute__((address_space(1))) const void;
using las_t = __attribute__((address_space(3))) void;
#define GLD_LDS16(gp, lp) \
    __builtin_amdgcn_global_load_lds((gas_t*)(gp), (las_t*)(lp), 16, 0, 0)

// round-to-nearest-even f32 -> bf16 bits
static __device__ __forceinline__ ushort f2bf(float f) {
    unsigned u = __float_as_uint(f);
    u = (u + 0x7fffu + ((u >> 16) & 1u)) >> 16;
    return (ushort)u;
}
// f32 <-> f16 (RTNE via hardware cvt)
static __device__ __forceinline__ ushort f2h(float f) {
    return __builtin_bit_cast(ushort, (_Float16)f);
}
static __device__ __forceinline__ float h2f(ushort u) {
    return (float)__builtin_bit_cast(_Float16, u);
}

// ---------------------------------------------------------------------------
// prep: vmean_i[v] = mean_n values[i][n][v]; cvec[r] = <vmean tile, Wout row r>
// (softmax rows sum to exactly 1 -> attention == add constant vector)
// ---------------------------------------------------------------------------
__global__ void vmean_kernel(const float* __restrict__ values,
                             float* __restrict__ vmean) {
    const int i = blockIdx.x, t = threadIdx.x;
    const float* vals = values + (size_t)i * NKVv * Vv;
    float s = 0.f;
    for (int n = 0; n < NKVv; ++n) s += vals[n * Vv + t];
    vmean[i * Vv + t] = s * (1.0f / NKVv);
}

__global__ void cvec_kernel(const float* __restrict__ vmean,
                            const float* __restrict__ Wout,
                            float* __restrict__ cvec) {
    const int w = threadIdx.x >> 6, lane = threadIdx.x & 63;
    const int r = blockIdx.x * 8 + w;          // 0..L*1024-1
    const int i = r >> 10;
    const float4 mv = *(const float4*)&vmean[i * Vv + lane * 4];
    const float* row = Wout + (size_t)r * 1024;
    float acc = 0.f;
#pragma unroll
    for (int c = 0; c < 4; ++c) {
        const float4 rv = *(const float4*)&row[c * 256 + lane * 4];
        acc += mv.x * rv.x + mv.y * rv.y + mv.z * rv.z + mv.w * rv.w;
    }
#pragma unroll
    for (int o = 1; o < 64; o <<= 1) acc += __shfl_xor(acc, o, 64);
    if (lane == 0) cvec[r] = acc;
}

// ---------------------------------------------------------------------------
// wprep: one block per W row (i,n). Single read of W does BOTH:
//   Wb[i][n][k] = bf16(W[i][n][k] * g_{i-1}[k])  (layer 0 unscaled)
//   ub/vb[i-1][n] = <g_{i-1} | lnb_{i-1}, W[i][n,:]>  (layers 1,2 only)
// ---------------------------------------------------------------------------
__global__ void wprep(const float* __restrict__ W,
                      const float* __restrict__ lng,
                      const float* __restrict__ lnb,
                      ushort* __restrict__ Wb,
                      float* __restrict__ ub, float* __restrict__ vb) {
    __shared__ float rs[8];
    const int row = blockIdx.x;          // 0..3071
    const int i = row >> 10, n = row & 1023;
    const int t = threadIdx.x, lane = t & 63, wv = t >> 6;
    const float* Wr = W + (size_t)row * 1024;
    const float4 w4 = *(const float4*)&Wr[t * 4];
    float4 g4 = make_float4(1.f, 1.f, 1.f, 1.f);
    float4 b4 = make_float4(0.f, 0.f, 0.f, 0.f);
    if (i > 0) {
        g4 = *(const float4*)&lng[(i - 1) * 1024 + t * 4];
        b4 = *(const float4*)&lnb[(i - 1) * 1024 + t * 4];
    }
    const float s0 = w4.x * g4.x, s1 = w4.y * g4.y, s2 = w4.z * g4.z, s3 = w4.w * g4.w;
    ushort4 o = {f2bf(s0), f2bf(s1), f2bf(s2), f2bf(s3)};
    *(ushort4*)&Wb[(size_t)row * 1024 + t * 4] = o;
    float su = s0 + s1 + s2 + s3;
    float sv = w4.x * b4.x + w4.y * b4.y + w4.z * b4.z + w4.w * b4.w;
#pragma unroll
    for (int d = 1; d < 64; d <<= 1) {
        su += __shfl_xor(su, d, 64);
        sv += __shfl_xor(sv, d, 64);
    }
    if (lane == 0) { rs[wv * 2] = su; rs[wv * 2 + 1] = sv; }
    __syncthreads();
    if (t == 0 && i > 0) {
        ub[(i - 1) * 1024 + n] = rs[0] + rs[2] + rs[4] + rs[6];
        vb[(i - 1) * 1024 + n] = rs[1] + rs[3] + rs[5] + rs[7];
    }
}

// wfprep: one block per (slice i, out-row n). Single Wf read does:
//   Wfb[n][i*1024+k] = bf16(Wf[n][i*1024+k] * g_i[k])
//   uf/vf[i][n] = <g_i | lnb_i, Wf[n, i-slice]>
__global__ void wfprep(const float* __restrict__ Wf,
                       const float* __restrict__ lng,
                       const float* __restrict__ lnb,
                       ushort* __restrict__ Wfb,
                       float* __restrict__ uf, float* __restrict__ vf) {
    __shared__ float rs[8];
    const int bid = blockIdx.x;          // 0..767 = i*256 + n
    const int i = bid >> 8, n = bid & 255;
    const int t = threadIdx.x, lane = t & 63, wv = t >> 6;
    const size_t base = (size_t)n * ZLD + i * 1024 + t * 4;
    const float4 w4 = *(const float4*)&Wf[base];
    const float4 g4 = *(const float4*)&lng[i * 1024 + t * 4];
    const float4 b4 = *(const float4*)&lnb[i * 1024 + t * 4];
    const float s0 = w4.x * g4.x, s1 = w4.y * g4.y, s2 = w4.z * g4.z, s3 = w4.w * g4.w;
    ushort4 o = {f2bf(s0), f2bf(s1), f2bf(s2), f2bf(s3)};
    *(ushort4*)&Wfb[base] = o;
    float su = s0 + s1 + s2 + s3;
    float sv = w4.x * b4.x + w4.y * b4.y + w4.z * b4.z + w4.w * b4.w;
#pragma unroll
    for (int d = 1; d < 64; d <<= 1) {
        su += __shfl_xor(su, d, 64);
        sv += __shfl_xor(sv, d, 64);
    }
    if (lane == 0) { rs[wv * 2] = su; rs[wv * 2 + 1] = sv; }
    __syncthreads();
    if (t == 0) {
        uf[i * 256 + n] = rs[0] + rs[2] + rs[4] + rs[6];
        vf[i * 256 + n] = rs[1] + rs[3] + rs[5] + rs[7];
    }
}

// x (B,1024) f32 -> bf16 into zbuf[:, 2048:3072] (row stride ZLD)
__global__ void conv_x(const float* __restrict__ x, ushort* __restrict__ z) {
    const int t = blockIdx.x * 256 + threadIdx.x;  // B*128 threads
    const int row = t >> 7, c8 = (t & 127) << 3;
    const float4 v0 = *(const float4*)&x[(size_t)row * 1024 + c8];
    const float4 v1 = *(const float4*)&x[(size_t)row * 1024 + c8 + 4];
    ushort4 o0 = {f2bf(v0.x), f2bf(v0.y), f2bf(v0.z), f2bf(v0.w)};
    ushort4 o1 = {f2bf(v1.x), f2bf(v1.y), f2bf(v1.z), f2bf(v1.w)};
    ushort* p = z + (size_t)row * ZLD + 2048 + c8;
    *(ushort4*)p       = o0;
    *(ushort4*)(p + 4) = o1;
}

// ---------------------------------------------------------------------------
// 256x256 bf16 MFMA NT GEMM — round-9 schedule (read-early, counted vmcnt,
// XOR bank-swizzle), plus FUSED (m,r) computation in the prologue:
// pstats_in loads are issued and DRAINED (data-dependence + sched_barrier)
// BEFORE the stage gl_lds issue, so the in-loop vmcnt FIFO counts only
// stage loads. (m,r) lives in a dedicated 2KB LDS slab [137216,139264)
// that As/Bs/tile never touch, surviving the main loop into the epilogue.
// Global mr3 copy is stored in the EPILOGUE (stores would pollute vmcnt).
//
// MODE 0 (layer 0): val = relu(acc+bias)+cvec; row (sum,sq) -> pstats_out;
//   bf16 stored coalesced (LDS transpose) into zbuf slot (raw pre-LN h).
// MODE 2 (layers 1,2): prologue computes (m,r) of PREVIOUS layer from
//   pstats_in; epilogue val = relu(r*acc - r*m*u + v + bias) + cvec;
//   bx==0 blocks also publish mr3. pstats ping-pongs between layers.
// MODE 1 (final, split-K by layer): raw acc -> f16 psum slice (coalesced
//   via LDS transpose); bx==2 blocks compute+publish mr3 for layer 2.
// Grid: 256 blocks (MODE 0/2) or 192 blocks (MODE 1), 512 threads.
// ---------------------------------------------------------------------------
#define READ_A(QR, DD)                                                        \
    do { _Pragma("unroll")                                                    \
        for (int mf = 0; mf < 4; ++mf) {                                      \
            const int _o = (DD) * 16384 + (QR) * 8192 + (arow_l + mf * 16) * 64; \
            aR[mf][0] = *(const bf16x8*)&As[_o + ck0];                        \
            aR[mf][1] = *(const bf16x8*)&As[_o + ck1];                        \
        } } while (0)

#define READ_B(QC, DD, BR)                                                    \
    do { _Pragma("unroll")                                                    \
        for (int nf = 0; nf < 2; ++nf) {                                      \
            const int _o = (DD) * 16384 + (QC) * 8192 + (brow_l + nf * 16) * 64; \
            BR[nf][0] = *(const bf16x8*)&Bs[_o + ck0];                        \
            BR[nf][1] = *(const bf16x8*)&Bs[_o + ck1];                        \
        } } while (0)

#define STAGE_A(KT, H, DD)                                                    \
    do { const ushort* _p = gAs + (size_t)((H) * 128 + w16) * lda + (KT) * 64; \
         ushort* _l = As + (DD) * 16384 + (H) * 8192 + w16 * 64;              \
         GLD_LDS16(_p, _l);                                                   \
         GLD_LDS16(_p + (size_t)8 * lda, _l + 512); } while (0)

#define STAGE_B(KT, H, DD)                                                    \
    do { const ushort* _p = gBs + (size_t)((H) * 128 + w16) * ldb + (KT) * 64; \
         ushort* _l = Bs + (DD) * 16384 + (H) * 8192 + w16 * 64;              \
         GLD_LDS16(_p, _l);                                                   \
         GLD_LDS16(_p + (size_t)8 * ldb, _l + 512); } while (0)

#define MFMA_Q(QR, QC, BR)                                                    \
    do { __builtin_amdgcn_s_setprio(1);                                       \
        _Pragma("unroll")                                                     \
        for (int mf = 0; mf < 4; ++mf) {                                      \
            _Pragma("unroll")                                                 \
            for (int nf = 0; nf < 2; ++nf) {                                  \
                acc[QR][QC][mf][nf] = __builtin_amdgcn_mfma_f32_16x16x32_bf16( \
                    aR[mf][0], BR[nf][0], acc[QR][QC][mf][nf], 0, 0, 0);      \
                acc[QR][QC][mf][nf] = __builtin_amdgcn_mfma_f32_16x16x32_bf16( \
                    aR[mf][1], BR[nf][1], acc[QR][QC][mf][nf], 0, 0, 0);      \
            }                                                                 \
        }                                                                     \
        __builtin_amdgcn_s_setprio(0); } while (0)

template<int MODE>
__global__ __launch_bounds__(512, 1)
void gemm256(const ushort* __restrict__ A, int lda,
             const ushort* __restrict__ Bw, int ldb,
             const float* __restrict__ bias,
             const float* __restrict__ cvec,
             const float* __restrict__ u_,
             const float* __restrict__ v_,
             const float2* __restrict__ pstats_in,   // prev-layer stats
             float2* __restrict__ mrout,             // global (B) mr publish
             void* __restrict__ Cv, int ldc,
             int NT, int ksplit,
             float2* __restrict__ pstats_out) {
    // [0,64K) As dbuf | [64K,128K) Bs dbuf | tile at +2048 (epilogue, over
    // As/Bs) | [137216,139264) mrs slab (persists through main loop)
    __shared__ __align__(16) char smem[139264];
    ushort* As = (ushort*)smem;            // [2][2][128][64]
    ushort* Bs = (ushort*)(smem + 65536);  // [2][2][128][64]
    float2* mrs = (float2*)(smem + 137216);
    const int tid  = threadIdx.x;
    const int lane = tid & 63;
    const int w    = tid >> 6;        // wave 0..7
    const int wr2  = w >> 2, wc2 = w & 3;
    const int w16  = w * 16;

    // XCD-chunked swizzle (bijective: nwg % 8 == 0)
    const int wg  = blockIdx.x;
    const int qchunk = (MODE == 1) ? 24 : 32;
    const int swz = (wg & 7) * qchunk + (wg >> 3);
    const int by  = swz & 63;
    const int bx  = swz >> 6;
    const int m0  = by * 256;
    const int n0  = (MODE == 1) ? 0 : bx * 256;
    const int koff = (MODE == 1) ? bx * ksplit : 0;

    // staging source (inverse-XOR-swizzled column chunk; LDS dest is linear)
    const int swzc = ((lane & 7) ^ ((lane >> 3) & 7)) << 3;
    const ushort* gAs = A  + (size_t)(m0 + (lane >> 3)) * lda + koff + swzc;
    const ushort* gBs = Bw + (size_t)(n0 + (lane >> 3)) * ldb + koff + swzc;

    const int arow_l = wr2 * 64 + (lane & 15);
    const int brow_l = wc2 * 32 + (lane & 15);
    const int ck0 = (((lane >> 4))     ^ (lane & 7)) << 3;   // ks=0 chunk
    const int ck1 = ((4 + (lane >> 4)) ^ (lane & 7)) << 3;   // ks=1 chunk

    f32x4 acc[2][2][4][2] = {};
    bf16x8 aR[4][2], bR0[2][2], bR1[2][2];

    // ---- fused mr: load pstats rows, compute (mean, rsqrt), park in mrs.
    // Drained BEFORE stages issue (data-dep + sched_barrier) so the in-loop
    // vmcnt FIFO sees only stage gl_lds.
    const bool doMR = (MODE == 2) || (MODE == 1 && bx == 2);
    float2 myMR = make_float2(0.f, 0.f);
    if (doMR && tid < 256) {
        const float4* pp = (const float4*)(pstats_in + (((size_t)(m0 + tid)) << 4));
        float sum = 0.f, sq = 0.f;
#pragma unroll
        for (int j = 0; j < 8; ++j) {
            const float4 t4 = pp[j];
            sum += t4.x + t4.z; sq += t4.y + t4.w;
        }
        const float m = sum * (1.f / Dv);
        const float var = sq * (1.f / Dv) - m * m;
        myMR = make_float2(m, rsqrtf(var + EPS));
        if (MODE == 2) mrs[tid] = myMR;
    }
    __builtin_amdgcn_sched_barrier(0);   // pstats loads fully retired first

    // prologue: tile 0 halves in steady-state stage order a0,b0,b1,a1;
    // vmcnt(4)+barrier binds A0(0),B0(0) == steady-state entry condition.
    STAGE_A(0, 0, 0);
    STAGE_B(0, 0, 0);
    STAGE_B(0, 1, 0);
    STAGE_A(0, 1, 0);
    asm volatile("s_waitcnt vmcnt(4)" ::: "memory");
    __builtin_amdgcn_s_barrier();

    for (int t = 0; t < NT; ++t) {
        const int d  = t & 1;
        const int e2 = d ^ 1;
        const bool pf = (t + 1) < NT;
        // ---- ph0: Q(0,0). A0(t),B0(t) bound by previous vmcnt+barrier.
        READ_A(0, d);
        READ_B(0, d, bR0);
        if (pf) STAGE_A(t + 1, 0, e2);
        if (pf) asm volatile("s_waitcnt vmcnt(4)" ::: "memory");  // binds B1(t)
        else    asm volatile("s_waitcnt vmcnt(2)" ::: "memory");
        __builtin_amdgcn_s_barrier();
        MFMA_Q(0, 0, bR0);
        // ---- ph1: Q(0,1). B1(t) bound by ph0's vmcnt+barrier.
        READ_B(1, d, bR1);
        if (pf) STAGE_B(t + 1, 0, e2);
        if (pf) asm volatile("s_waitcnt vmcnt(4)" ::: "memory");  // binds A1(t)
        else    asm volatile("s_waitcnt vmcnt(0)" ::: "memory");
        __builtin_amdgcn_s_barrier();
        MFMA_Q(0, 1, bR1);
        // ---- ph2+3 merged: Q(1,1) then Q(1,0). A1(t) bound by ph1's barrier.
        READ_A(1, d);
        if (pf) STAGE_B(t + 1, 1, e2);
        MFMA_Q(1, 1, bR1);
        if (pf) STAGE_A(t + 1, 1, e2);
        if (pf) asm volatile("s_waitcnt vmcnt(4)" ::: "memory");  // binds A0,B0(t+1)
        __builtin_amdgcn_s_barrier();
        MFMA_Q(1, 0, bR0);
    }

    // publish mr3 (global store safe now — vmcnt games over)
    if (doMR && tid < 256 && (MODE == 1 || bx == 0)) mrout[m0 + tid] = myMR;

    // epilogue: C/D layout col = lane&15, row = (lane>>4)*4 + r  [m89-verified]
    const int lg4 = (lane >> 4) << 2;
    ushort* tile = (ushort*)(smem + 2048);   // [256][264], 528B rows
    if (MODE != 1) {
        float bsv[2][2], csv[2][2], uu[2][2], vv[2][2];
#pragma unroll
        for (int qc = 0; qc < 2; ++qc)
#pragma unroll
            for (int nf = 0; nf < 2; ++nf) {
                const int col = n0 + qc * 128 + wc2 * 32 + nf * 16 + (lane & 15);
                bsv[qc][nf] = bias[col];
                csv[qc][nf] = cvec[col];
                if (MODE == 2) { uu[qc][nf] = u_[col]; vv[qc][nf] = v_[col]; }
            }
        __syncthreads();                       // drain LDS reads; staging LDS dead
        // fused epilogue + LN pass 1 (row partials over this block's 256 cols)
#pragma unroll
        for (int qr = 0; qr < 2; ++qr)
#pragma unroll
            for (int mf = 0; mf < 4; ++mf)
#pragma unroll
                for (int r = 0; r < 4; ++r) {
                    const int rloc = qr * 128 + wr2 * 64 + mf * 16 + lg4 + r;
                    float rw = 1.f, rmw = 0.f;
                    if (MODE == 2) {
                        const float2 q = mrs[rloc];
                        rw = q.y; rmw = q.y * q.x;
                    }
                    float sum = 0.f, sq = 0.f;
#pragma unroll
                    for (int qc = 0; qc < 2; ++qc)
#pragma unroll
                        for (int nf = 0; nf < 2; ++nf) {
                            float a = acc[qr][qc][mf][nf][r];
                            float val;
                            if (MODE == 2)
                                val = fmaf(rw, a, fmaf(-rmw, uu[qc][nf],
                                          vv[qc][nf] + bsv[qc][nf]));
                            else
                                val = a + bsv[qc][nf];
                            val = fmaxf(val, 0.f) + csv[qc][nf];
                            acc[qr][qc][mf][nf][r] = val;
                            sum += val; sq += val * val;
                        }
#pragma unroll
                    for (int o = 1; o < 16; o <<= 1) {
                        sum += __shfl_xor(sum, o, 64);
                        sq  += __shfl_xor(sq,  o, 64);
                    }
                    if ((lane & 15) == 0)
                        pstats_out[(((size_t)(m0 + rloc)) << 4) + (bx << 2) + wc2] =
                            make_float2(sum, sq);
                }
        // bf16 transpose tile + coalesced store into zbuf slot
#pragma unroll
        for (int qr = 0; qr < 2; ++qr)
#pragma unroll
            for (int qc = 0; qc < 2; ++qc)
#pragma unroll
                for (int mf = 0; mf < 4; ++mf)
#pragma unroll
                    for (int nf = 0; nf < 2; ++nf)
#pragma unroll
                        for (int r = 0; r < 4; ++r) {
                            const int rloc = qr * 128 + wr2 * 64 + mf * 16 + lg4 + r;
                            const int cloc = qc * 128 + wc2 * 32 + nf * 16 + (lane & 15);
                            tile[rloc * 264 + cloc] = f2bf(acc[qr][qc][mf][nf][r]);
                        }
    } else {
        // MODE 1: raw f32 acc -> f16 tile (coalesced store below)
        __syncthreads();
#pragma unroll
        for (int qr = 0; qr < 2; ++qr)
#pragma unroll
            for (int qc = 0; qc < 2; ++qc)
#pragma unroll
                for (int mf = 0; mf < 4; ++mf)
#pragma unroll
                    for (int nf = 0; nf < 2; ++nf)
#pragma unroll
                        for (int r = 0; r < 4; ++r) {
                            const int rloc = qr * 128 + wr2 * 64 + mf * 16 + lg4 + r;
                            const int cloc = qc * 128 + wc2 * 32 + nf * 16 + (lane & 15);
                            tile[rloc * 264 + cloc] = f2h(acc[qr][qc][mf][nf][r]);
                        }
    }
    __syncthreads();
    ushort* C16 = (MODE == 1)
        ? ((ushort*)Cv + (size_t)bx * ((size_t)Bv * OUTv))
        : (ushort*)Cv;
    for (int c = tid; c < 256 * 32; c += 512) {
        const int row = c >> 5, ch = (c & 31) << 3;
        const bf16x8 v = *(const bf16x8*)&tile[row * 264 + ch];
        *(bf16x8*)&C16[(size_t)(m0 + row) * ldc + n0 + ch] = v;
    }
}

// ---------------------------------------------------------------------------
// Final: per-layer LN-folded reduce + bias + LayerNorm(256) + sigmoid.
// val[n] = sum_i r_i*(ps_i[n] - m_i*uf_i[n]) + sum_i vf_i[n] + bf[n]
// psum slices are f16. 4 rows/block, 1 wave per row, 4 cols/lane.
// ---------------------------------------------------------------------------
__global__ void ln_sig_reduce(const ushort* __restrict__ ps,   // f16 (3,B,256)
                              const float2* __restrict__ mr,   // (3,B)
                              const float* __restrict__ uf,    // (3,256)
                              const float* __restrict__ vf,    // (3,256)
                              const float* __restrict__ bf_,
                              const float* __restrict__ g,
                              const float* __restrict__ bb,
                              float* __restrict__ y) {
    const int lane = threadIdx.x & 63;
    const int row  = blockIdx.x * 4 + (threadIdx.x >> 6);
    const size_t base = (size_t)row * OUTv + lane * 4;
    const size_t SP = (size_t)Bv * OUTv;
    const float2 q0 = mr[row];
    const float2 q1 = mr[Bv + row];
    const float2 q2 = mr[2 * Bv + row];
    const ushort4 a0 = *(const ushort4*)&ps[base];
    const ushort4 a1 = *(const ushort4*)&ps[base + SP];
    const ushort4 a2 = *(const ushort4*)&ps[base + 2 * SP];
    const float4 u0 = *(const float4*)&uf[lane * 4];
    const float4 u1 = *(const float4*)&uf[256 + lane * 4];
    const float4 u2 = *(const float4*)&uf[512 + lane * 4];
    const float4 f0 = *(const float4*)&vf[lane * 4];
    const float4 f1 = *(const float4*)&vf[256 + lane * 4];
    const float4 f2 = *(const float4*)&vf[512 + lane * 4];
    const float4 bv4 = *(const float4*)&bf_[lane * 4];
    const float cst_x = f0.x + f1.x + f2.x + bv4.x;
    const float cst_y = f0.y + f1.y + f2.y + bv4.y;
    const float cst_z = f0.z + f1.z + f2.z + bv4.z;
    const float cst_w = f0.w + f1.w + f2.w + bv4.w;
    const float v0 = q0.y * (h2f(a0.x) - q0.x * u0.x) + q1.y * (h2f(a1.x) - q1.x * u1.x)
                   + q2.y * (h2f(a2.x) - q2.x * u2.x) + cst_x;
    const float v1 = q0.y * (h2f(a0.y) - q0.x * u0.y) + q1.y * (h2f(a1.y) - q1.x * u1.y)
                   + q2.y * (h2f(a2.y) - q2.x * u2.y) + cst_y;
    const float v2 = q0.y * (h2f(a0.z) - q0.x * u0.z) + q1.y * (h2f(a1.z) - q1.x * u1.z)
                   + q2.y * (h2f(a2.z) - q2.x * u2.z) + cst_z;
    const float v3 = q0.y * (h2f(a0.w) - q0.x * u0.w) + q1.y * (h2f(a1.w) - q1.x * u1.w)
                   + q2.y * (h2f(a2.w) - q2.x * u2.w) + cst_w;
    float s = v0 + v1 + v2 + v3;
#pragma unroll
    for (int o = 1; o < 64; o <<= 1) s += __shfl_xor(s, o, 64);
    const float mean = s * (1.f / OUTv);
    const float d0 = v0 - mean, d1 = v1 - mean, d2 = v2 - mean, d3 = v3 - mean;
    float q = d0 * d0 + d1 * d1 + d2 * d2 + d3 * d3;
#pragma unroll
    for (int o = 1; o < 64; o <<= 1) q += __shfl_xor(q, o, 64);
    const float r = rsqrtf(q * (1.f / OUTv) + EPS);
    const float4 gg = *(const float4*)&g[lane * 4];
    const float4 bv = *(const float4*)&bb[lane * 4];
    float4 o;
    const float t0 = d0 * r * gg.x + bv.x;
    const float t1 = d1 * r * gg.y + bv.y;
    const float t2 = d2 * r * gg.z + bv.z;
    const float t3 = d3 * r * gg.w + bv.w;
    o.x = 1.f / (1.f + expf(-t0));
    o.y = 1.f / (1.f + expf(-t1));
    o.z = 1.f / (1.f + expf(-t2));
    o.w = 1.f / (1.f + expf(-t3));
    *(float4*)&y[base] = o;
}

// ---------------------------------------------------------------------------
extern "C" void kernel_launch(void* const* d_in, const int* in_sizes, int n_in,
                              void* d_out, int out_size, void* d_ws, size_t ws_size,
                              hipStream_t stream) {
    const float* x      = (const float*)d_in[0];
    const float* W      = (const float*)d_in[1];
    const float* b      = (const float*)d_in[2];
    // d_in[3] = Wq, d_in[4] = keys : dead code (softmax row-sums are 1)
    const float* values = (const float*)d_in[5];
    const float* Wout   = (const float*)d_in[6];
    const float* ln_g   = (const float*)d_in[7];
    const float* ln_b   = (const float*)d_in[8];
    const float* Wf     = (const float*)d_in[9];
    const float* bf     = (const float*)d_in[10];
    const float* lnf_g  = (const float*)d_in[11];
    const float* lnf_b  = (const float*)d_in[12];
    float* out = (float*)d_out;

    // workspace layout (~140 MB):
    char* ws = (char*)d_ws;
    ushort* zbuf = (ushort*)ws;                                  // (B,3072) bf16 RAW h + xb
    ws += (size_t)Bv * ZLD * sizeof(ushort);                     // 100.7 MB
    ushort* psum = (ushort*)ws;                                  // (3,B,256) f16 split-K partials
    ws += (size_t)3 * Bv * OUTv * sizeof(ushort);                // 25.2 MB
    ushort* Wb = (ushort*)ws;                                    // (L,1024,1024) bf16 g-folded
    ws += (size_t)Lv * Dv * Dv * sizeof(ushort);                 // 6.3 MB
    ushort* Wfb = (ushort*)ws;                                   // (256,3072) bf16 g-folded
    ws += (size_t)OUTv * ZLD * sizeof(ushort);                   // 1.6 MB
    float* cvec = (float*)ws;                                    // (L,1024)
    ws += (size_t)Lv * Dv * sizeof(float);
    float* vmean = (float*)ws;                                   // (L,256)
    ws += (size_t)Lv * Vv * sizeof(float);
    float2* psA = (float2*)ws;                                   // (B,16) ping
    ws += (size_t)Bv * 16 * sizeof(float2);                      // 2 MB
    float2* psB = (float2*)ws;                                   // (B,16) pong
    ws += (size_t)Bv * 16 * sizeof(float2);                      // 2 MB
    float2* mr3 = (float2*)ws;                                   // (3,B)
    ws += (size_t)3 * Bv * sizeof(float2);                       // 384 KB
    float* ub = (float*)ws; ws += 2 * Dv * sizeof(float);        // (2,1024)
    float* vb = (float*)ws; ws += 2 * Dv * sizeof(float);
    float* uf = (float*)ws; ws += 3 * OUTv * sizeof(float);      // (3,256)
    float* vf = (float*)ws; ws += 3 * OUTv * sizeof(float);

    // prep (single-read fused weight converts + fold vectors)
    wprep<<<Lv * Dv, 256, 0, stream>>>(W, ln_g, ln_b, Wb, ub, vb);
    wfprep<<<3 * OUTv, 256, 0, stream>>>(Wf, ln_g, ln_b, Wfb, uf, vf);
    conv_x<<<Bv * 128 / 256, 256, 0, stream>>>(x, zbuf);
    vmean_kernel<<<Lv, 256, 0, stream>>>(values, vmean);
    cvec_kernel<<<Lv * Dv / 8, 512, 0, stream>>>(vmean, Wout, cvec);

    // layer 0: A = xb (cols 2048:3072) -> raw h0 + pstats into psA
    gemm256<0><<<dim3(256), 512, 0, stream>>>(
        zbuf + 2048, ZLD, Wb, Dv,
        b, cvec, nullptr, nullptr, nullptr, nullptr,
        (void*)(zbuf + 0), ZLD, /*NT=*/16, 0, psA);

    // layer 1: fused mr(layer0) from psA; writes pstats(layer1) -> psB
    gemm256<2><<<dim3(256), 512, 0, stream>>>(
        zbuf, ZLD, Wb + (size_t)Dv * Dv, Dv,
        b + Dv, cvec + Dv, ub, vb, psA, mr3,
        (void*)(zbuf + Dv), ZLD, /*NT=*/16, 0, psB);

    // layer 2: fused mr(layer1) from psB; writes pstats(layer2) -> psA
    gemm256<2><<<dim3(256), 512, 0, stream>>>(
        zbuf + Dv, ZLD, Wb + (size_t)2 * Dv * Dv, Dv,
        b + 2 * Dv, cvec + 2 * Dv, ub + Dv, vb + Dv, psB, mr3 + Bv,
        (void*)(zbuf + 2 * Dv), ZLD, /*NT=*/16, 0, psA);

    // final GEMM: split-K by layer (3 x K=1024), 192 blocks, f16 partials;
    // bx==2 blocks also compute+publish mr3(layer2) from psA.
    gemm256<1><<<dim3(192), 512, 0, stream>>>(
        zbuf, ZLD, Wfb, ZLD, nullptr, nullptr, nullptr, nullptr,
        psA, mr3 + 2 * Bv,
        (void*)psum, OUTv, /*NT=*/16, /*ksplit=*/1024, nullptr);

    ln_sig_reduce<<<Bv / 4, 256, 0, stream>>>(psum, mr3, uf, vf, bf,
                                              lnf_g, lnf_b, out);
}